// Round 1
// baseline (10368.779 us; speedup 1.0000x reference)
//
#include <hip/hip_runtime.h>
#include <hip/hip_bf16.h>

#define Bn 64
#define Cn 2048
#define Nn 162          // H*W = 18*9
#define Pn 81           // Nn/2
#define INFV 1.0e9f

// ws layout (in floats)
#define OFF_P    0                          // [64][16][162] norm^2 partials
#define OFF_QS   (64*16*162)                // [64][162] masked row scale (0 or 1/norm)
#define OFF_KS   (OFF_QS + 64*162)          // [64][162] col scale 1/norm
#define OFF_COST (OFF_KS + 64*162)          // [64][162][162] cost = -sim (fp32)
#define OFF_PD   (OFF_COST + 64*162*162)    // [64] per-batch pos_dis

static __device__ __forceinline__ unsigned short f2bf(float x) {
    unsigned int u = __builtin_bit_cast(unsigned int, x);
    unsigned int r = (u + 0x7fffu + ((u >> 16) & 1u)) >> 16;   // RNE
    return (unsigned short)r;
}
static __device__ __forceinline__ float bf2f(unsigned short h) {
    unsigned int u = ((unsigned int)h) << 16;
    return __builtin_bit_cast(float, u);
}

// ---------------- K1: norm^2 partials ----------------
__global__ void k_norm(const float* __restrict__ feat, float* __restrict__ ws) {
    int chunk = blockIdx.x;     // 16 chunks of 128 channels
    int b     = blockIdx.y;
    int t     = threadIdx.x;
    if (t >= Nn) return;
    const float* base = feat + ((size_t)b * Cn + (size_t)chunk * 128) * Nn + t;
    float acc = 0.f;
    #pragma unroll 4
    for (int c = 0; c < 128; ++c) { float x = base[(size_t)c * Nn]; acc = fmaf(x, x, acc); }
    ws[OFF_P + (size_t)(b * 16 + chunk) * Nn + t] = acc;
}

// ---------------- K2: per-batch stats: mask threshold + scales ----------------
__global__ void k_stats(float* __restrict__ ws) {
    int b = blockIdx.x;
    int t = threadIdx.x;        // 192 threads, 162 active
    __shared__ float arr[Nn];
    __shared__ float thr;
    float norm = 0.f;
    if (t < Nn) {
        float s = 0.f;
        #pragma unroll
        for (int ch = 0; ch < 16; ++ch) s += ws[OFF_P + (size_t)(b * 16 + ch) * Nn + t];
        norm = sqrtf(s);
        arr[t] = norm;
    }
    __syncthreads();
    float mn = INFV, mx = -INFV;
    for (int k = 0; k < Nn; ++k) { float v = arr[k]; mn = fminf(mn, v); mx = fmaxf(mx, v); }
    __syncthreads();
    float mval = 0.f;
    if (t < Nn) mval = (norm - mn) / (mx - mn + 1e-12f);
    __syncthreads();
    if (t < Nn) arr[t] = mval;
    __syncthreads();
    if (t < Nn) {
        int cl = 0, ce = 0, ceb = 0;
        for (int k = 0; k < Nn; ++k) {
            float v = arr[k];
            cl  += (v <  mval);
            ce  += (v == mval);
            ceb += (v == mval && k < t);
        }
        // sorted[81]: count_less <= 81 < count_less + count_eq; single writer = first index among equals
        if (cl <= Pn && (cl + ce) > Pn && ceb == 0) thr = mval;
    }
    __syncthreads();
    if (t < Nn) {
        float inv = 1.f / fmaxf(norm, 1e-12f);
        ws[OFF_KS + (size_t)b * Nn + t] = inv;
        ws[OFF_QS + (size_t)b * Nn + t] = (mval < thr) ? 0.f : inv;
    }
}

// ---------------- K3: similarity GEMM -> cost = -sim ----------------
#define BM 32
#define BN 192          // 162 padded to 192 (16 thread-groups x 12 cols, b128-aligned)
#define KC 16
__global__ __launch_bounds__(256) void k_gemm(const float* __restrict__ feat,
                                              const int* __restrict__ pos_ind,
                                              float* __restrict__ ws) {
    int mt = blockIdx.x;        // 6 M-tiles of 32 rows
    int b  = blockIdx.y;
    int t  = threadIdx.x;
    int j0 = mt * BM;
    int pb = pos_ind[b];
    const float* Ag = feat + (size_t)b  * Cn * Nn;
    const float* Bg = feat + (size_t)pb * Cn * Nn;
    __shared__ float As[KC][BM];
    __shared__ float Bs[KC][BN];
    float acc[2][12];
    #pragma unroll
    for (int r = 0; r < 2; ++r)
        #pragma unroll
        for (int k = 0; k < 12; ++k) acc[r][k] = 0.f;
    int tx = t & 15, ty = t >> 4;
    for (int c0 = 0; c0 < Cn; c0 += KC) {
        #pragma unroll
        for (int r = 0; r < 2; ++r) {
            int i = t + 256 * r; int c = i >> 5, jj = i & 31;
            int j = j0 + jj;
            As[c][jj] = (j < Nn) ? Ag[(size_t)(c0 + c) * Nn + j] : 0.f;
        }
        #pragma unroll
        for (int r = 0; r < 12; ++r) {
            int i = t + 256 * r; int c = i / BN, m = i - c * BN;
            Bs[c][m] = (m < Nn) ? Bg[(size_t)(c0 + c) * Nn + m] : 0.f;
        }
        __syncthreads();
        #pragma unroll
        for (int c = 0; c < KC; ++c) {
            float a0 = As[c][ty * 2], a1 = As[c][ty * 2 + 1];
            #pragma unroll
            for (int k = 0; k < 12; ++k) {
                float bv = Bs[c][tx * 12 + k];
                acc[0][k] = fmaf(a0, bv, acc[0][k]);
                acc[1][k] = fmaf(a1, bv, acc[1][k]);
            }
        }
        __syncthreads();
    }
    #pragma unroll
    for (int rr = 0; rr < 2; ++rr) {
        int row = j0 + ty * 2 + rr;
        if (row >= Nn) continue;
        float qs = ws[OFF_QS + (size_t)b * Nn + row];
        #pragma unroll
        for (int k = 0; k < 12; ++k) {
            int m = tx * 12 + k;
            if (m >= Nn) continue;
            float ks = ws[OFF_KS + (size_t)pb * Nn + m];
            ws[OFF_COST + ((size_t)b * Nn + row) * Nn + m] = -(acc[rr][k] * qs * ks);
        }
    }
}

// ---------------- K4: Hungarian (JV), one wave per batch ----------------
#define CSTR 164
__global__ __launch_bounds__(64) void k_hung(float* __restrict__ ws) {
    int b = blockIdx.x;
    int lane = threadIdx.x;
    __shared__ unsigned short C[Nn * CSTR];   // bf16 cost, 53 KB
    __shared__ float U[Nn + 1];
    __shared__ int   Pa[Nn + 1];
    __shared__ int   W[Nn + 1];
    const float* cg = ws + OFF_COST + (size_t)b * Nn * Nn;

    for (int row = 0; row < Nn; ++row)
        for (int col = lane; col < Nn; col += 64)
            C[row * CSTR + col] = f2bf(cg[row * Nn + col]);
    for (int j = lane; j <= Nn; j += 64) { U[j] = 0.f; Pa[j] = 0; }
    __syncthreads();

    int  jc[3];  bool valid[3];
    #pragma unroll
    for (int k = 0; k < 3; ++k) { jc[k] = lane + 64 * k; valid[k] = (jc[k] <= Nn); }
    float v_[3] = {0.f, 0.f, 0.f};

    for (int i = 1; i <= Nn; ++i) {
        float minv[3] = {INFV, INFV, INFV};
        bool  used[3] = {false, false, false};
        for (int j = lane; j <= Nn; j += 64) W[j] = 0;
        if (lane == 0) Pa[0] = i;
        __syncthreads();
        int j0 = 0;
        for (int step = 0; step < Nn + 2; ++step) {
            #pragma unroll
            for (int k = 0; k < 3; ++k) if (valid[k] && jc[k] == j0) used[k] = true;
            int i0 = Pa[j0];
            float ui0 = U[i0];
            float mv[3];
            #pragma unroll
            for (int k = 0; k < 3; ++k) {
                mv[k] = INFV;
                if (valid[k] && jc[k] >= 1 && !used[k]) {
                    float cur = bf2f(C[(i0 - 1) * CSTR + (jc[k] - 1)]) - ui0 - v_[k];
                    if (cur < minv[k]) { minv[k] = cur; W[jc[k]] = j0; }
                    mv[k] = minv[k];
                }
            }
            float bv = mv[0]; int bj = jc[0];
            if (mv[1] < bv) { bv = mv[1]; bj = jc[1]; }
            if (mv[2] < bv) { bv = mv[2]; bj = jc[2]; }
            #pragma unroll
            for (int off = 32; off; off >>= 1) {
                float ov = __shfl_xor(bv, off);
                int   oj = __shfl_xor(bj, off);
                if (ov < bv || (ov == bv && oj < bj)) { bv = ov; bj = oj; }
            }
            float delta = bv; int j1 = bj;
            #pragma unroll
            for (int k = 0; k < 3; ++k) {
                if (!valid[k]) continue;
                if (used[k]) {
                    v_[k] -= delta;
                    int rk = Pa[jc[k]];
                    U[rk] += delta;           // rows distinct across used cols
                } else if (jc[k] >= 1) {
                    minv[k] -= delta;
                }
            }
            j0 = j1;
            if (Pa[j1] == 0) break;
        }
        __syncthreads();
        if (lane == 0) {
            int jj = j0, guard = 0;
            while (jj != 0 && guard++ <= Nn) { int j1 = W[jj]; Pa[jj] = Pa[j1]; jj = j1; }
        }
        __syncthreads();
    }

    float tot = 0.f;
    #pragma unroll
    for (int k = 0; k < 3; ++k) {
        int j = jc[k];
        if (j >= 1 && j <= Nn) {
            int row = Pa[j];                  // 1..Nn
            tot -= cg[(size_t)(row - 1) * Nn + (j - 1)];   // sim = -cost, fp32
        }
    }
    #pragma unroll
    for (int off = 32; off; off >>= 1) tot += __shfl_xor(tot, off);
    if (lane == 0) ws[OFF_PD + b] = 1.f - tot * (1.f / (float)Pn);
}

// ---------------- K5: mean over batches ----------------
__global__ void k_final(const float* __restrict__ ws, float* __restrict__ out) {
    float v = ws[OFF_PD + threadIdx.x];
    #pragma unroll
    for (int off = 32; off; off >>= 1) v += __shfl_xor(v, off);
    if (threadIdx.x == 0) out[0] = v * (1.f / 64.f);
}

extern "C" void kernel_launch(void* const* d_in, const int* in_sizes, int n_in,
                              void* d_out, int out_size, void* d_ws, size_t ws_size,
                              hipStream_t stream) {
    const float* feat = (const float*)d_in[0];
    const int*   pos  = (const int*)d_in[1];
    float* ws  = (float*)d_ws;
    float* out = (float*)d_out;
    k_norm <<<dim3(16, 64), 192, 0, stream>>>(feat, ws);
    k_stats<<<64, 192, 0, stream>>>(ws);
    k_gemm <<<dim3(6, 64), 256, 0, stream>>>(feat, pos, ws);
    k_hung <<<64, 64, 0, stream>>>(ws);
    k_final<<<1, 64, 0, stream>>>(ws, out);
}

// Round 2
// 3827.148 us; speedup vs baseline: 2.7093x; 2.7093x over previous
//
#include <hip/hip_runtime.h>
#include <hip/hip_bf16.h>

#define Bn 64
#define Cn 2048
#define Nn 162          // H*W = 18*9
#define Pn 81           // Nn/2
#define INFV 1.0e9f
#define BIGI 0x7FFFFFFF
#define CSTR 192        // LDS row stride (u16), keeps all jcol<=191 in-bounds

// ws layout (in floats)
#define OFF_P    0                          // [64][16][162] norm^2 partials
#define OFF_QS   (64*16*162)                // [64][162] masked row scale (0 or 1/norm)
#define OFF_KS   (OFF_QS + 64*162)          // [64][162] col scale 1/norm
#define OFF_COST (OFF_KS + 64*162)          // [64][162][162] cost = -sim (fp32)
#define OFF_PD   (OFF_COST + 64*162*162)    // [64] per-batch pos_dis

static __device__ __forceinline__ unsigned short f2bf(float x) {
    unsigned int u = __builtin_bit_cast(unsigned int, x);
    unsigned int r = (u + 0x7fffu + ((u >> 16) & 1u)) >> 16;   // RNE
    return (unsigned short)r;
}
static __device__ __forceinline__ float bf2f(unsigned short h) {
    unsigned int u = ((unsigned int)h) << 16;
    return __builtin_bit_cast(float, u);
}
static __device__ __forceinline__ unsigned umin32(unsigned a, unsigned b) { return a < b ? a : b; }
// order-preserving float->uint flip
static __device__ __forceinline__ unsigned flipf(float f) {
    unsigned u = __builtin_bit_cast(unsigned, f);
    return u ^ (0x80000000u | (unsigned)((int)u >> 31));
}
static __device__ __forceinline__ float unflipf(unsigned u) {
    unsigned m = 0x80000000u | ~((unsigned)((int)u >> 31));
    return __builtin_bit_cast(float, u ^ m);
}
// min across 64 lanes, result uniform (via SGPRs). 4x DPP row_ror + 4x readlane.
static __device__ __forceinline__ unsigned reduceMin64(unsigned x) {
    int v = (int)x, t;
    t = __builtin_amdgcn_update_dpp(0, v, 0x121, 0xF, 0xF, true); v = (int)umin32((unsigned)v, (unsigned)t);
    t = __builtin_amdgcn_update_dpp(0, v, 0x122, 0xF, 0xF, true); v = (int)umin32((unsigned)v, (unsigned)t);
    t = __builtin_amdgcn_update_dpp(0, v, 0x124, 0xF, 0xF, true); v = (int)umin32((unsigned)v, (unsigned)t);
    t = __builtin_amdgcn_update_dpp(0, v, 0x128, 0xF, 0xF, true); v = (int)umin32((unsigned)v, (unsigned)t);
    unsigned a = (unsigned)__builtin_amdgcn_readlane(v, 0);
    unsigned b = (unsigned)__builtin_amdgcn_readlane(v, 16);
    unsigned c = (unsigned)__builtin_amdgcn_readlane(v, 32);
    unsigned d = (unsigned)__builtin_amdgcn_readlane(v, 48);
    return umin32(umin32(a, b), umin32(c, d));
}

// ---------------- K1: norm^2 partials ----------------
__global__ void k_norm(const float* __restrict__ feat, float* __restrict__ ws) {
    int chunk = blockIdx.x;     // 16 chunks of 128 channels
    int b     = blockIdx.y;
    int t     = threadIdx.x;
    if (t >= Nn) return;
    const float* base = feat + ((size_t)b * Cn + (size_t)chunk * 128) * Nn + t;
    float acc = 0.f;
    #pragma unroll 4
    for (int c = 0; c < 128; ++c) { float x = base[(size_t)c * Nn]; acc = fmaf(x, x, acc); }
    ws[OFF_P + (size_t)(b * 16 + chunk) * Nn + t] = acc;
}

// ---------------- K2: per-batch stats: mask threshold + scales ----------------
__global__ void k_stats(float* __restrict__ ws) {
    int b = blockIdx.x;
    int t = threadIdx.x;        // 192 threads, 162 active
    __shared__ float arr[Nn];
    __shared__ float thr;
    float norm = 0.f;
    if (t < Nn) {
        float s = 0.f;
        #pragma unroll
        for (int ch = 0; ch < 16; ++ch) s += ws[OFF_P + (size_t)(b * 16 + ch) * Nn + t];
        norm = sqrtf(s);
        arr[t] = norm;
    }
    __syncthreads();
    float mn = INFV, mx = -INFV;
    for (int k = 0; k < Nn; ++k) { float v = arr[k]; mn = fminf(mn, v); mx = fmaxf(mx, v); }
    __syncthreads();
    float mval = 0.f;
    if (t < Nn) mval = (norm - mn) / (mx - mn + 1e-12f);
    __syncthreads();
    if (t < Nn) arr[t] = mval;
    __syncthreads();
    if (t < Nn) {
        int cl = 0, ce = 0, ceb = 0;
        for (int k = 0; k < Nn; ++k) {
            float v = arr[k];
            cl  += (v <  mval);
            ce  += (v == mval);
            ceb += (v == mval && k < t);
        }
        if (cl <= Pn && (cl + ce) > Pn && ceb == 0) thr = mval;
    }
    __syncthreads();
    if (t < Nn) {
        float inv = 1.f / fmaxf(norm, 1e-12f);
        ws[OFF_KS + (size_t)b * Nn + t] = inv;
        ws[OFF_QS + (size_t)b * Nn + t] = (mval < thr) ? 0.f : inv;
    }
}

// ---------------- K3: similarity GEMM -> cost = -sim ----------------
#define BM 32
#define BN 192
#define KC 16
__global__ __launch_bounds__(256) void k_gemm(const float* __restrict__ feat,
                                              const int* __restrict__ pos_ind,
                                              float* __restrict__ ws) {
    int mt = blockIdx.x;        // 6 M-tiles of 32 rows
    int b  = blockIdx.y;
    int t  = threadIdx.x;
    int j0 = mt * BM;
    int pb = pos_ind[b];
    const float* Ag = feat + (size_t)b  * Cn * Nn;
    const float* Bg = feat + (size_t)pb * Cn * Nn;
    __shared__ float As[KC][BM];
    __shared__ float Bs[KC][BN];
    float acc[2][12];
    #pragma unroll
    for (int r = 0; r < 2; ++r)
        #pragma unroll
        for (int k = 0; k < 12; ++k) acc[r][k] = 0.f;
    int tx = t & 15, ty = t >> 4;
    for (int c0 = 0; c0 < Cn; c0 += KC) {
        #pragma unroll
        for (int r = 0; r < 2; ++r) {
            int i = t + 256 * r; int c = i >> 5, jj = i & 31;
            int j = j0 + jj;
            As[c][jj] = (j < Nn) ? Ag[(size_t)(c0 + c) * Nn + j] : 0.f;
        }
        #pragma unroll
        for (int r = 0; r < 12; ++r) {
            int i = t + 256 * r; int c = i / BN, m = i - c * BN;
            Bs[c][m] = (m < Nn) ? Bg[(size_t)(c0 + c) * Nn + m] : 0.f;
        }
        __syncthreads();
        #pragma unroll
        for (int c = 0; c < KC; ++c) {
            float a0 = As[c][ty * 2], a1 = As[c][ty * 2 + 1];
            #pragma unroll
            for (int k = 0; k < 12; ++k) {
                float bv = Bs[c][tx * 12 + k];
                acc[0][k] = fmaf(a0, bv, acc[0][k]);
                acc[1][k] = fmaf(a1, bv, acc[1][k]);
            }
        }
        __syncthreads();
    }
    #pragma unroll
    for (int rr = 0; rr < 2; ++rr) {
        int row = j0 + ty * 2 + rr;
        if (row >= Nn) continue;
        float qs = ws[OFF_QS + (size_t)b * Nn + row];
        #pragma unroll
        for (int k = 0; k < 12; ++k) {
            int m = tx * 12 + k;
            if (m >= Nn) continue;
            float ks = ws[OFF_KS + (size_t)pb * Nn + m];
            ws[OFF_COST + ((size_t)b * Nn + row) * Nn + m] = -(acc[rr][k] * qs * ks);
        }
    }
}

// ---------------- K4: Hungarian (JV) with column-reduction init ----------------
// One wave per batch. All dual/assignment state register-distributed by column
// (3 cols per lane). Cross-lane traffic = v_readlane (uniform idx) + DPP reduce.
__global__ __launch_bounds__(64) void k_hung(float* __restrict__ ws) {
    const int b = blockIdx.x;
    const int lane = threadIdx.x;
    __shared__ unsigned short C[Nn * CSTR];   // bf16 cost, 60.8 KB
    __shared__ int rowBest[Nn + 1];
    const float* cg = ws + OFF_COST + (size_t)b * Nn * Nn;

    for (int row = 0; row < Nn; ++row)
        for (int col = lane; col < Nn; col += 64)
            C[row * CSTR + col] = f2bf(cg[row * Nn + col]);
    for (int r = lane; r <= Nn; r += 64) rowBest[r] = BIGI;
    __syncthreads();

    int jcol[3]; bool valid[3];
    #pragma unroll
    for (int k = 0; k < 3; ++k) { jcol[k] = lane + 64 * k; valid[k] = (jcol[k] <= Nn); }

    // column reduction: v[j] = min_i c[i][j], argmin row (first min)
    float cm[3] = {INFV, INFV, INFV}; int im[3] = {0, 0, 0};
    for (int r = 0; r < Nn; ++r) {
        #pragma unroll
        for (int k = 0; k < 3; ++k) if (valid[k] && jcol[k] >= 1) {
            float c = bf2f(C[r * CSTR + jcol[k] - 1]);
            if (c < cm[k]) { cm[k] = c; im[k] = r + 1; }
        }
    }
    // greedy claim: row r goes to the smallest col whose argmin is r
    #pragma unroll
    for (int k = 0; k < 3; ++k) if (valid[k] && jcol[k] >= 1) atomicMin(&rowBest[im[k]], jcol[k]);
    __syncthreads();

    float v_[3], ur_[3]; int Pa_[3], way_[3];
    #pragma unroll
    for (int k = 0; k < 3; ++k) {
        bool realc = valid[k] && jcol[k] >= 1;
        v_[k]  = realc ? cm[k] : 0.f;
        Pa_[k] = (realc && rowBest[im[k]] == jcol[k]) ? im[k] : 0;
        ur_[k] = 0.f;
        way_[k] = 0;
    }
    unsigned long long mm0 = __ballot(lane + 1 <= Nn && rowBest[lane + 1] != BIGI);
    unsigned long long mm1 = __ballot(lane + 65 <= Nn && rowBest[lane + 65] != BIGI);
    unsigned long long mm2 = __ballot(lane + 129 <= Nn && rowBest[lane + 129] != BIGI);

    for (int i = 1; i <= Nn; ++i) {
        int bi = i - 1;
        unsigned long long mm = bi < 64 ? mm0 : (bi < 128 ? mm1 : mm2);
        if ((mm >> (bi & 63)) & 1ULL) continue;           // greedy-matched row

        if (lane == 0) { Pa_[0] = i; ur_[0] = 0.f; }
        float minv_[3] = {INFV, INFV, INFV};
        bool  used_[3] = {false, false, false};
        #pragma unroll
        for (int k = 0; k < 3; ++k) way_[k] = 0;
        int j0 = 0, jfree = -1;

        for (int it = 0; it <= Nn + 1; ++it) {
            int l0 = j0 & 63, s0 = j0 >> 6;
            if (lane == l0) {
                if (s0 == 0) used_[0] = true; else if (s0 == 1) used_[1] = true; else used_[2] = true;
            }
            int pa_s = (s0 == 0) ? Pa_[0] : ((s0 == 1) ? Pa_[1] : Pa_[2]);
            int ur_s = __builtin_bit_cast(int, (s0 == 0) ? ur_[0] : ((s0 == 1) ? ur_[1] : ur_[2]));
            int i0 = __builtin_amdgcn_readlane(pa_s, l0);
            float ur0 = __builtin_bit_cast(float, __builtin_amdgcn_readlane(ur_s, l0));
            if (i0 == 0) { jfree = j0; break; }           // reached a free column

            const int rowoff = (i0 - 1) * CSTR;
            unsigned pk = 0xFFFFFFFFu;
            #pragma unroll
            for (int k = 0; k < 3; ++k) {
                int ci = jcol[k] - 1; if (ci < 0) ci = 0;
                float c = bf2f(C[rowoff + ci]);
                float cur = c - ur0 - v_[k];
                bool cand = valid[k] && (jcol[k] >= 1) && !used_[k];
                if (cand && cur < minv_[k]) { minv_[k] = cur; way_[k] = j0; }
                unsigned pkk = cand ? ((flipf(minv_[k]) & 0xFFFFFF00u) | (unsigned)(jcol[k] - 1))
                                    : 0xFFFFFFFFu;
                pk = umin32(pk, pkk);
            }
            pk = reduceMin64(pk);
            int j1 = (int)(pk & 0xFFu) + 1;
            float delta = unflipf(pk & 0xFFFFFF00u);
            #pragma unroll
            for (int k = 0; k < 3; ++k) {
                if (used_[k]) { v_[k] -= delta; ur_[k] += delta; }
                else          { minv_[k] -= delta; }
            }
            j0 = j1;
        }

        int j = (jfree >= 0) ? jfree : j0;
        while (j != 0) {                                   // augment along way[] path
            int l = j & 63, s = j >> 6;
            int way_s = (s == 0) ? way_[0] : ((s == 1) ? way_[1] : way_[2]);
            int w = __builtin_amdgcn_readlane(way_s, l);
            int lw = w & 63, sw = w >> 6;
            int pa_w = (sw == 0) ? Pa_[0] : ((sw == 1) ? Pa_[1] : Pa_[2]);
            int ur_w = __builtin_bit_cast(int, (sw == 0) ? ur_[0] : ((sw == 1) ? ur_[1] : ur_[2]));
            int paw = __builtin_amdgcn_readlane(pa_w, lw);
            int urw = __builtin_amdgcn_readlane(ur_w, lw);
            if (lane == l) {
                if (s == 0)      { Pa_[0] = paw; ur_[0] = __builtin_bit_cast(float, urw); }
                else if (s == 1) { Pa_[1] = paw; ur_[1] = __builtin_bit_cast(float, urw); }
                else             { Pa_[2] = paw; ur_[2] = __builtin_bit_cast(float, urw); }
            }
            j = w;
        }
    }

    float tot = 0.f;
    #pragma unroll
    for (int k = 0; k < 3; ++k) {
        if (valid[k] && jcol[k] >= 1) {
            int row = Pa_[k];                              // 1..Nn
            tot -= cg[(size_t)(row - 1) * Nn + (jcol[k] - 1)];  // sim = -cost, fp32
        }
    }
    #pragma unroll
    for (int off = 32; off; off >>= 1) tot += __shfl_xor(tot, off);
    if (lane == 0) ws[OFF_PD + b] = 1.f - tot * (1.f / (float)Pn);
}

// ---------------- K5: mean over batches ----------------
__global__ void k_final(const float* __restrict__ ws, float* __restrict__ out) {
    float v = ws[OFF_PD + threadIdx.x];
    #pragma unroll
    for (int off = 32; off; off >>= 1) v += __shfl_xor(v, off);
    if (threadIdx.x == 0) out[0] = v * (1.f / 64.f);
}

extern "C" void kernel_launch(void* const* d_in, const int* in_sizes, int n_in,
                              void* d_out, int out_size, void* d_ws, size_t ws_size,
                              hipStream_t stream) {
    const float* feat = (const float*)d_in[0];
    const int*   pos  = (const int*)d_in[1];
    float* ws  = (float*)d_ws;
    float* out = (float*)d_out;
    k_norm <<<dim3(16, 64), 192, 0, stream>>>(feat, ws);
    k_stats<<<64, 192, 0, stream>>>(ws);
    k_gemm <<<dim3(6, 64), 256, 0, stream>>>(feat, pos, ws);
    k_hung <<<64, 64, 0, stream>>>(ws);
    k_final<<<1, 64, 0, stream>>>(ws, out);
}

// Round 3
// 2553.929 us; speedup vs baseline: 4.0599x; 1.4985x over previous
//
#include <hip/hip_runtime.h>
#include <hip/hip_bf16.h>

#define Bn 64
#define Cn 2048
#define Nn 162          // H*W = 18*9
#define Pn 81           // Nn/2
#define INFV 1.0e9f
#define BIGI 0x7FFFFFFF
#define RBW 328         // LDS cost-row stride in BYTES: 128 cols packed as u32 pairs (256B) + 34 u16 + pad

// ws layout (in floats)
#define OFF_P    0                          // [64][16][162] norm^2 partials
#define OFF_QS   (64*16*162)                // [64][162] masked row scale (0 or 1/norm)
#define OFF_KS   (OFF_QS + 64*162)          // [64][162] col scale 1/norm
#define OFF_COST (OFF_KS + 64*162)          // [64][162][162] cost = -sim (fp32)
#define OFF_PD   (OFF_COST + 64*162*162)    // [64] per-batch pos_dis

static __device__ __forceinline__ unsigned short f2bf(float x) {
    unsigned int u = __builtin_bit_cast(unsigned int, x);
    unsigned int r = (u + 0x7fffu + ((u >> 16) & 1u)) >> 16;   // RNE
    return (unsigned short)r;
}
static __device__ __forceinline__ float bf2f(unsigned short h) {
    unsigned int u = ((unsigned int)h) << 16;
    return __builtin_bit_cast(float, u);
}
static __device__ __forceinline__ unsigned umin32(unsigned a, unsigned b) { return a < b ? a : b; }
static __device__ __forceinline__ unsigned umax32(unsigned a, unsigned b) { return a > b ? a : b; }
// order-preserving float->uint flip
static __device__ __forceinline__ unsigned flipf(float f) {
    unsigned u = __builtin_bit_cast(unsigned, f);
    return u ^ (0x80000000u | (unsigned)((int)u >> 31));
}
static __device__ __forceinline__ float unflipf(unsigned u) {
    unsigned m = 0x80000000u | ~((unsigned)((int)u >> 31));
    return __builtin_bit_cast(float, u ^ m);
}
static __device__ __forceinline__ unsigned packv(float v, int id) {
    return (flipf(v) & 0xFFFFFF00u) | (unsigned)id;
}
// min across 64 lanes, wave-uniform result (4x DPP row_ror + 4x readlane + 3 min)
static __device__ __forceinline__ unsigned reduceMin64(unsigned x) {
    int v = (int)x, t;
    t = __builtin_amdgcn_update_dpp(0, v, 0x121, 0xF, 0xF, true); v = (int)umin32((unsigned)v, (unsigned)t);
    t = __builtin_amdgcn_update_dpp(0, v, 0x122, 0xF, 0xF, true); v = (int)umin32((unsigned)v, (unsigned)t);
    t = __builtin_amdgcn_update_dpp(0, v, 0x124, 0xF, 0xF, true); v = (int)umin32((unsigned)v, (unsigned)t);
    t = __builtin_amdgcn_update_dpp(0, v, 0x128, 0xF, 0xF, true); v = (int)umin32((unsigned)v, (unsigned)t);
    unsigned a = (unsigned)__builtin_amdgcn_readlane(v, 0);
    unsigned b = (unsigned)__builtin_amdgcn_readlane(v, 16);
    unsigned c = (unsigned)__builtin_amdgcn_readlane(v, 32);
    unsigned d = (unsigned)__builtin_amdgcn_readlane(v, 48);
    return umin32(umin32(a, b), umin32(c, d));
}
static __device__ __forceinline__ int rlanei(int v, int l) { return __builtin_amdgcn_readlane(v, l); }
static __device__ __forceinline__ float rlanef(float v, int l) {
    return __builtin_bit_cast(float, __builtin_amdgcn_readlane(__builtin_bit_cast(int, v), l));
}
static __device__ __forceinline__ int laneOf(int id) { return id < 128 ? (id >> 1) : (id - 128); }
static __device__ __forceinline__ int slotOf(int id) { return id < 128 ? (id & 1) : 2; }
#define SEL3(s, a0, a1, a2) ((s) == 0 ? (a0) : ((s) == 1 ? (a1) : (a2)))

// ---------------- K1: norm^2 partials ----------------
__global__ void k_norm(const float* __restrict__ feat, float* __restrict__ ws) {
    int chunk = blockIdx.x;
    int b     = blockIdx.y;
    int t     = threadIdx.x;
    if (t >= Nn) return;
    const float* base = feat + ((size_t)b * Cn + (size_t)chunk * 128) * Nn + t;
    float acc = 0.f;
    #pragma unroll 4
    for (int c = 0; c < 128; ++c) { float x = base[(size_t)c * Nn]; acc = fmaf(x, x, acc); }
    ws[OFF_P + (size_t)(b * 16 + chunk) * Nn + t] = acc;
}

// ---------------- K2: per-batch stats ----------------
__global__ void k_stats(float* __restrict__ ws) {
    int b = blockIdx.x;
    int t = threadIdx.x;
    __shared__ float arr[Nn];
    __shared__ float thr;
    float norm = 0.f;
    if (t < Nn) {
        float s = 0.f;
        #pragma unroll
        for (int ch = 0; ch < 16; ++ch) s += ws[OFF_P + (size_t)(b * 16 + ch) * Nn + t];
        norm = sqrtf(s);
        arr[t] = norm;
    }
    __syncthreads();
    float mn = INFV, mx = -INFV;
    for (int k = 0; k < Nn; ++k) { float v = arr[k]; mn = fminf(mn, v); mx = fmaxf(mx, v); }
    __syncthreads();
    float mval = 0.f;
    if (t < Nn) mval = (norm - mn) / (mx - mn + 1e-12f);
    __syncthreads();
    if (t < Nn) arr[t] = mval;
    __syncthreads();
    if (t < Nn) {
        int cl = 0, ce = 0, ceb = 0;
        for (int k = 0; k < Nn; ++k) {
            float v = arr[k];
            cl  += (v <  mval);
            ce  += (v == mval);
            ceb += (v == mval && k < t);
        }
        if (cl <= Pn && (cl + ce) > Pn && ceb == 0) thr = mval;
    }
    __syncthreads();
    if (t < Nn) {
        float inv = 1.f / fmaxf(norm, 1e-12f);
        ws[OFF_KS + (size_t)b * Nn + t] = inv;
        ws[OFF_QS + (size_t)b * Nn + t] = (mval < thr) ? 0.f : inv;
    }
}

// ---------------- K3: similarity GEMM -> cost = -sim ----------------
#define BM 32
#define BN 192
#define KC 16
__global__ __launch_bounds__(256) void k_gemm(const float* __restrict__ feat,
                                              const int* __restrict__ pos_ind,
                                              float* __restrict__ ws) {
    int mt = blockIdx.x;
    int b  = blockIdx.y;
    int t  = threadIdx.x;
    int j0 = mt * BM;
    int pb = pos_ind[b];
    const float* Ag = feat + (size_t)b  * Cn * Nn;
    const float* Bg = feat + (size_t)pb * Cn * Nn;
    __shared__ float As[KC][BM];
    __shared__ float Bs[KC][BN];
    float acc[2][12];
    #pragma unroll
    for (int r = 0; r < 2; ++r)
        #pragma unroll
        for (int k = 0; k < 12; ++k) acc[r][k] = 0.f;
    int tx = t & 15, ty = t >> 4;
    for (int c0 = 0; c0 < Cn; c0 += KC) {
        #pragma unroll
        for (int r = 0; r < 2; ++r) {
            int i = t + 256 * r; int c = i >> 5, jj = i & 31;
            int j = j0 + jj;
            As[c][jj] = (j < Nn) ? Ag[(size_t)(c0 + c) * Nn + j] : 0.f;
        }
        #pragma unroll
        for (int r = 0; r < 12; ++r) {
            int i = t + 256 * r; int c = i / BN, m = i - c * BN;
            Bs[c][m] = (m < Nn) ? Bg[(size_t)(c0 + c) * Nn + m] : 0.f;
        }
        __syncthreads();
        #pragma unroll
        for (int c = 0; c < KC; ++c) {
            float2 a2 = *(const float2*)&As[c][ty * 2];
            float4 b4a = *(const float4*)&Bs[c][tx * 12];
            float4 b4b = *(const float4*)&Bs[c][tx * 12 + 4];
            float4 b4c = *(const float4*)&Bs[c][tx * 12 + 8];
            const float bv[12] = {b4a.x, b4a.y, b4a.z, b4a.w,
                                  b4b.x, b4b.y, b4b.z, b4b.w,
                                  b4c.x, b4c.y, b4c.z, b4c.w};
            #pragma unroll
            for (int k = 0; k < 12; ++k) {
                acc[0][k] = fmaf(a2.x, bv[k], acc[0][k]);
                acc[1][k] = fmaf(a2.y, bv[k], acc[1][k]);
            }
        }
        __syncthreads();
    }
    #pragma unroll
    for (int rr = 0; rr < 2; ++rr) {
        int row = j0 + ty * 2 + rr;
        if (row >= Nn) continue;
        float qs = ws[OFF_QS + (size_t)b * Nn + row];
        #pragma unroll
        for (int k = 0; k < 12; ++k) {
            int m = tx * 12 + k;
            if (m >= Nn) continue;
            float ks = ws[OFF_KS + (size_t)pb * Nn + m];
            ws[OFF_COST + ((size_t)b * Nn + row) * Nn + m] = -(acc[rr][k] * qs * ks);
        }
    }
}

// ---------------- K4: LAPJV (CR + ARR + Dijkstra), one wave per batch ----------------
// Lane owns cols id0=2*lane, id1=2*lane+1, id2=128+lane (lane<34). All dual /
// matching state in registers; cross-lane = readlane(uniform) + DPP reduce.
__global__ __launch_bounds__(64) void k_hung(float* __restrict__ ws) {
    const int b = blockIdx.x;
    const int lane = threadIdx.x;
    __shared__ unsigned short Cw[(Nn * RBW) / 2 + 32];
    __shared__ int rowBest[Nn + 1];
    __shared__ float Ulds[Nn + 1];
    const float* cg = ws + OFF_COST + (size_t)b * Nn * Nn;

    const bool v2ok = (lane < Nn - 128);     // lane < 34
    const int id0 = 2 * lane, id1 = 2 * lane + 1, id2 = 128 + lane;

    // ---- stage cost to LDS (bf16; cols 0..127 pair-packed, 128..161 u16) ----
    for (int r = 0; r < Nn; ++r) {
        float2 f2 = *(const float2*)(cg + (size_t)r * Nn + 2 * lane);
        unsigned pk = (unsigned)f2bf(f2.x) | ((unsigned)f2bf(f2.y) << 16);
        *(unsigned*)((char*)Cw + r * RBW + 4 * lane) = pk;
        if (v2ok) {
            float fx = cg[(size_t)r * Nn + 128 + lane];
            *(unsigned short*)((char*)Cw + r * RBW + 256 + 2 * lane) = f2bf(fx);
        }
    }
    for (int r = lane; r <= Nn; r += 64) { rowBest[r] = BIGI; Ulds[r] = 0.f; }
    __syncthreads();

    // ---- column reduction: v[j] = min_i c[i][j], argmin row ----
    float cm0 = INFV, cm1 = INFV, cm2 = INFV; int im0 = 1, im1 = 1, im2 = 1;
    for (int r = 0; r < Nn; ++r) {
        unsigned pr = *(const unsigned*)((const char*)Cw + r * RBW + 4 * lane);
        float c0 = bf2f((unsigned short)pr);
        float c1 = bf2f((unsigned short)(pr >> 16));
        float c2 = bf2f(*(const unsigned short*)((const char*)Cw + r * RBW + 256 + 2 * lane));
        if (c0 < cm0) { cm0 = c0; im0 = r + 1; }
        if (c1 < cm1) { cm1 = c1; im1 = r + 1; }
        if (v2ok && c2 < cm2) { cm2 = c2; im2 = r + 1; }
    }
    atomicMin(&rowBest[im0], id0);
    atomicMin(&rowBest[im1], id1);
    if (v2ok) atomicMin(&rowBest[im2], id2);
    __syncthreads();

    float v0 = cm0, v1 = cm1, v2 = v2ok ? cm2 : 0.f;
    int Pa0 = (rowBest[im0] == id0) ? im0 : 0;
    int Pa1 = (rowBest[im1] == id1) ? im1 : 0;
    int Pa2 = (v2ok && rowBest[im2] == id2) ? im2 : 0;
    float ur0 = 0.f, ur1 = 0.f, ur2 = 0.f;
    float minv0 = INFV, minv1 = INFV, minv2 = INFV;
    int way0 = 255, way1 = 255, way2 = 255;
    bool used0 = false, used1 = false, used2 = false;

    // free-row bitmasks (rows 1..162)
    unsigned long long fr0 = ~__ballot(rowBest[lane + 1] != BIGI);
    unsigned long long fr1 = ~__ballot(rowBest[lane + 65] != BIGI);
    unsigned long long fr2 = (~__ballot(v2ok ? (rowBest[lane + 129] != BIGI) : true))
                             & ((1ull << (Nn - 128)) - 1);

    // ---- ARR: 2 passes (lap.c); strict-displaced reprocess, tie-displaced defer ----
    unsigned long long nx0 = 0, nx1 = 0, nx2 = 0;
    int arrIt = 0;
    for (int pass = 0; pass < 2; ++pass) {
        while ((fr0 | fr1 | fr2) != 0 && arrIt < 2500) {
            ++arrIt;
            int i;
            if (fr0)      { int t = __builtin_ctzll(fr0); i = t + 1;   fr0 &= fr0 - 1; }
            else if (fr1) { int t = __builtin_ctzll(fr1); i = t + 65;  fr1 &= fr1 - 1; }
            else          { int t = __builtin_ctzll(fr2); i = t + 129; fr2 &= fr2 - 1; }
            int roff = (i - 1) * RBW;
            unsigned pr = *(const unsigned*)((const char*)Cw + roff + 4 * lane);
            float r0 = bf2f((unsigned short)pr) - v0;
            float r1 = bf2f((unsigned short)(pr >> 16)) - v1;
            float r2 = bf2f(*(const unsigned short*)((const char*)Cw + roff + 256 + 2 * lane)) - v2;
            unsigned p0 = packv(r0, id0);
            unsigned p1 = packv(r1, id1);
            unsigned p2 = v2ok ? packv(r2, id2) : 0xFFFFFFFFu;
            unsigned lmin = umin32(p0, umin32(p1, p2));
            unsigned lmed = umin32(umax32(p0, p1), umax32(umin32(p0, p1), p2));
            unsigned M1 = reduceMin64(lmin);
            unsigned M2 = reduceMin64(lmin == M1 ? lmed : lmin);
            int j1 = (int)(M1 & 0xFFu), j2 = (int)(M2 & 0xFFu);
            int l1 = laneOf(j1), s1 = slotOf(j1);
            int l2 = laneOf(j2), s2 = slotOf(j2);
            float umin_e = rlanef(SEL3(s1, r0, r1, r2), l1);
            float usub_e = rlanef(SEL3(s2, r0, r1, r2), l2);
            int iA = rlanei(SEL3(s1, Pa0, Pa1, Pa2), l1);
            int iB = rlanei(SEL3(s2, Pa0, Pa1, Pa2), l2);
            if (usub_e < umin_e) {   // exact-order fix for 24-bit packed argmin
                int tj = j1; j1 = j2; j2 = tj;
                int tl = l1; l1 = l2; l2 = tl;
                int ts = s1; s1 = s2; s2 = ts;
                float tv = umin_e; umin_e = usub_e; usub_e = tv;
                int ti = iA; iA = iB; iB = ti;
            }
            bool strict = (umin_e < usub_e);
            int jt, idisp;
            float ua = usub_e;
            if (strict) {
                float d = usub_e - umin_e;
                if (lane == l1) { if (s1 == 0) v0 -= d; else if (s1 == 1) v1 -= d; else v2 -= d; }
                jt = j1; idisp = iA;
            } else if (iA > 0) {
                jt = j2; idisp = iB;
            } else {
                jt = j1; idisp = 0;
            }
            int lt = laneOf(jt), st = slotOf(jt);
            if (lane == lt) {
                if (st == 0)      { Pa0 = i; ur0 = ua; }
                else if (st == 1) { Pa1 = i; ur1 = ua; }
                else              { Pa2 = i; ur2 = ua; }
            }
            if (lane == 0) Ulds[i] = ua;
            if (idisp > 0) {
                if (strict) {
                    if (idisp <= 64)       fr0 |= 1ull << (idisp - 1);
                    else if (idisp <= 128) fr1 |= 1ull << (idisp - 65);
                    else                   fr2 |= 1ull << (idisp - 129);
                } else {
                    if (idisp <= 64)       nx0 |= 1ull << (idisp - 1);
                    else if (idisp <= 128) nx1 |= 1ull << (idisp - 65);
                    else                   nx2 |= 1ull << (idisp - 129);
                }
            }
        }
        fr0 |= nx0; fr1 |= nx1; fr2 |= nx2;
        nx0 = nx1 = nx2 = 0;
    }

    // ---- Dijkstra augmentation for remaining free rows ----
    while ((fr0 | fr1 | fr2) != 0) {
        int i;
        if (fr0)      { int t = __builtin_ctzll(fr0); i = t + 1;   fr0 &= fr0 - 1; }
        else if (fr1) { int t = __builtin_ctzll(fr1); i = t + 65;  fr1 &= fr1 - 1; }
        else          { int t = __builtin_ctzll(fr2); i = t + 129; fr2 &= fr2 - 1; }
        float u_root = Ulds[i];
        minv0 = minv1 = minv2 = INFV;
        way0 = way1 = way2 = 255;
        used0 = used1 = used2 = false;
        {   // root relax
            int roff = (i - 1) * RBW;
            unsigned pr = *(const unsigned*)((const char*)Cw + roff + 4 * lane);
            float c0 = bf2f((unsigned short)pr);
            float c1 = bf2f((unsigned short)(pr >> 16));
            float c2 = bf2f(*(const unsigned short*)((const char*)Cw + roff + 256 + 2 * lane));
            minv0 = c0 - (u_root + v0);
            minv1 = c1 - (u_root + v1);
            minv2 = v2ok ? (c2 - (u_root + v2)) : INFV;
        }
        int jend = -1;
        for (int it = 0; it < Nn + 2; ++it) {
            unsigned q0 = used0 ? 0xFFFFFFFFu : packv(minv0, id0);
            unsigned q1 = used1 ? 0xFFFFFFFFu : packv(minv1, id1);
            unsigned q2 = (v2ok && !used2) ? packv(minv2, id2) : 0xFFFFFFFFu;
            unsigned pk = reduceMin64(umin32(q0, umin32(q1, q2)));
            int j1 = (int)(pk & 0xFFu);
            float delta = unflipf(pk & 0xFFFFFF00u);
            u_root += delta;
            v0 = used0 ? v0 - delta : v0;  ur0 = used0 ? ur0 + delta : ur0;  minv0 = used0 ? minv0 : minv0 - delta;
            v1 = used1 ? v1 - delta : v1;  ur1 = used1 ? ur1 + delta : ur1;  minv1 = used1 ? minv1 : minv1 - delta;
            v2 = used2 ? v2 - delta : v2;  ur2 = used2 ? ur2 + delta : ur2;  minv2 = used2 ? minv2 : minv2 - delta;
            int l1 = laneOf(j1), s1 = slotOf(j1);
            bool hit = (lane == l1);
            if (s1 == 0) used0 |= hit; else if (s1 == 1) used1 |= hit; else used2 |= hit;
            int i1 = rlanei(SEL3(s1, Pa0, Pa1, Pa2), l1);
            if (i1 == 0) { jend = j1; break; }
            float u1 = rlanef(SEL3(s1, ur0, ur1, ur2), l1);
            int roff = (i1 - 1) * RBW;
            unsigned pr = *(const unsigned*)((const char*)Cw + roff + 4 * lane);
            float c0 = bf2f((unsigned short)pr);
            float c1 = bf2f((unsigned short)(pr >> 16));
            float c2 = bf2f(*(const unsigned short*)((const char*)Cw + roff + 256 + 2 * lane));
            float n0 = c0 - (u1 + v0), n1 = c1 - (u1 + v1), n2 = c2 - (u1 + v2);
            if (!used0 && n0 < minv0) { minv0 = n0; way0 = j1; }
            if (!used1 && n1 < minv1) { minv1 = n1; way1 = j1; }
            if (v2ok && !used2 && n2 < minv2) { minv2 = n2; way2 = j1; }
        }
        int j = jend;
        while (j >= 0) {          // augment: walk predecessor chain, shift matching
            int l = laneOf(j), s = slotOf(j);
            int w = rlanei(SEL3(s, way0, way1, way2), l);
            int pnew; float unew;
            if (w == 255) { pnew = i; unew = u_root; }
            else {
                int lw = laneOf(w), sw = slotOf(w);
                pnew = rlanei(SEL3(sw, Pa0, Pa1, Pa2), lw);
                unew = rlanef(SEL3(sw, ur0, ur1, ur2), lw);
            }
            if (lane == l) {
                if (s == 0)      { Pa0 = pnew; ur0 = unew; }
                else if (s == 1) { Pa1 = pnew; ur1 = unew; }
                else             { Pa2 = pnew; ur2 = unew; }
            }
            j = (w == 255) ? -1 : w;
        }
    }

    // ---- assigned-sim sum from fp32 cost ----
    float tot = 0.f;
    if (Pa0 > 0) tot -= cg[(size_t)(Pa0 - 1) * Nn + id0];
    if (Pa1 > 0) tot -= cg[(size_t)(Pa1 - 1) * Nn + id1];
    if (v2ok && Pa2 > 0) tot -= cg[(size_t)(Pa2 - 1) * Nn + id2];
    #pragma unroll
    for (int off = 32; off; off >>= 1) tot += __shfl_xor(tot, off);
    if (lane == 0) ws[OFF_PD + b] = 1.f - tot * (1.f / (float)Pn);
}

// ---------------- K5: mean over batches ----------------
__global__ void k_final(const float* __restrict__ ws, float* __restrict__ out) {
    float v = ws[OFF_PD + threadIdx.x];
    #pragma unroll
    for (int off = 32; off; off >>= 1) v += __shfl_xor(v, off);
    if (threadIdx.x == 0) out[0] = v * (1.f / 64.f);
}

extern "C" void kernel_launch(void* const* d_in, const int* in_sizes, int n_in,
                              void* d_out, int out_size, void* d_ws, size_t ws_size,
                              hipStream_t stream) {
    const float* feat = (const float*)d_in[0];
    const int*   pos  = (const int*)d_in[1];
    float* ws  = (float*)d_ws;
    float* out = (float*)d_out;
    k_norm <<<dim3(16, 64), 192, 0, stream>>>(feat, ws);
    k_stats<<<64, 192, 0, stream>>>(ws);
    k_gemm <<<dim3(6, 64), 256, 0, stream>>>(feat, pos, ws);
    k_hung <<<64, 64, 0, stream>>>(ws);
    k_final<<<1, 64, 0, stream>>>(ws, out);
}

// Round 4
// 2525.986 us; speedup vs baseline: 4.1048x; 1.0111x over previous
//
#include <hip/hip_runtime.h>
#include <hip/hip_bf16.h>

#define Bn 64
#define Cn 2048
#define Nn 162          // H*W = 18*9
#define Pn 81           // Nn/2
#define INFV 1.0e9f
#define BIGI 0x7FFFFFFF
#define RBW 328         // LDS cost-row stride BYTES: 128 cols as u32-packed fp16 pairs (256B) + 34 u16 + pad
#define ARRCAP 700

// ws layout (in floats)
#define OFF_P    0                          // [64][16][162] norm^2 partials
#define OFF_QS   (64*16*162)                // [64][162] masked row scale (0 or 1/norm)
#define OFF_KS   (OFF_QS + 64*162)          // [64][162] col scale 1/norm
#define OFF_COST (OFF_KS + 64*162)          // [64][162][162] cost = -sim (fp32)
#define OFF_PD   (OFF_COST + 64*162*162)    // [64] per-batch pos_dis

static __device__ __forceinline__ unsigned short f2h(float x) {
    _Float16 h = (_Float16)x;                       // v_cvt_f16_f32 (RNE)
    return __builtin_bit_cast(unsigned short, h);
}
static __device__ __forceinline__ float h2f(unsigned short u) {
    return (float)__builtin_bit_cast(_Float16, u);  // v_cvt_f32_f16
}
static __device__ __forceinline__ unsigned umin32(unsigned a, unsigned b) { return a < b ? a : b; }
static __device__ __forceinline__ unsigned umax32(unsigned a, unsigned b) { return a > b ? a : b; }
// pack for NON-NEGATIVE floats: positive-float bits are order-isomorphic to uint
static __device__ __forceinline__ unsigned packnn(float v, int id) {
    float c = fmaxf(v, 0.f);
    return (__builtin_bit_cast(unsigned, c) & 0xFFFFFF00u) | (unsigned)id;
}
static __device__ __forceinline__ float unpacknn(unsigned pk) {
    return __builtin_bit_cast(float, pk & 0xFFFFFF00u);
}
// min across 64 lanes, wave-uniform result in SGPRs (4x DPP row_ror + 4x readlane + 3 s_min)
static __device__ __forceinline__ unsigned reduceMin64(unsigned x) {
    int v = (int)x, t;
    t = __builtin_amdgcn_update_dpp(0, v, 0x121, 0xF, 0xF, true); v = (int)umin32((unsigned)v, (unsigned)t);
    t = __builtin_amdgcn_update_dpp(0, v, 0x122, 0xF, 0xF, true); v = (int)umin32((unsigned)v, (unsigned)t);
    t = __builtin_amdgcn_update_dpp(0, v, 0x124, 0xF, 0xF, true); v = (int)umin32((unsigned)v, (unsigned)t);
    t = __builtin_amdgcn_update_dpp(0, v, 0x128, 0xF, 0xF, true); v = (int)umin32((unsigned)v, (unsigned)t);
    unsigned a = (unsigned)__builtin_amdgcn_readlane(v, 0);
    unsigned b = (unsigned)__builtin_amdgcn_readlane(v, 16);
    unsigned c = (unsigned)__builtin_amdgcn_readlane(v, 32);
    unsigned d = (unsigned)__builtin_amdgcn_readlane(v, 48);
    return umin32(umin32(a, b), umin32(c, d));
}
static __device__ __forceinline__ int rlanei(int v, int l) { return __builtin_amdgcn_readlane(v, l); }
static __device__ __forceinline__ float rlanef(float v, int l) {
    return __builtin_bit_cast(float, __builtin_amdgcn_readlane(__builtin_bit_cast(int, v), l));
}
static __device__ __forceinline__ int laneOf(int id) { return id < 128 ? (id >> 1) : (id - 128); }
static __device__ __forceinline__ int slotOf(int id) { return id < 128 ? (id & 1) : 2; }
#define SEL3(s, a0, a1, a2) ((s) == 0 ? (a0) : ((s) == 1 ? (a1) : (a2)))

// ---------------- K1: norm^2 partials ----------------
__global__ void k_norm(const float* __restrict__ feat, float* __restrict__ ws) {
    int chunk = blockIdx.x;
    int b     = blockIdx.y;
    int t     = threadIdx.x;
    if (t >= Nn) return;
    const float* base = feat + ((size_t)b * Cn + (size_t)chunk * 128) * Nn + t;
    float acc = 0.f;
    #pragma unroll 4
    for (int c = 0; c < 128; ++c) { float x = base[(size_t)c * Nn]; acc = fmaf(x, x, acc); }
    ws[OFF_P + (size_t)(b * 16 + chunk) * Nn + t] = acc;
}

// ---------------- K2: per-batch stats ----------------
__global__ void k_stats(float* __restrict__ ws) {
    int b = blockIdx.x;
    int t = threadIdx.x;
    __shared__ float arr[Nn];
    __shared__ float thr;
    float norm = 0.f;
    if (t < Nn) {
        float s = 0.f;
        #pragma unroll
        for (int ch = 0; ch < 16; ++ch) s += ws[OFF_P + (size_t)(b * 16 + ch) * Nn + t];
        norm = sqrtf(s);
        arr[t] = norm;
    }
    __syncthreads();
    float mn = INFV, mx = -INFV;
    for (int k = 0; k < Nn; ++k) { float v = arr[k]; mn = fminf(mn, v); mx = fmaxf(mx, v); }
    __syncthreads();
    float mval = 0.f;
    if (t < Nn) mval = (norm - mn) / (mx - mn + 1e-12f);
    __syncthreads();
    if (t < Nn) arr[t] = mval;
    __syncthreads();
    if (t < Nn) {
        int cl = 0, ce = 0, ceb = 0;
        for (int k = 0; k < Nn; ++k) {
            float v = arr[k];
            cl  += (v <  mval);
            ce  += (v == mval);
            ceb += (v == mval && k < t);
        }
        if (cl <= Pn && (cl + ce) > Pn && ceb == 0) thr = mval;
    }
    __syncthreads();
    if (t < Nn) {
        float inv = 1.f / fmaxf(norm, 1e-12f);
        ws[OFF_KS + (size_t)b * Nn + t] = inv;
        ws[OFF_QS + (size_t)b * Nn + t] = (mval < thr) ? 0.f : inv;
    }
}

// ---------------- K3: similarity GEMM -> cost = -sim ----------------
#define BM 32
#define BN 192
#define KC 16
__global__ __launch_bounds__(256) void k_gemm(const float* __restrict__ feat,
                                              const int* __restrict__ pos_ind,
                                              float* __restrict__ ws) {
    int mt = blockIdx.x;
    int b  = blockIdx.y;
    int t  = threadIdx.x;
    int j0 = mt * BM;
    int pb = pos_ind[b];
    const float* Ag = feat + (size_t)b  * Cn * Nn;
    const float* Bg = feat + (size_t)pb * Cn * Nn;
    __shared__ float As[KC][BM];
    __shared__ float Bs[KC][BN];
    float acc[2][12];
    #pragma unroll
    for (int r = 0; r < 2; ++r)
        #pragma unroll
        for (int k = 0; k < 12; ++k) acc[r][k] = 0.f;
    int tx = t & 15, ty = t >> 4;
    for (int c0 = 0; c0 < Cn; c0 += KC) {
        #pragma unroll
        for (int r = 0; r < 2; ++r) {
            int i = t + 256 * r; int c = i >> 5, jj = i & 31;
            int j = j0 + jj;
            As[c][jj] = (j < Nn) ? Ag[(size_t)(c0 + c) * Nn + j] : 0.f;
        }
        #pragma unroll
        for (int r = 0; r < 12; ++r) {
            int i = t + 256 * r; int c = i / BN, m = i - c * BN;
            Bs[c][m] = (m < Nn) ? Bg[(size_t)(c0 + c) * Nn + m] : 0.f;
        }
        __syncthreads();
        #pragma unroll
        for (int c = 0; c < KC; ++c) {
            float2 a2 = *(const float2*)&As[c][ty * 2];
            float4 b4a = *(const float4*)&Bs[c][tx * 12];
            float4 b4b = *(const float4*)&Bs[c][tx * 12 + 4];
            float4 b4c = *(const float4*)&Bs[c][tx * 12 + 8];
            const float bv[12] = {b4a.x, b4a.y, b4a.z, b4a.w,
                                  b4b.x, b4b.y, b4b.z, b4b.w,
                                  b4c.x, b4c.y, b4c.z, b4c.w};
            #pragma unroll
            for (int k = 0; k < 12; ++k) {
                acc[0][k] = fmaf(a2.x, bv[k], acc[0][k]);
                acc[1][k] = fmaf(a2.y, bv[k], acc[1][k]);
            }
        }
        __syncthreads();
    }
    #pragma unroll
    for (int rr = 0; rr < 2; ++rr) {
        int row = j0 + ty * 2 + rr;
        if (row >= Nn) continue;
        float qs = ws[OFF_QS + (size_t)b * Nn + row];
        #pragma unroll
        for (int k = 0; k < 12; ++k) {
            int m = tx * 12 + k;
            if (m >= Nn) continue;
            float ks = ws[OFF_KS + (size_t)pb * Nn + m];
            ws[OFF_COST + ((size_t)b * Nn + row) * Nn + m] = -(acc[rr][k] * qs * ks);
        }
    }
}

// ---------------- K4: LAPJV (CR + rtr + ARR + Dijkstra), one wave per batch ----------------
// Lane owns cols id0=2*lane, id1=2*lane+1, id2=128+lane (lane<34). All dual /
// matching state in registers; cross-lane = readlane(uniform) + DPP reduce.
__global__ __launch_bounds__(64) void k_hung(float* __restrict__ ws) {
    const int b = blockIdx.x;
    const int lane = threadIdx.x;
    __shared__ unsigned short Cw[(Nn * RBW) / 2 + 32];
    __shared__ int rowBest[Nn + 1];
    __shared__ float Ulds[Nn + 1];
    const float* cg = ws + OFF_COST + (size_t)b * Nn * Nn;

    const bool v2ok = (lane < Nn - 128);     // lane < 34
    const int id0 = 2 * lane, id1 = 2 * lane + 1, id2 = 128 + lane;
    const int a32 = 4 * lane;                // byte offset of this lane's packed pair
    const int a16 = 256 + 2 * lane;          // byte offset of this lane's slot-2 u16

    // ---- stage cost to LDS (fp16; cols 0..127 pair-packed, 128..161 u16) ----
    for (int r = 0; r < Nn; ++r) {
        float2 f2 = *(const float2*)(cg + (size_t)r * Nn + 2 * lane);
        unsigned pk = (unsigned)f2h(f2.x) | ((unsigned)f2h(f2.y) << 16);
        *(unsigned*)((char*)Cw + r * RBW + a32) = pk;
        if (v2ok) {
            float fx = cg[(size_t)r * Nn + 128 + lane];
            *(unsigned short*)((char*)Cw + r * RBW + a16) = f2h(fx);
        }
    }
    for (int r = lane; r <= Nn; r += 64) { rowBest[r] = BIGI; Ulds[r] = 0.f; }
    __syncthreads();

    // ---- column reduction: v[j] = min_i c[i][j], argmin row ----
    float cm0 = INFV, cm1 = INFV, cm2 = INFV; int im0 = 1, im1 = 1, im2 = 1;
    for (int r = 0; r < Nn; ++r) {
        unsigned pr = *(const unsigned*)((const char*)Cw + r * RBW + a32);
        float c0 = h2f((unsigned short)pr);
        float c1 = h2f((unsigned short)(pr >> 16));
        float c2 = h2f(*(const unsigned short*)((const char*)Cw + r * RBW + a16));
        if (c0 < cm0) { cm0 = c0; im0 = r + 1; }
        if (c1 < cm1) { cm1 = c1; im1 = r + 1; }
        if (v2ok && c2 < cm2) { cm2 = c2; im2 = r + 1; }
    }
    atomicMin(&rowBest[im0], id0);
    atomicMin(&rowBest[im1], id1);
    if (v2ok) atomicMin(&rowBest[im2], id2);
    __syncthreads();

    float v0 = cm0, v1 = cm1, v2 = v2ok ? cm2 : 0.f;
    int Pa0 = (rowBest[im0] == id0) ? im0 : 0;
    int Pa1 = (rowBest[im1] == id1) ? im1 : 0;
    int Pa2 = (v2ok && rowBest[im2] == id2) ? im2 : 0;
    float ur0 = 0.f, ur1 = 0.f, ur2 = 0.f;

    // ---- reduction transfer (lap.c rtr), old-v semantics -> independent row scans ----
    {
        float dv0 = 0.f, dv1 = 0.f, dv2 = 0.f;
        for (int r = 1; r <= Nn; ++r) {
            int j1c = rowBest[r];
            if (j1c == BIGI) continue;                 // row not CR-matched
            int roff = (r - 1) * RBW;
            unsigned pr = *(const unsigned*)((const char*)Cw + roff + a32);
            float r0 = h2f((unsigned short)pr) - v0;
            float r1 = h2f((unsigned short)(pr >> 16)) - v1;
            float r2 = h2f(*(const unsigned short*)((const char*)Cw + roff + a16)) - v2;
            unsigned p0 = (id0 == j1c) ? 0xFFFFFFFFu : packnn(r0, id0);
            unsigned p1 = (id1 == j1c) ? 0xFFFFFFFFu : packnn(r1, id1);
            unsigned p2 = (v2ok && id2 != j1c) ? packnn(r2, id2) : 0xFFFFFFFFu;
            unsigned pk = reduceMin64(umin32(p0, umin32(p1, p2)));
            float min2 = unpacknn(pk);                 // >= 0; trunc rounds down -> safe
            if (id0 == j1c) { dv0 += min2; ur0 = min2; }
            if (id1 == j1c) { dv1 += min2; ur1 = min2; }
            if (v2ok && id2 == j1c) { dv2 += min2; ur2 = min2; }
            if (lane == 0) Ulds[r] = min2;
        }
        v0 -= dv0; v1 -= dv1; v2 -= dv2;
    }

    float minv0 = INFV, minv1 = INFV, minv2 = INFV;
    int way0 = 255, way1 = 255, way2 = 255;
    bool used0 = false, used1 = false, used2 = false;

    // free-row bitmasks (rows 1..162)
    unsigned long long fr0 = ~__ballot(rowBest[lane + 1] != BIGI);
    unsigned long long fr1 = ~__ballot(rowBest[lane + 65] != BIGI);
    unsigned long long fr2 = (~__ballot(v2ok ? (rowBest[lane + 129] != BIGI) : true))
                             & ((1ull << (Nn - 128)) - 1);

    // ---- ARR: 2 passes (lap.c); strict-displaced reprocess, tie-displaced defer ----
    unsigned long long nx0 = 0, nx1 = 0, nx2 = 0;
    int arrIt = 0;
    for (int pass = 0; pass < 2; ++pass) {
        while ((fr0 | fr1 | fr2) != 0 && arrIt < ARRCAP) {
            ++arrIt;
            int i;
            if (fr0)      { int t = __builtin_ctzll(fr0); i = t + 1;   fr0 &= fr0 - 1; }
            else if (fr1) { int t = __builtin_ctzll(fr1); i = t + 65;  fr1 &= fr1 - 1; }
            else          { int t = __builtin_ctzll(fr2); i = t + 129; fr2 &= fr2 - 1; }
            int roff = (i - 1) * RBW;
            unsigned pr = *(const unsigned*)((const char*)Cw + roff + a32);
            float r0 = h2f((unsigned short)pr) - v0;
            float r1 = h2f((unsigned short)(pr >> 16)) - v1;
            float r2 = h2f(*(const unsigned short*)((const char*)Cw + roff + a16)) - v2;
            unsigned p0 = packnn(r0, id0);
            unsigned p1 = packnn(r1, id1);
            unsigned p2 = v2ok ? packnn(r2, id2) : 0xFFFFFFFFu;
            unsigned lmin = umin32(p0, umin32(p1, p2));
            unsigned lmed = umin32(umax32(p0, p1), umax32(umin32(p0, p1), p2));
            unsigned M1 = reduceMin64(lmin);
            unsigned M2 = reduceMin64(lmin == M1 ? lmed : lmin);
            int j1 = (int)(M1 & 0xFFu), j2 = (int)(M2 & 0xFFu);
            int l1 = laneOf(j1), s1 = slotOf(j1);
            int l2 = laneOf(j2), s2 = slotOf(j2);
            float umin_e = rlanef(SEL3(s1, r0, r1, r2), l1);
            float usub_e = rlanef(SEL3(s2, r0, r1, r2), l2);
            int iA = rlanei(SEL3(s1, Pa0, Pa1, Pa2), l1);
            int iB = rlanei(SEL3(s2, Pa0, Pa1, Pa2), l2);
            if (usub_e < umin_e) {   // exact-order fix for 24-bit packed argmin
                int tj = j1; j1 = j2; j2 = tj;
                int tl = l1; l1 = l2; l2 = tl;
                int ts = s1; s1 = s2; s2 = ts;
                float tv = umin_e; umin_e = usub_e; usub_e = tv;
                int ti = iA; iA = iB; iB = ti;
            }
            bool strict = (umin_e < usub_e);
            int jt, idisp;
            float ua = usub_e;
            if (strict) {
                float d = usub_e - umin_e;
                if (lane == l1) { if (s1 == 0) v0 -= d; else if (s1 == 1) v1 -= d; else v2 -= d; }
                jt = j1; idisp = iA;
            } else if (iA > 0) {
                jt = j2; idisp = iB;
            } else {
                jt = j1; idisp = 0;
            }
            int lt = laneOf(jt), st = slotOf(jt);
            if (lane == lt) {
                if (st == 0)      { Pa0 = i; ur0 = ua; }
                else if (st == 1) { Pa1 = i; ur1 = ua; }
                else              { Pa2 = i; ur2 = ua; }
            }
            if (lane == 0) Ulds[i] = ua;
            if (idisp > 0) {
                if (strict) {
                    if (idisp <= 64)       fr0 |= 1ull << (idisp - 1);
                    else if (idisp <= 128) fr1 |= 1ull << (idisp - 65);
                    else                   fr2 |= 1ull << (idisp - 129);
                } else {
                    if (idisp <= 64)       nx0 |= 1ull << (idisp - 1);
                    else if (idisp <= 128) nx1 |= 1ull << (idisp - 65);
                    else                   nx2 |= 1ull << (idisp - 129);
                }
            }
        }
        fr0 |= nx0; fr1 |= nx1; fr2 |= nx2;
        nx0 = nx1 = nx2 = 0;
    }

    // ---- Dijkstra augmentation for remaining free rows ----
    while ((fr0 | fr1 | fr2) != 0) {
        int i;
        if (fr0)      { int t = __builtin_ctzll(fr0); i = t + 1;   fr0 &= fr0 - 1; }
        else if (fr1) { int t = __builtin_ctzll(fr1); i = t + 65;  fr1 &= fr1 - 1; }
        else          { int t = __builtin_ctzll(fr2); i = t + 129; fr2 &= fr2 - 1; }
        float u_root = Ulds[i];
        minv0 = minv1 = minv2 = INFV;
        way0 = way1 = way2 = 255;
        used0 = used1 = used2 = false;
        {   // root relax
            int roff = (i - 1) * RBW;
            unsigned pr = *(const unsigned*)((const char*)Cw + roff + a32);
            float c0 = h2f((unsigned short)pr);
            float c1 = h2f((unsigned short)(pr >> 16));
            float c2 = h2f(*(const unsigned short*)((const char*)Cw + roff + a16));
            minv0 = c0 - (u_root + v0);
            minv1 = c1 - (u_root + v1);
            minv2 = v2ok ? (c2 - (u_root + v2)) : INFV;
        }
        int jend = -1;
        for (int it = 0; it < Nn + 2; ++it) {
            unsigned q0 = used0 ? 0xFFFFFFFFu : packnn(minv0, id0);
            unsigned q1 = used1 ? 0xFFFFFFFFu : packnn(minv1, id1);
            unsigned q2 = (v2ok && !used2) ? packnn(minv2, id2) : 0xFFFFFFFFu;
            unsigned pk = reduceMin64(umin32(q0, umin32(q1, q2)));
            int j1 = (int)(pk & 0xFFu);
            float delta = unpacknn(pk);
            int l1 = laneOf(j1), s1 = slotOf(j1);
            int i1 = rlanei(SEL3(s1, Pa0, Pa1, Pa2), l1);
            float u1 = rlanef(SEL3(s1, ur0, ur1, ur2), l1);
            // dual updates with OLD used set (j1 not yet marked)
            u_root += delta;
            v0 = used0 ? v0 - delta : v0;  ur0 = used0 ? ur0 + delta : ur0;  minv0 = used0 ? minv0 : minv0 - delta;
            v1 = used1 ? v1 - delta : v1;  ur1 = used1 ? ur1 + delta : ur1;  minv1 = used1 ? minv1 : minv1 - delta;
            v2 = used2 ? v2 - delta : v2;  ur2 = used2 ? ur2 + delta : ur2;  minv2 = used2 ? minv2 : minv2 - delta;
            bool hit = (lane == l1);
            if (s1 == 0) used0 |= hit; else if (s1 == 1) used1 |= hit; else used2 |= hit;
            if (i1 == 0) { jend = j1; break; }
            int roff = (i1 - 1) * RBW;
            unsigned pr = *(const unsigned*)((const char*)Cw + roff + a32);
            float c0 = h2f((unsigned short)pr);
            float c1 = h2f((unsigned short)(pr >> 16));
            float c2 = h2f(*(const unsigned short*)((const char*)Cw + roff + a16));
            float n0 = c0 - (u1 + v0), n1 = c1 - (u1 + v1), n2 = c2 - (u1 + v2);
            if (!used0 && n0 < minv0) { minv0 = n0; way0 = j1; }
            if (!used1 && n1 < minv1) { minv1 = n1; way1 = j1; }
            if (v2ok && !used2 && n2 < minv2) { minv2 = n2; way2 = j1; }
        }
        int j = jend;
        while (j >= 0) {          // augment: walk predecessor chain, shift matching
            int l = laneOf(j), s = slotOf(j);
            int w = rlanei(SEL3(s, way0, way1, way2), l);
            int pnew; float unew;
            if (w == 255) { pnew = i; unew = u_root; }
            else {
                int lw = laneOf(w), sw = slotOf(w);
                pnew = rlanei(SEL3(sw, Pa0, Pa1, Pa2), lw);
                unew = rlanef(SEL3(sw, ur0, ur1, ur2), lw);
            }
            if (lane == l) {
                if (s == 0)      { Pa0 = pnew; ur0 = unew; }
                else if (s == 1) { Pa1 = pnew; ur1 = unew; }
                else             { Pa2 = pnew; ur2 = unew; }
            }
            j = (w == 255) ? -1 : w;
        }
    }

    // ---- assigned-sim sum from fp32 cost ----
    float tot = 0.f;
    if (Pa0 > 0) tot -= cg[(size_t)(Pa0 - 1) * Nn + id0];
    if (Pa1 > 0) tot -= cg[(size_t)(Pa1 - 1) * Nn + id1];
    if (v2ok && Pa2 > 0) tot -= cg[(size_t)(Pa2 - 1) * Nn + id2];
    #pragma unroll
    for (int off = 32; off; off >>= 1) tot += __shfl_xor(tot, off);
    if (lane == 0) ws[OFF_PD + b] = 1.f - tot * (1.f / (float)Pn);
}

// ---------------- K5: mean over batches ----------------
__global__ void k_final(const float* __restrict__ ws, float* __restrict__ out) {
    float v = ws[OFF_PD + threadIdx.x];
    #pragma unroll
    for (int off = 32; off; off >>= 1) v += __shfl_xor(v, off);
    if (threadIdx.x == 0) out[0] = v * (1.f / 64.f);
}

extern "C" void kernel_launch(void* const* d_in, const int* in_sizes, int n_in,
                              void* d_out, int out_size, void* d_ws, size_t ws_size,
                              hipStream_t stream) {
    const float* feat = (const float*)d_in[0];
    const int*   pos  = (const int*)d_in[1];
    float* ws  = (float*)d_ws;
    float* out = (float*)d_out;
    k_norm <<<dim3(16, 64), 192, 0, stream>>>(feat, ws);
    k_stats<<<64, 192, 0, stream>>>(ws);
    k_gemm <<<dim3(6, 64), 256, 0, stream>>>(feat, pos, ws);
    k_hung <<<64, 64, 0, stream>>>(ws);
    k_final<<<1, 64, 0, stream>>>(ws, out);
}

// Round 5
// 681.800 us; speedup vs baseline: 15.2080x; 3.7049x over previous
//
#include <hip/hip_runtime.h>
#include <hip/hip_bf16.h>

#define Bn 64
#define Cn 2048
#define Nn 162          // H*W = 18*9
#define Pn 81           // Nn/2
#define INFV 1.0e9f
#define BIGI 0x7FFFFFFF
#define RBW 328         // LDS cost-row stride BYTES: 128 cols as u32-packed fp16 pairs (256B) + 34 u16 + pad
#define ARRCAP 700

// ws layout (in floats)
#define OFF_P    0                          // [64][16][162] norm^2 partials
#define OFF_QS   (64*16*162)                // [64][162] masked row scale (0 or 1/norm)
#define OFF_KS   (OFF_QS + 64*162)          // [64][162] col scale 1/norm
#define OFF_COST (OFF_KS + 64*162)          // [64][162][162] cost = -sim (fp32)
#define OFF_PD   (OFF_COST + 64*162*162)    // [64] per-batch pos_dis

static __device__ __forceinline__ unsigned short f2h(float x) {
    _Float16 h = (_Float16)x;                       // v_cvt_f16_f32 (RNE)
    return __builtin_bit_cast(unsigned short, h);
}
static __device__ __forceinline__ float h2f(unsigned short u) {
    return (float)__builtin_bit_cast(_Float16, u);  // v_cvt_f32_f16
}
static __device__ __forceinline__ unsigned umin32(unsigned a, unsigned b) { return a < b ? a : b; }
static __device__ __forceinline__ unsigned umax32(unsigned a, unsigned b) { return a > b ? a : b; }
// pack for NON-NEGATIVE floats: positive-float bits are order-isomorphic to uint
static __device__ __forceinline__ unsigned packnn(float v, int id) {
    float c = fmaxf(v, 0.f);
    return (__builtin_bit_cast(unsigned, c) & 0xFFFFFF00u) | (unsigned)id;
}
static __device__ __forceinline__ float unpacknn(unsigned pk) {
    return __builtin_bit_cast(float, pk & 0xFFFFFF00u);
}
// min across 64 lanes, wave-uniform result in SGPRs (4x DPP row_ror + 4x readlane + 3 s_min)
static __device__ __forceinline__ unsigned reduceMin64(unsigned x) {
    int v = (int)x, t;
    t = __builtin_amdgcn_update_dpp(0, v, 0x121, 0xF, 0xF, true); v = (int)umin32((unsigned)v, (unsigned)t);
    t = __builtin_amdgcn_update_dpp(0, v, 0x122, 0xF, 0xF, true); v = (int)umin32((unsigned)v, (unsigned)t);
    t = __builtin_amdgcn_update_dpp(0, v, 0x124, 0xF, 0xF, true); v = (int)umin32((unsigned)v, (unsigned)t);
    t = __builtin_amdgcn_update_dpp(0, v, 0x128, 0xF, 0xF, true); v = (int)umin32((unsigned)v, (unsigned)t);
    unsigned a = (unsigned)__builtin_amdgcn_readlane(v, 0);
    unsigned b = (unsigned)__builtin_amdgcn_readlane(v, 16);
    unsigned c = (unsigned)__builtin_amdgcn_readlane(v, 32);
    unsigned d = (unsigned)__builtin_amdgcn_readlane(v, 48);
    return umin32(umin32(a, b), umin32(c, d));
}
static __device__ __forceinline__ int rlanei(int v, int l) { return __builtin_amdgcn_readlane(v, l); }
static __device__ __forceinline__ float rlanef(float v, int l) {
    return __builtin_bit_cast(float, __builtin_amdgcn_readlane(__builtin_bit_cast(int, v), l));
}
static __device__ __forceinline__ int laneOf(int id) { return id < 128 ? (id >> 1) : (id - 128); }
static __device__ __forceinline__ int slotOf(int id) { return id < 128 ? (id & 1) : 2; }
#define SEL3(s, a0, a1, a2) ((s) == 0 ? (a0) : ((s) == 1 ? (a1) : (a2)))

// ---------------- K1: norm^2 partials ----------------
__global__ void k_norm(const float* __restrict__ feat, float* __restrict__ ws) {
    int chunk = blockIdx.x;
    int b     = blockIdx.y;
    int t     = threadIdx.x;
    if (t >= Nn) return;
    const float* base = feat + ((size_t)b * Cn + (size_t)chunk * 128) * Nn + t;
    float acc = 0.f;
    #pragma unroll 4
    for (int c = 0; c < 128; ++c) { float x = base[(size_t)c * Nn]; acc = fmaf(x, x, acc); }
    ws[OFF_P + (size_t)(b * 16 + chunk) * Nn + t] = acc;
}

// ---------------- K2: per-batch stats ----------------
__global__ void k_stats(float* __restrict__ ws) {
    int b = blockIdx.x;
    int t = threadIdx.x;
    __shared__ float arr[Nn];
    __shared__ float thr;
    float norm = 0.f;
    if (t < Nn) {
        float s = 0.f;
        #pragma unroll
        for (int ch = 0; ch < 16; ++ch) s += ws[OFF_P + (size_t)(b * 16 + ch) * Nn + t];
        norm = sqrtf(s);
        arr[t] = norm;
    }
    __syncthreads();
    float mn = INFV, mx = -INFV;
    for (int k = 0; k < Nn; ++k) { float v = arr[k]; mn = fminf(mn, v); mx = fmaxf(mx, v); }
    __syncthreads();
    float mval = 0.f;
    if (t < Nn) mval = (norm - mn) / (mx - mn + 1e-12f);
    __syncthreads();
    if (t < Nn) arr[t] = mval;
    __syncthreads();
    if (t < Nn) {
        int cl = 0, ce = 0, ceb = 0;
        for (int k = 0; k < Nn; ++k) {
            float v = arr[k];
            cl  += (v <  mval);
            ce  += (v == mval);
            ceb += (v == mval && k < t);
        }
        if (cl <= Pn && (cl + ce) > Pn && ceb == 0) thr = mval;
    }
    __syncthreads();
    if (t < Nn) {
        float inv = 1.f / fmaxf(norm, 1e-12f);
        ws[OFF_KS + (size_t)b * Nn + t] = inv;
        ws[OFF_QS + (size_t)b * Nn + t] = (mval < thr) ? 0.f : inv;
    }
}

// ---------------- K3: similarity GEMM -> cost = -sim ----------------
#define BM 32
#define BN 192
#define KC 16
__global__ __launch_bounds__(256) void k_gemm(const float* __restrict__ feat,
                                              const int* __restrict__ pos_ind,
                                              float* __restrict__ ws) {
    int mt = blockIdx.x;
    int b  = blockIdx.y;
    int t  = threadIdx.x;
    int j0 = mt * BM;
    int pb = pos_ind[b];
    const float* Ag = feat + (size_t)b  * Cn * Nn;
    const float* Bg = feat + (size_t)pb * Cn * Nn;
    __shared__ float As[KC][BM];
    __shared__ float Bs[KC][BN];
    float acc[2][12];
    #pragma unroll
    for (int r = 0; r < 2; ++r)
        #pragma unroll
        for (int k = 0; k < 12; ++k) acc[r][k] = 0.f;
    int tx = t & 15, ty = t >> 4;
    for (int c0 = 0; c0 < Cn; c0 += KC) {
        #pragma unroll
        for (int r = 0; r < 2; ++r) {
            int i = t + 256 * r; int c = i >> 5, jj = i & 31;
            int j = j0 + jj;
            As[c][jj] = (j < Nn) ? Ag[(size_t)(c0 + c) * Nn + j] : 0.f;
        }
        #pragma unroll
        for (int r = 0; r < 12; ++r) {
            int i = t + 256 * r; int c = i / BN, m = i - c * BN;
            Bs[c][m] = (m < Nn) ? Bg[(size_t)(c0 + c) * Nn + m] : 0.f;
        }
        __syncthreads();
        #pragma unroll
        for (int c = 0; c < KC; ++c) {
            float2 a2 = *(const float2*)&As[c][ty * 2];
            float4 b4a = *(const float4*)&Bs[c][tx * 12];
            float4 b4b = *(const float4*)&Bs[c][tx * 12 + 4];
            float4 b4c = *(const float4*)&Bs[c][tx * 12 + 8];
            const float bv[12] = {b4a.x, b4a.y, b4a.z, b4a.w,
                                  b4b.x, b4b.y, b4b.z, b4b.w,
                                  b4c.x, b4c.y, b4c.z, b4c.w};
            #pragma unroll
            for (int k = 0; k < 12; ++k) {
                acc[0][k] = fmaf(a2.x, bv[k], acc[0][k]);
                acc[1][k] = fmaf(a2.y, bv[k], acc[1][k]);
            }
        }
        __syncthreads();
    }
    #pragma unroll
    for (int rr = 0; rr < 2; ++rr) {
        int row = j0 + ty * 2 + rr;
        if (row >= Nn) continue;
        float qs = ws[OFF_QS + (size_t)b * Nn + row];
        #pragma unroll
        for (int k = 0; k < 12; ++k) {
            int m = tx * 12 + k;
            if (m >= Nn) continue;
            float ks = ws[OFF_KS + (size_t)pb * Nn + m];
            ws[OFF_COST + ((size_t)b * Nn + row) * Nn + m] = -(acc[rr][k] * qs * ks);
        }
    }
}

// ---------------- K4: rectangular LAPJV over NONZERO rows only ----------------
// Masked rows (qs==0) have cost rows == 0 exactly -> contribute 0 to the
// objective for any column -> solve ~81x162 rectangular LAP over active rows.
// Lane owns cols id0=2*lane, id1=2*lane+1, id2=128+lane (lane<34).
__global__ __launch_bounds__(64) void k_hung(float* __restrict__ ws) {
    const int b = blockIdx.x;
    const int lane = threadIdx.x;
    __shared__ unsigned short Cw[(Nn * RBW) / 2 + 32];
    __shared__ int rowBest[Nn + 1];
    __shared__ float Ulds[Nn + 1];
    const float* cg  = ws + OFF_COST + (size_t)b * Nn * Nn;
    const float* qsv = ws + OFF_QS   + (size_t)b * Nn;

    const bool v2ok = (lane < Nn - 128);     // lane < 34
    const int id0 = 2 * lane, id1 = 2 * lane + 1, id2 = 128 + lane;
    const int a32 = 4 * lane;
    const int a16 = 256 + 2 * lane;

    // ---- active-row masks (bit t of actK = 0-based row 64*K + t) ----
    float q0 = qsv[lane];
    float q1 = qsv[64 + lane];
    float q2v = v2ok ? qsv[128 + lane] : 0.f;
    unsigned long long act0 = __ballot(q0 != 0.f);
    unsigned long long act1 = __ballot(q1 != 0.f);
    unsigned long long act2 = __ballot(v2ok && q2v != 0.f);

    for (int r = lane; r <= Nn; r += 64) { rowBest[r] = BIGI; Ulds[r] = 0.f; }

    // ---- stage ACTIVE rows to LDS (fp16; cols 0..127 pair-packed, 128..161 u16) ----
#define STAGE_ROW(r) { \
        float2 f2 = *(const float2*)(cg + (size_t)(r) * Nn + 2 * lane); \
        unsigned pk = (unsigned)f2h(f2.x) | ((unsigned)f2h(f2.y) << 16); \
        *(unsigned*)((char*)Cw + (r) * RBW + a32) = pk; \
        if (v2ok) *(unsigned short*)((char*)Cw + (r) * RBW + a16) = f2h(cg[(size_t)(r) * Nn + 128 + lane]); }
    { unsigned long long m = act0;
      while (m) { int r = __builtin_ctzll(m); m &= m - 1; STAGE_ROW(r); }
      m = act1;
      while (m) { int r = 64 + __builtin_ctzll(m); m &= m - 1; STAGE_ROW(r); }
      m = act2;
      while (m) { int r = 128 + __builtin_ctzll(m); m &= m - 1; STAGE_ROW(r); } }
    __syncthreads();

    if ((act0 | act1 | act2) == 0ull) {      // no active rows: pos_dis = 1 exactly
        if (lane == 0) ws[OFF_PD + b] = 1.f;
        return;
    }

    // ---- column reduction over ACTIVE rows: v[j] = min, argmin row ----
    float cm0 = INFV, cm1 = INFV, cm2 = INFV; int im0 = 0, im1 = 0, im2 = 0;
#define CR_ROW(r) { \
        unsigned pr = *(const unsigned*)((const char*)Cw + (r) * RBW + a32); \
        float c0 = h2f((unsigned short)pr); \
        float c1 = h2f((unsigned short)(pr >> 16)); \
        float c2 = h2f(*(const unsigned short*)((const char*)Cw + (r) * RBW + a16)); \
        if (c0 < cm0) { cm0 = c0; im0 = (r) + 1; } \
        if (c1 < cm1) { cm1 = c1; im1 = (r) + 1; } \
        if (v2ok && c2 < cm2) { cm2 = c2; im2 = (r) + 1; } }
    { unsigned long long m = act0;
      while (m) { int r = __builtin_ctzll(m); m &= m - 1; CR_ROW(r); }
      m = act1;
      while (m) { int r = 64 + __builtin_ctzll(m); m &= m - 1; CR_ROW(r); }
      m = act2;
      while (m) { int r = 128 + __builtin_ctzll(m); m &= m - 1; CR_ROW(r); } }
    if (im0 > 0) atomicMin(&rowBest[im0], id0);
    if (im1 > 0) atomicMin(&rowBest[im1], id1);
    if (v2ok && im2 > 0) atomicMin(&rowBest[im2], id2);
    __syncthreads();

    float v0 = cm0, v1 = cm1, v2 = v2ok ? cm2 : 0.f;
    int Pa0 = (im0 > 0 && rowBest[im0] == id0) ? im0 : 0;
    int Pa1 = (im1 > 0 && rowBest[im1] == id1) ? im1 : 0;
    int Pa2 = (v2ok && im2 > 0 && rowBest[im2] == id2) ? im2 : 0;
    float ur0 = 0.f, ur1 = 0.f, ur2 = 0.f;

    // CR-matched / free masks (bit t = 1-based row 64*K + t + 1)
    unsigned long long cb0 = __ballot(rowBest[lane + 1] != BIGI);
    unsigned long long cb1 = __ballot(rowBest[lane + 65] != BIGI);
    unsigned long long cb2 = __ballot(v2ok && rowBest[lane + 129] != BIGI);
    unsigned long long fr0 = act0 & ~cb0;
    unsigned long long fr1 = act1 & ~cb1;
    unsigned long long fr2 = act2 & ~cb2;

    // ---- reduction transfer (lap.c rtr) over CR-matched rows, old-v semantics ----
    {
        float dv0 = 0.f, dv1 = 0.f, dv2 = 0.f;
#define RTR_ROW(rr1) { \
        int j1c = rowBest[rr1]; \
        int roff = ((rr1) - 1) * RBW; \
        unsigned pr = *(const unsigned*)((const char*)Cw + roff + a32); \
        float r0 = h2f((unsigned short)pr) - v0; \
        float r1 = h2f((unsigned short)(pr >> 16)) - v1; \
        float r2 = h2f(*(const unsigned short*)((const char*)Cw + roff + a16)) - v2; \
        unsigned p0 = (id0 == j1c) ? 0xFFFFFFFFu : packnn(r0, id0); \
        unsigned p1 = (id1 == j1c) ? 0xFFFFFFFFu : packnn(r1, id1); \
        unsigned p2 = (v2ok && id2 != j1c) ? packnn(r2, id2) : 0xFFFFFFFFu; \
        unsigned pk = reduceMin64(umin32(p0, umin32(p1, p2))); \
        float min2 = unpacknn(pk); \
        if (id0 == j1c) { dv0 += min2; ur0 = min2; } \
        if (id1 == j1c) { dv1 += min2; ur1 = min2; } \
        if (v2ok && id2 == j1c) { dv2 += min2; ur2 = min2; } \
        if (lane == 0) Ulds[rr1] = min2; }
        unsigned long long m = act0 & cb0;
        while (m) { int r = __builtin_ctzll(m) + 1; m &= m - 1; RTR_ROW(r); }
        m = act1 & cb1;
        while (m) { int r = __builtin_ctzll(m) + 65; m &= m - 1; RTR_ROW(r); }
        m = act2 & cb2;
        while (m) { int r = __builtin_ctzll(m) + 129; m &= m - 1; RTR_ROW(r); }
        v0 -= dv0; v1 -= dv1; v2 -= dv2;
    }

    float minv0 = INFV, minv1 = INFV, minv2 = INFV;
    int way0 = 255, way1 = 255, way2 = 255;
    bool used0 = false, used1 = false, used2 = false;

    // ---- ARR: 2 passes (lap.c); strict-displaced reprocess, tie-displaced defer ----
    unsigned long long nx0 = 0, nx1 = 0, nx2 = 0;
    int arrIt = 0;
    for (int pass = 0; pass < 2; ++pass) {
        while ((fr0 | fr1 | fr2) != 0 && arrIt < ARRCAP) {
            ++arrIt;
            int i;
            if (fr0)      { int t = __builtin_ctzll(fr0); i = t + 1;   fr0 &= fr0 - 1; }
            else if (fr1) { int t = __builtin_ctzll(fr1); i = t + 65;  fr1 &= fr1 - 1; }
            else          { int t = __builtin_ctzll(fr2); i = t + 129; fr2 &= fr2 - 1; }
            int roff = (i - 1) * RBW;
            unsigned pr = *(const unsigned*)((const char*)Cw + roff + a32);
            float r0 = h2f((unsigned short)pr) - v0;
            float r1 = h2f((unsigned short)(pr >> 16)) - v1;
            float r2 = h2f(*(const unsigned short*)((const char*)Cw + roff + a16)) - v2;
            unsigned p0 = packnn(r0, id0);
            unsigned p1 = packnn(r1, id1);
            unsigned p2 = v2ok ? packnn(r2, id2) : 0xFFFFFFFFu;
            unsigned lmin = umin32(p0, umin32(p1, p2));
            unsigned lmed = umin32(umax32(p0, p1), umax32(umin32(p0, p1), p2));
            unsigned M1 = reduceMin64(lmin);
            unsigned M2 = reduceMin64(lmin == M1 ? lmed : lmin);
            int j1 = (int)(M1 & 0xFFu), j2 = (int)(M2 & 0xFFu);
            int l1 = laneOf(j1), s1 = slotOf(j1);
            int l2 = laneOf(j2), s2 = slotOf(j2);
            float umin_e = rlanef(SEL3(s1, r0, r1, r2), l1);
            float usub_e = rlanef(SEL3(s2, r0, r1, r2), l2);
            int iA = rlanei(SEL3(s1, Pa0, Pa1, Pa2), l1);
            int iB = rlanei(SEL3(s2, Pa0, Pa1, Pa2), l2);
            if (usub_e < umin_e) {   // exact-order fix for 24-bit packed argmin
                int tj = j1; j1 = j2; j2 = tj;
                int tl = l1; l1 = l2; l2 = tl;
                int ts = s1; s1 = s2; s2 = ts;
                float tv = umin_e; umin_e = usub_e; usub_e = tv;
                int ti = iA; iA = iB; iB = ti;
            }
            bool strict = (umin_e < usub_e);
            int jt, idisp;
            float ua = usub_e;
            if (strict) {
                float d = usub_e - umin_e;
                if (lane == l1) { if (s1 == 0) v0 -= d; else if (s1 == 1) v1 -= d; else v2 -= d; }
                jt = j1; idisp = iA;
            } else if (iA > 0) {
                jt = j2; idisp = iB;
            } else {
                jt = j1; idisp = 0;
            }
            int lt = laneOf(jt), st = slotOf(jt);
            if (lane == lt) {
                if (st == 0)      { Pa0 = i; ur0 = ua; }
                else if (st == 1) { Pa1 = i; ur1 = ua; }
                else              { Pa2 = i; ur2 = ua; }
            }
            if (lane == 0) Ulds[i] = ua;
            if (idisp > 0) {
                if (strict) {
                    if (idisp <= 64)       fr0 |= 1ull << (idisp - 1);
                    else if (idisp <= 128) fr1 |= 1ull << (idisp - 65);
                    else                   fr2 |= 1ull << (idisp - 129);
                } else {
                    if (idisp <= 64)       nx0 |= 1ull << (idisp - 1);
                    else if (idisp <= 128) nx1 |= 1ull << (idisp - 65);
                    else                   nx2 |= 1ull << (idisp - 129);
                }
            }
        }
        fr0 |= nx0; fr1 |= nx1; fr2 |= nx2;
        nx0 = nx1 = nx2 = 0;
    }

    // ---- Dijkstra augmentation for remaining free rows ----
    while ((fr0 | fr1 | fr2) != 0) {
        int i;
        if (fr0)      { int t = __builtin_ctzll(fr0); i = t + 1;   fr0 &= fr0 - 1; }
        else if (fr1) { int t = __builtin_ctzll(fr1); i = t + 65;  fr1 &= fr1 - 1; }
        else          { int t = __builtin_ctzll(fr2); i = t + 129; fr2 &= fr2 - 1; }
        float u_root = Ulds[i];
        minv0 = minv1 = minv2 = INFV;
        way0 = way1 = way2 = 255;
        used0 = used1 = used2 = false;
        {   // root relax
            int roff = (i - 1) * RBW;
            unsigned pr = *(const unsigned*)((const char*)Cw + roff + a32);
            float c0 = h2f((unsigned short)pr);
            float c1 = h2f((unsigned short)(pr >> 16));
            float c2 = h2f(*(const unsigned short*)((const char*)Cw + roff + a16));
            minv0 = c0 - (u_root + v0);
            minv1 = c1 - (u_root + v1);
            minv2 = v2ok ? (c2 - (u_root + v2)) : INFV;
        }
        int jend = -1;
        for (int it = 0; it < Nn + 2; ++it) {
            unsigned q0p = used0 ? 0xFFFFFFFFu : packnn(minv0, id0);
            unsigned q1p = used1 ? 0xFFFFFFFFu : packnn(minv1, id1);
            unsigned q2p = (v2ok && !used2) ? packnn(minv2, id2) : 0xFFFFFFFFu;
            unsigned pk = reduceMin64(umin32(q0p, umin32(q1p, q2p)));
            int j1 = (int)(pk & 0xFFu);
            float delta = unpacknn(pk);
            int l1 = laneOf(j1), s1 = slotOf(j1);
            int i1 = rlanei(SEL3(s1, Pa0, Pa1, Pa2), l1);
            float u1 = rlanef(SEL3(s1, ur0, ur1, ur2), l1);
            // dual updates with OLD used set (j1 not yet marked)
            u_root += delta;
            v0 = used0 ? v0 - delta : v0;  ur0 = used0 ? ur0 + delta : ur0;  minv0 = used0 ? minv0 : minv0 - delta;
            v1 = used1 ? v1 - delta : v1;  ur1 = used1 ? ur1 + delta : ur1;  minv1 = used1 ? minv1 : minv1 - delta;
            v2 = used2 ? v2 - delta : v2;  ur2 = used2 ? ur2 + delta : ur2;  minv2 = used2 ? minv2 : minv2 - delta;
            bool hit = (lane == l1);
            if (s1 == 0) used0 |= hit; else if (s1 == 1) used1 |= hit; else used2 |= hit;
            if (i1 == 0) { jend = j1; break; }
            int roff = (i1 - 1) * RBW;
            unsigned pr = *(const unsigned*)((const char*)Cw + roff + a32);
            float c0 = h2f((unsigned short)pr);
            float c1 = h2f((unsigned short)(pr >> 16));
            float c2 = h2f(*(const unsigned short*)((const char*)Cw + roff + a16));
            float n0 = c0 - (u1 + v0), n1 = c1 - (u1 + v1), n2 = c2 - (u1 + v2);
            if (!used0 && n0 < minv0) { minv0 = n0; way0 = j1; }
            if (!used1 && n1 < minv1) { minv1 = n1; way1 = j1; }
            if (v2ok && !used2 && n2 < minv2) { minv2 = n2; way2 = j1; }
        }
        int j = jend;
        while (j >= 0) {          // augment: walk predecessor chain, shift matching
            int l = laneOf(j), s = slotOf(j);
            int w = rlanei(SEL3(s, way0, way1, way2), l);
            int pnew; float unew;
            if (w == 255) { pnew = i; unew = u_root; }
            else {
                int lw = laneOf(w), sw = slotOf(w);
                pnew = rlanei(SEL3(sw, Pa0, Pa1, Pa2), lw);
                unew = rlanef(SEL3(sw, ur0, ur1, ur2), lw);
            }
            if (lane == l) {
                if (s == 0)      { Pa0 = pnew; ur0 = unew; }
                else if (s == 1) { Pa1 = pnew; ur1 = unew; }
                else             { Pa2 = pnew; ur2 = unew; }
            }
            j = (w == 255) ? -1 : w;
        }
    }

    // ---- assigned-sim sum from fp32 cost (inactive rows contribute exactly 0) ----
    float tot = 0.f;
    if (Pa0 > 0) tot -= cg[(size_t)(Pa0 - 1) * Nn + id0];
    if (Pa1 > 0) tot -= cg[(size_t)(Pa1 - 1) * Nn + id1];
    if (v2ok && Pa2 > 0) tot -= cg[(size_t)(Pa2 - 1) * Nn + id2];
    #pragma unroll
    for (int off = 32; off; off >>= 1) tot += __shfl_xor(tot, off);
    if (lane == 0) ws[OFF_PD + b] = 1.f - tot * (1.f / (float)Pn);
}

// ---------------- K5: mean over batches ----------------
__global__ void k_final(const float* __restrict__ ws, float* __restrict__ out) {
    float v = ws[OFF_PD + threadIdx.x];
    #pragma unroll
    for (int off = 32; off; off >>= 1) v += __shfl_xor(v, off);
    if (threadIdx.x == 0) out[0] = v * (1.f / 64.f);
}

extern "C" void kernel_launch(void* const* d_in, const int* in_sizes, int n_in,
                              void* d_out, int out_size, void* d_ws, size_t ws_size,
                              hipStream_t stream) {
    const float* feat = (const float*)d_in[0];
    const int*   pos  = (const int*)d_in[1];
    float* ws  = (float*)d_ws;
    float* out = (float*)d_out;
    k_norm <<<dim3(16, 64), 192, 0, stream>>>(feat, ws);
    k_stats<<<64, 192, 0, stream>>>(ws);
    k_gemm <<<dim3(6, 64), 256, 0, stream>>>(feat, pos, ws);
    k_hung <<<64, 64, 0, stream>>>(ws);
    k_final<<<1, 64, 0, stream>>>(ws, out);
}

// Round 6
// 349.316 us; speedup vs baseline: 29.6831x; 1.9518x over previous
//
#include <hip/hip_runtime.h>
#include <hip/hip_bf16.h>

#define Bn 64
#define Cn 2048
#define Nn 162          // H*W = 18*9
#define Pn 81           // Nn/2
#define INFV 1.0e9f
#define BIGI 0x7FFFFFFF
#define RBW 328         // k_hung LDS cost-row stride BYTES
#define ARRCAP 700

// ws layout (in floats)
#define OFF_P    0                          // [64][16][162] norm^2 partials
#define OFF_QS   (64*16*162)                // [64][162] masked row scale (0 or 1/norm)
#define OFF_KS   (OFF_QS + 64*162)          // [64][162] col scale 1/norm
#define OFF_COST (OFF_KS + 64*162)          // [64][162][162] cost = -sim (fp32)
#define OFF_PD   (OFF_COST + 64*162*162)    // [64] per-batch pos_dis

typedef __attribute__((ext_vector_type(8))) short bf16x8;
typedef __attribute__((ext_vector_type(4))) float f32x4;
typedef __attribute__((ext_vector_type(4))) unsigned u32x4;

static __device__ __forceinline__ unsigned short f2bf(float x) {
    unsigned int u = __builtin_bit_cast(unsigned int, x);
    unsigned int r = (u + 0x7fffu + ((u >> 16) & 1u)) >> 16;   // RNE
    return (unsigned short)r;
}
static __device__ __forceinline__ unsigned short f2h(float x) {
    _Float16 h = (_Float16)x;
    return __builtin_bit_cast(unsigned short, h);
}
static __device__ __forceinline__ float h2f(unsigned short u) {
    return (float)__builtin_bit_cast(_Float16, u);
}
static __device__ __forceinline__ unsigned umin32(unsigned a, unsigned b) { return a < b ? a : b; }
static __device__ __forceinline__ unsigned umax32(unsigned a, unsigned b) { return a > b ? a : b; }
static __device__ __forceinline__ unsigned packnn(float v, int id) {
    float c = fmaxf(v, 0.f);
    return (__builtin_bit_cast(unsigned, c) & 0xFFFFFF00u) | (unsigned)id;
}
static __device__ __forceinline__ float unpacknn(unsigned pk) {
    return __builtin_bit_cast(float, pk & 0xFFFFFF00u);
}
static __device__ __forceinline__ unsigned reduceMin64(unsigned x) {
    int v = (int)x, t;
    t = __builtin_amdgcn_update_dpp(0, v, 0x121, 0xF, 0xF, true); v = (int)umin32((unsigned)v, (unsigned)t);
    t = __builtin_amdgcn_update_dpp(0, v, 0x122, 0xF, 0xF, true); v = (int)umin32((unsigned)v, (unsigned)t);
    t = __builtin_amdgcn_update_dpp(0, v, 0x124, 0xF, 0xF, true); v = (int)umin32((unsigned)v, (unsigned)t);
    t = __builtin_amdgcn_update_dpp(0, v, 0x128, 0xF, 0xF, true); v = (int)umin32((unsigned)v, (unsigned)t);
    unsigned a = (unsigned)__builtin_amdgcn_readlane(v, 0);
    unsigned b = (unsigned)__builtin_amdgcn_readlane(v, 16);
    unsigned c = (unsigned)__builtin_amdgcn_readlane(v, 32);
    unsigned d = (unsigned)__builtin_amdgcn_readlane(v, 48);
    return umin32(umin32(a, b), umin32(c, d));
}
static __device__ __forceinline__ int rlanei(int v, int l) { return __builtin_amdgcn_readlane(v, l); }
static __device__ __forceinline__ float rlanef(float v, int l) {
    return __builtin_bit_cast(float, __builtin_amdgcn_readlane(__builtin_bit_cast(int, v), l));
}
static __device__ __forceinline__ int laneOf(int id) { return id < 128 ? (id >> 1) : (id - 128); }
static __device__ __forceinline__ int slotOf(int id) { return id < 128 ? (id & 1) : 2; }
#define SEL3(s, a0, a1, a2) ((s) == 0 ? (a0) : ((s) == 1 ? (a1) : (a2)))

// ---------------- K1: norm^2 partials ----------------
__global__ void k_norm(const float* __restrict__ feat, float* __restrict__ ws) {
    int chunk = blockIdx.x;
    int b     = blockIdx.y;
    int t     = threadIdx.x;
    if (t >= Nn) return;
    const float* base = feat + ((size_t)b * Cn + (size_t)chunk * 128) * Nn + t;
    float acc = 0.f;
    #pragma unroll 4
    for (int c = 0; c < 128; ++c) { float x = base[(size_t)c * Nn]; acc = fmaf(x, x, acc); }
    ws[OFF_P + (size_t)(b * 16 + chunk) * Nn + t] = acc;
}

// ---------------- K2: per-batch stats ----------------
__global__ void k_stats(float* __restrict__ ws) {
    int b = blockIdx.x;
    int t = threadIdx.x;
    __shared__ float arr[Nn];
    __shared__ float thr;
    float norm = 0.f;
    if (t < Nn) {
        float s = 0.f;
        #pragma unroll
        for (int ch = 0; ch < 16; ++ch) s += ws[OFF_P + (size_t)(b * 16 + ch) * Nn + t];
        norm = sqrtf(s);
        arr[t] = norm;
    }
    __syncthreads();
    float mn = INFV, mx = -INFV;
    for (int k = 0; k < Nn; ++k) { float v = arr[k]; mn = fminf(mn, v); mx = fmaxf(mx, v); }
    __syncthreads();
    float mval = 0.f;
    if (t < Nn) mval = (norm - mn) / (mx - mn + 1e-12f);
    __syncthreads();
    if (t < Nn) arr[t] = mval;
    __syncthreads();
    if (t < Nn) {
        int cl = 0, ce = 0, ceb = 0;
        for (int k = 0; k < Nn; ++k) {
            float v = arr[k];
            cl  += (v <  mval);
            ce  += (v == mval);
            ceb += (v == mval && k < t);
        }
        if (cl <= Pn && (cl + ce) > Pn && ceb == 0) thr = mval;
    }
    __syncthreads();
    if (t < Nn) {
        float inv = 1.f / fmaxf(norm, 1e-12f);
        ws[OFF_KS + (size_t)b * Nn + t] = inv;
        ws[OFF_QS + (size_t)b * Nn + t] = (mval < thr) ? 0.f : inv;
    }
}

// ---------------- K3: bf16 MFMA similarity GEMM -> cost = -sim ----------------
// Grid 704 = 11 M-tiles x 64 batches, XCD-chunked (same-batch blocks share an
// XCD's L2 for B reuse). Block = 4 waves; tile 16 rows x 192 cols (12 col-tiles,
// 3 per wave). K staged 64-wide to LDS as [row][K] bf16 with XOR slot swizzle.
__global__ __launch_bounds__(256) void k_mm(const float* __restrict__ feat,
                                            const int* __restrict__ pos_ind,
                                            float* __restrict__ ws) {
    int wg = blockIdx.x;
    int xcd = wg & 7, kk = wg >> 3;
    int b  = xcd + 8 * (kk / 11);
    int mt = kk % 11;
    int tid = threadIdx.x;
    int lane = tid & 63, w = tid >> 6;
    int q0 = mt * 16;
    int pb = pos_ind[b];
    const float* Ag = feat + (size_t)b  * Cn * Nn;
    const float* Bg = feat + (size_t)pb * Cn * Nn;
    __shared__ u32x4 As4[16 * 8];      // [16 rows][8 slots of 16B]  (rows=query)
    __shared__ u32x4 Bs4[192 * 8];     // [192 rows][8 slots]        (rows=key)

    f32x4 acc0 = {0.f, 0.f, 0.f, 0.f}, acc1 = acc0, acc2 = acc0;
    const int ct0 = w * 3, ct1 = w * 3 + 1, ct2 = w * 3 + 2;   // col tiles 0..11
    const int fr = lane & 15, fq = lane >> 4;

    for (int c0 = 0; c0 < Cn; c0 += 64) {
        // ---- A stage: 16 rows x 8 octs (128 tasks) ----
        if (tid < 128) {
            int o = tid & 7, n = tid >> 3;
            int q = q0 + n;
            u32x4 v = {0u, 0u, 0u, 0u};
            if (q < Nn) {
                const float* s = Ag + (size_t)(c0 + o * 8) * Nn + q;
                float f0 = s[0],      f1 = s[Nn],     f2 = s[2 * Nn], f3 = s[3 * Nn];
                float f4 = s[4 * Nn], f5 = s[5 * Nn], f6 = s[6 * Nn], f7 = s[7 * Nn];
                v[0] = (unsigned)f2bf(f0) | ((unsigned)f2bf(f1) << 16);
                v[1] = (unsigned)f2bf(f2) | ((unsigned)f2bf(f3) << 16);
                v[2] = (unsigned)f2bf(f4) | ((unsigned)f2bf(f5) << 16);
                v[3] = (unsigned)f2bf(f6) | ((unsigned)f2bf(f7) << 16);
            }
            As4[n * 8 + (o ^ (n & 7))] = v;
        }
        // ---- B stage: 192 rows x 8 octs (1536 tasks, 6 iters) ----
        #pragma unroll
        for (int it = 0; it < 6; ++it) {
            int task = it * 256 + tid;
            int o = task & 7, n = task >> 3;       // n 0..191
            u32x4 v = {0u, 0u, 0u, 0u};
            if (n < Nn) {
                const float* s = Bg + (size_t)(c0 + o * 8) * Nn + n;
                float f0 = s[0],      f1 = s[Nn],     f2 = s[2 * Nn], f3 = s[3 * Nn];
                float f4 = s[4 * Nn], f5 = s[5 * Nn], f6 = s[6 * Nn], f7 = s[7 * Nn];
                v[0] = (unsigned)f2bf(f0) | ((unsigned)f2bf(f1) << 16);
                v[1] = (unsigned)f2bf(f2) | ((unsigned)f2bf(f3) << 16);
                v[2] = (unsigned)f2bf(f4) | ((unsigned)f2bf(f5) << 16);
                v[3] = (unsigned)f2bf(f6) | ((unsigned)f2bf(f7) << 16);
            }
            Bs4[n * 8 + (o ^ (n & 7))] = v;
        }
        __syncthreads();
        // ---- 2 k-steps of 32 ----
        #pragma unroll
        for (int ks = 0; ks < 2; ++ks) {
            int bslot = (ks * 4 + fq) ^ (fr & 7);
            bf16x8 af  = *(const bf16x8*)&As4[fr * 8 + bslot];
            bf16x8 bf0 = *(const bf16x8*)&Bs4[(ct0 * 16 + fr) * 8 + bslot];
            bf16x8 bf1 = *(const bf16x8*)&Bs4[(ct1 * 16 + fr) * 8 + bslot];
            bf16x8 bf2 = *(const bf16x8*)&Bs4[(ct2 * 16 + fr) * 8 + bslot];
            acc0 = __builtin_amdgcn_mfma_f32_16x16x32_bf16(af, bf0, acc0, 0, 0, 0);
            acc1 = __builtin_amdgcn_mfma_f32_16x16x32_bf16(af, bf1, acc1, 0, 0, 0);
            acc2 = __builtin_amdgcn_mfma_f32_16x16x32_bf16(af, bf2, acc2, 0, 0, 0);
        }
        __syncthreads();
    }

    // ---- epilogue: cost[r][c] = -(sim * qs[r] * ks[c]) ----
    const float* qsv = ws + OFF_QS + (size_t)b  * Nn;
    const float* ksv = ws + OFF_KS + (size_t)pb * Nn;
    float* cost = ws + OFF_COST + (size_t)b * Nn * Nn;
    int c0_ = ct0 * 16 + fr, c1_ = ct1 * 16 + fr, c2_ = ct2 * 16 + fr;
    float ks0 = (c0_ < Nn) ? ksv[c0_] : 0.f;
    float ks1 = (c1_ < Nn) ? ksv[c1_] : 0.f;
    float ks2 = (c2_ < Nn) ? ksv[c2_] : 0.f;
    #pragma unroll
    for (int j = 0; j < 4; ++j) {
        int r = q0 + fq * 4 + j;
        if (r < Nn) {
            float qsr = qsv[r];
            if (c0_ < Nn) cost[(size_t)r * Nn + c0_] = -(acc0[j] * qsr * ks0);
            if (c1_ < Nn) cost[(size_t)r * Nn + c1_] = -(acc1[j] * qsr * ks1);
            if (c2_ < Nn) cost[(size_t)r * Nn + c2_] = -(acc2[j] * qsr * ks2);
        }
    }
}

// ---------------- K4: rectangular LAPJV over NONZERO rows only ----------------
__global__ __launch_bounds__(64) void k_hung(float* __restrict__ ws) {
    const int b = blockIdx.x;
    const int lane = threadIdx.x;
    __shared__ unsigned short Cw[(Nn * RBW) / 2 + 32];
    __shared__ int rowBest[Nn + 1];
    __shared__ float Ulds[Nn + 1];
    const float* cg  = ws + OFF_COST + (size_t)b * Nn * Nn;
    const float* qsv = ws + OFF_QS   + (size_t)b * Nn;

    const bool v2ok = (lane < Nn - 128);     // lane < 34
    const int id0 = 2 * lane, id1 = 2 * lane + 1, id2 = 128 + lane;
    const int a32 = 4 * lane;
    const int a16 = 256 + 2 * lane;

    float q0 = qsv[lane];
    float q1 = qsv[64 + lane];
    float q2v = v2ok ? qsv[128 + lane] : 0.f;
    unsigned long long act0 = __ballot(q0 != 0.f);
    unsigned long long act1 = __ballot(q1 != 0.f);
    unsigned long long act2 = __ballot(v2ok && q2v != 0.f);

    for (int r = lane; r <= Nn; r += 64) { rowBest[r] = BIGI; Ulds[r] = 0.f; }

#define STAGE_ROW(r) { \
        float2 f2 = *(const float2*)(cg + (size_t)(r) * Nn + 2 * lane); \
        unsigned pk = (unsigned)f2h(f2.x) | ((unsigned)f2h(f2.y) << 16); \
        *(unsigned*)((char*)Cw + (r) * RBW + a32) = pk; \
        if (v2ok) *(unsigned short*)((char*)Cw + (r) * RBW + a16) = f2h(cg[(size_t)(r) * Nn + 128 + lane]); }
    { unsigned long long m = act0;
      while (m) { int r = __builtin_ctzll(m); m &= m - 1; STAGE_ROW(r); }
      m = act1;
      while (m) { int r = 64 + __builtin_ctzll(m); m &= m - 1; STAGE_ROW(r); }
      m = act2;
      while (m) { int r = 128 + __builtin_ctzll(m); m &= m - 1; STAGE_ROW(r); } }
    __syncthreads();

    if ((act0 | act1 | act2) == 0ull) {
        if (lane == 0) ws[OFF_PD + b] = 1.f;
        return;
    }

    float cm0 = INFV, cm1 = INFV, cm2 = INFV; int im0 = 0, im1 = 0, im2 = 0;
#define CR_ROW(r) { \
        unsigned pr = *(const unsigned*)((const char*)Cw + (r) * RBW + a32); \
        float c0 = h2f((unsigned short)pr); \
        float c1 = h2f((unsigned short)(pr >> 16)); \
        float c2 = h2f(*(const unsigned short*)((const char*)Cw + (r) * RBW + a16)); \
        if (c0 < cm0) { cm0 = c0; im0 = (r) + 1; } \
        if (c1 < cm1) { cm1 = c1; im1 = (r) + 1; } \
        if (v2ok && c2 < cm2) { cm2 = c2; im2 = (r) + 1; } }
    { unsigned long long m = act0;
      while (m) { int r = __builtin_ctzll(m); m &= m - 1; CR_ROW(r); }
      m = act1;
      while (m) { int r = 64 + __builtin_ctzll(m); m &= m - 1; CR_ROW(r); }
      m = act2;
      while (m) { int r = 128 + __builtin_ctzll(m); m &= m - 1; CR_ROW(r); } }
    if (im0 > 0) atomicMin(&rowBest[im0], id0);
    if (im1 > 0) atomicMin(&rowBest[im1], id1);
    if (v2ok && im2 > 0) atomicMin(&rowBest[im2], id2);
    __syncthreads();

    float v0 = cm0, v1 = cm1, v2 = v2ok ? cm2 : 0.f;
    int Pa0 = (im0 > 0 && rowBest[im0] == id0) ? im0 : 0;
    int Pa1 = (im1 > 0 && rowBest[im1] == id1) ? im1 : 0;
    int Pa2 = (v2ok && im2 > 0 && rowBest[im2] == id2) ? im2 : 0;
    float ur0 = 0.f, ur1 = 0.f, ur2 = 0.f;

    unsigned long long cb0 = __ballot(rowBest[lane + 1] != BIGI);
    unsigned long long cb1 = __ballot(rowBest[lane + 65] != BIGI);
    unsigned long long cb2 = __ballot(v2ok && rowBest[lane + 129] != BIGI);
    unsigned long long fr0 = act0 & ~cb0;
    unsigned long long fr1 = act1 & ~cb1;
    unsigned long long fr2 = act2 & ~cb2;

    {
        float dv0 = 0.f, dv1 = 0.f, dv2 = 0.f;
#define RTR_ROW(rr1) { \
        int j1c = rowBest[rr1]; \
        int roff = ((rr1) - 1) * RBW; \
        unsigned pr = *(const unsigned*)((const char*)Cw + roff + a32); \
        float r0 = h2f((unsigned short)pr) - v0; \
        float r1 = h2f((unsigned short)(pr >> 16)) - v1; \
        float r2 = h2f(*(const unsigned short*)((const char*)Cw + roff + a16)) - v2; \
        unsigned p0 = (id0 == j1c) ? 0xFFFFFFFFu : packnn(r0, id0); \
        unsigned p1 = (id1 == j1c) ? 0xFFFFFFFFu : packnn(r1, id1); \
        unsigned p2 = (v2ok && id2 != j1c) ? packnn(r2, id2) : 0xFFFFFFFFu; \
        unsigned pk = reduceMin64(umin32(p0, umin32(p1, p2))); \
        float min2 = unpacknn(pk); \
        if (id0 == j1c) { dv0 += min2; ur0 = min2; } \
        if (id1 == j1c) { dv1 += min2; ur1 = min2; } \
        if (v2ok && id2 == j1c) { dv2 += min2; ur2 = min2; } \
        if (lane == 0) Ulds[rr1] = min2; }
        unsigned long long m = act0 & cb0;
        while (m) { int r = __builtin_ctzll(m) + 1; m &= m - 1; RTR_ROW(r); }
        m = act1 & cb1;
        while (m) { int r = __builtin_ctzll(m) + 65; m &= m - 1; RTR_ROW(r); }
        m = act2 & cb2;
        while (m) { int r = __builtin_ctzll(m) + 129; m &= m - 1; RTR_ROW(r); }
        v0 -= dv0; v1 -= dv1; v2 -= dv2;
    }

    float minv0 = INFV, minv1 = INFV, minv2 = INFV;
    int way0 = 255, way1 = 255, way2 = 255;
    bool used0 = false, used1 = false, used2 = false;

    unsigned long long nx0 = 0, nx1 = 0, nx2 = 0;
    int arrIt = 0;
    for (int pass = 0; pass < 2; ++pass) {
        while ((fr0 | fr1 | fr2) != 0 && arrIt < ARRCAP) {
            ++arrIt;
            int i;
            if (fr0)      { int t = __builtin_ctzll(fr0); i = t + 1;   fr0 &= fr0 - 1; }
            else if (fr1) { int t = __builtin_ctzll(fr1); i = t + 65;  fr1 &= fr1 - 1; }
            else          { int t = __builtin_ctzll(fr2); i = t + 129; fr2 &= fr2 - 1; }
            int roff = (i - 1) * RBW;
            unsigned pr = *(const unsigned*)((const char*)Cw + roff + a32);
            float r0 = h2f((unsigned short)pr) - v0;
            float r1 = h2f((unsigned short)(pr >> 16)) - v1;
            float r2 = h2f(*(const unsigned short*)((const char*)Cw + roff + a16)) - v2;
            unsigned p0 = packnn(r0, id0);
            unsigned p1 = packnn(r1, id1);
            unsigned p2 = v2ok ? packnn(r2, id2) : 0xFFFFFFFFu;
            unsigned lmin = umin32(p0, umin32(p1, p2));
            unsigned lmed = umin32(umax32(p0, p1), umax32(umin32(p0, p1), p2));
            unsigned M1 = reduceMin64(lmin);
            unsigned M2 = reduceMin64(lmin == M1 ? lmed : lmin);
            int j1 = (int)(M1 & 0xFFu), j2 = (int)(M2 & 0xFFu);
            int l1 = laneOf(j1), s1 = slotOf(j1);
            int l2 = laneOf(j2), s2 = slotOf(j2);
            float umin_e = rlanef(SEL3(s1, r0, r1, r2), l1);
            float usub_e = rlanef(SEL3(s2, r0, r1, r2), l2);
            int iA = rlanei(SEL3(s1, Pa0, Pa1, Pa2), l1);
            int iB = rlanei(SEL3(s2, Pa0, Pa1, Pa2), l2);
            if (usub_e < umin_e) {
                int tj = j1; j1 = j2; j2 = tj;
                int tl = l1; l1 = l2; l2 = tl;
                int ts = s1; s1 = s2; s2 = ts;
                float tv = umin_e; umin_e = usub_e; usub_e = tv;
                int ti = iA; iA = iB; iB = ti;
            }
            bool strict = (umin_e < usub_e);
            int jt, idisp;
            float ua = usub_e;
            if (strict) {
                float d = usub_e - umin_e;
                if (lane == l1) { if (s1 == 0) v0 -= d; else if (s1 == 1) v1 -= d; else v2 -= d; }
                jt = j1; idisp = iA;
            } else if (iA > 0) {
                jt = j2; idisp = iB;
            } else {
                jt = j1; idisp = 0;
            }
            int lt = laneOf(jt), st = slotOf(jt);
            if (lane == lt) {
                if (st == 0)      { Pa0 = i; ur0 = ua; }
                else if (st == 1) { Pa1 = i; ur1 = ua; }
                else              { Pa2 = i; ur2 = ua; }
            }
            if (lane == 0) Ulds[i] = ua;
            if (idisp > 0) {
                if (strict) {
                    if (idisp <= 64)       fr0 |= 1ull << (idisp - 1);
                    else if (idisp <= 128) fr1 |= 1ull << (idisp - 65);
                    else                   fr2 |= 1ull << (idisp - 129);
                } else {
                    if (idisp <= 64)       nx0 |= 1ull << (idisp - 1);
                    else if (idisp <= 128) nx1 |= 1ull << (idisp - 65);
                    else                   nx2 |= 1ull << (idisp - 129);
                }
            }
        }
        fr0 |= nx0; fr1 |= nx1; fr2 |= nx2;
        nx0 = nx1 = nx2 = 0;
    }

    while ((fr0 | fr1 | fr2) != 0) {
        int i;
        if (fr0)      { int t = __builtin_ctzll(fr0); i = t + 1;   fr0 &= fr0 - 1; }
        else if (fr1) { int t = __builtin_ctzll(fr1); i = t + 65;  fr1 &= fr1 - 1; }
        else          { int t = __builtin_ctzll(fr2); i = t + 129; fr2 &= fr2 - 1; }
        float u_root = Ulds[i];
        minv0 = minv1 = minv2 = INFV;
        way0 = way1 = way2 = 255;
        used0 = used1 = used2 = false;
        {
            int roff = (i - 1) * RBW;
            unsigned pr = *(const unsigned*)((const char*)Cw + roff + a32);
            float c0 = h2f((unsigned short)pr);
            float c1 = h2f((unsigned short)(pr >> 16));
            float c2 = h2f(*(const unsigned short*)((const char*)Cw + roff + a16));
            minv0 = c0 - (u_root + v0);
            minv1 = c1 - (u_root + v1);
            minv2 = v2ok ? (c2 - (u_root + v2)) : INFV;
        }
        int jend = -1;
        for (int it = 0; it < Nn + 2; ++it) {
            unsigned q0p = used0 ? 0xFFFFFFFFu : packnn(minv0, id0);
            unsigned q1p = used1 ? 0xFFFFFFFFu : packnn(minv1, id1);
            unsigned q2p = (v2ok && !used2) ? packnn(minv2, id2) : 0xFFFFFFFFu;
            unsigned pk = reduceMin64(umin32(q0p, umin32(q1p, q2p)));
            int j1 = (int)(pk & 0xFFu);
            float delta = unpacknn(pk);
            int l1 = laneOf(j1), s1 = slotOf(j1);
            int i1 = rlanei(SEL3(s1, Pa0, Pa1, Pa2), l1);
            float u1 = rlanef(SEL3(s1, ur0, ur1, ur2), l1);
            u_root += delta;
            v0 = used0 ? v0 - delta : v0;  ur0 = used0 ? ur0 + delta : ur0;  minv0 = used0 ? minv0 : minv0 - delta;
            v1 = used1 ? v1 - delta : v1;  ur1 = used1 ? ur1 + delta : ur1;  minv1 = used1 ? minv1 : minv1 - delta;
            v2 = used2 ? v2 - delta : v2;  ur2 = used2 ? ur2 + delta : ur2;  minv2 = used2 ? minv2 : minv2 - delta;
            bool hit = (lane == l1);
            if (s1 == 0) used0 |= hit; else if (s1 == 1) used1 |= hit; else used2 |= hit;
            if (i1 == 0) { jend = j1; break; }
            int roff = (i1 - 1) * RBW;
            unsigned pr = *(const unsigned*)((const char*)Cw + roff + a32);
            float c0 = h2f((unsigned short)pr);
            float c1 = h2f((unsigned short)(pr >> 16));
            float c2 = h2f(*(const unsigned short*)((const char*)Cw + roff + a16));
            float n0 = c0 - (u1 + v0), n1 = c1 - (u1 + v1), n2 = c2 - (u1 + v2);
            if (!used0 && n0 < minv0) { minv0 = n0; way0 = j1; }
            if (!used1 && n1 < minv1) { minv1 = n1; way1 = j1; }
            if (v2ok && !used2 && n2 < minv2) { minv2 = n2; way2 = j1; }
        }
        int j = jend;
        while (j >= 0) {
            int l = laneOf(j), s = slotOf(j);
            int w = rlanei(SEL3(s, way0, way1, way2), l);
            int pnew; float unew;
            if (w == 255) { pnew = i; unew = u_root; }
            else {
                int lw = laneOf(w), sw = slotOf(w);
                pnew = rlanei(SEL3(sw, Pa0, Pa1, Pa2), lw);
                unew = rlanef(SEL3(sw, ur0, ur1, ur2), lw);
            }
            if (lane == l) {
                if (s == 0)      { Pa0 = pnew; ur0 = unew; }
                else if (s == 1) { Pa1 = pnew; ur1 = unew; }
                else             { Pa2 = pnew; ur2 = unew; }
            }
            j = (w == 255) ? -1 : w;
        }
    }

    float tot = 0.f;
    if (Pa0 > 0) tot -= cg[(size_t)(Pa0 - 1) * Nn + id0];
    if (Pa1 > 0) tot -= cg[(size_t)(Pa1 - 1) * Nn + id1];
    if (v2ok && Pa2 > 0) tot -= cg[(size_t)(Pa2 - 1) * Nn + id2];
    #pragma unroll
    for (int off = 32; off; off >>= 1) tot += __shfl_xor(tot, off);
    if (lane == 0) ws[OFF_PD + b] = 1.f - tot * (1.f / (float)Pn);
}

// ---------------- K5: mean over batches ----------------
__global__ void k_final(const float* __restrict__ ws, float* __restrict__ out) {
    float v = ws[OFF_PD + threadIdx.x];
    #pragma unroll
    for (int off = 32; off; off >>= 1) v += __shfl_xor(v, off);
    if (threadIdx.x == 0) out[0] = v * (1.f / 64.f);
}

extern "C" void kernel_launch(void* const* d_in, const int* in_sizes, int n_in,
                              void* d_out, int out_size, void* d_ws, size_t ws_size,
                              hipStream_t stream) {
    const float* feat = (const float*)d_in[0];
    const int*   pos  = (const int*)d_in[1];
    float* ws  = (float*)d_ws;
    float* out = (float*)d_out;
    k_norm <<<dim3(16, 64), 192, 0, stream>>>(feat, ws);
    k_stats<<<64, 192, 0, stream>>>(ws);
    k_mm   <<<704, 256, 0, stream>>>(feat, pos, ws);
    k_hung <<<64, 64, 0, stream>>>(ws);
    k_final<<<1, 64, 0, stream>>>(ws, out);
}

// Round 7
// 153.001 us; speedup vs baseline: 67.7695x; 2.2831x over previous
//
#include <hip/hip_runtime.h>
#include <hip/hip_bf16.h>

#define Bn 64
#define Cn 2048
#define Nn 162          // H*W = 18*9
#define Pn 81           // Nn/2
#define NP 176          // padded N for featT rows (11 tiles of 16)
#define INFV 1.0e9f
#define BIGI 0x7FFFFFFF
#define RBW 328         // k_hung LDS cost-row stride BYTES
#define ARRCAP 700

// ws layout (in floats)
#define OFF_T    0                           // bf16 featT [64][176][2048] = 11,534,336 floats
#define OFF_P    11534336                    // [64][32][192] norm^2 partials
#define OFF_QS   (OFF_P + 64*32*192)         // [64][162] masked row scale
#define OFF_KS   (OFF_QS + 64*162)           // [64][162] col scale
#define OFF_COST (OFF_KS + 64*162)           // [64][162][162] cost = -sim (fp32)
#define OFF_PD   (OFF_COST + 64*162*162)     // [64] per-batch pos_dis

typedef __attribute__((ext_vector_type(8))) short bf16x8;
typedef __attribute__((ext_vector_type(4))) float f32x4;
typedef __attribute__((ext_vector_type(4))) unsigned u32x4;

static __device__ __forceinline__ unsigned short f2bf(float x) {
    unsigned int u = __builtin_bit_cast(unsigned int, x);
    unsigned int r = (u + 0x7fffu + ((u >> 16) & 1u)) >> 16;   // RNE
    return (unsigned short)r;
}
static __device__ __forceinline__ unsigned short f2h(float x) {
    _Float16 h = (_Float16)x;
    return __builtin_bit_cast(unsigned short, h);
}
static __device__ __forceinline__ float h2f(unsigned short u) {
    return (float)__builtin_bit_cast(_Float16, u);
}
static __device__ __forceinline__ unsigned umin32(unsigned a, unsigned b) { return a < b ? a : b; }
static __device__ __forceinline__ unsigned umax32(unsigned a, unsigned b) { return a > b ? a : b; }
static __device__ __forceinline__ unsigned packnn(float v, int id) {
    float c = fmaxf(v, 0.f);
    return (__builtin_bit_cast(unsigned, c) & 0xFFFFFF00u) | (unsigned)id;
}
static __device__ __forceinline__ float unpacknn(unsigned pk) {
    return __builtin_bit_cast(float, pk & 0xFFFFFF00u);
}
static __device__ __forceinline__ unsigned reduceMin64(unsigned x) {
    int v = (int)x, t;
    t = __builtin_amdgcn_update_dpp(0, v, 0x121, 0xF, 0xF, true); v = (int)umin32((unsigned)v, (unsigned)t);
    t = __builtin_amdgcn_update_dpp(0, v, 0x122, 0xF, 0xF, true); v = (int)umin32((unsigned)v, (unsigned)t);
    t = __builtin_amdgcn_update_dpp(0, v, 0x124, 0xF, 0xF, true); v = (int)umin32((unsigned)v, (unsigned)t);
    t = __builtin_amdgcn_update_dpp(0, v, 0x128, 0xF, 0xF, true); v = (int)umin32((unsigned)v, (unsigned)t);
    unsigned a = (unsigned)__builtin_amdgcn_readlane(v, 0);
    unsigned b = (unsigned)__builtin_amdgcn_readlane(v, 16);
    unsigned c = (unsigned)__builtin_amdgcn_readlane(v, 32);
    unsigned d = (unsigned)__builtin_amdgcn_readlane(v, 48);
    return umin32(umin32(a, b), umin32(c, d));
}
static __device__ __forceinline__ int rlanei(int v, int l) { return __builtin_amdgcn_readlane(v, l); }
static __device__ __forceinline__ float rlanef(float v, int l) {
    return __builtin_bit_cast(float, __builtin_amdgcn_readlane(__builtin_bit_cast(int, v), l));
}
static __device__ __forceinline__ int laneOf(int id) { return id < 128 ? (id >> 1) : (id - 128); }
static __device__ __forceinline__ int slotOf(int id) { return id < 128 ? (id & 1) : 2; }
#define SEL3(s, a0, a1, a2) ((s) == 0 ? (a0) : ((s) == 1 ? (a1) : (a2)))

// ---------------- K1: fused transpose (fp32 [C][N] -> bf16 [NP][C]) + norm^2 partials ----------------
__global__ __launch_bounds__(256) void k_tr(const float* __restrict__ feat, float* __restrict__ ws) {
    int x = blockIdx.x;            // 0..95: cc = ch-chunk (32), ct = col-chunk (3)
    int cc = x / 3, ct = x % 3;
    int b = blockIdx.y;
    int tid = threadIdx.x;
    __shared__ float Ts[64][65];
    #pragma unroll
    for (int it = 0; it < 16; ++it) {
        int ch = it * 4 + (tid >> 6);
        int col = tid & 63;
        int gc = ct * 64 + col;
        float v = (gc < Nn) ? feat[((size_t)b * Cn + cc * 64 + ch) * Nn + gc] : 0.f;
        Ts[ch][col] = v;
    }
    __syncthreads();
    if (tid < 64) {                // norm^2 partial for this 64-ch chunk (fixed order, deterministic)
        float s = 0.f;
        #pragma unroll 8
        for (int ch = 0; ch < 64; ++ch) { float v = Ts[ch][tid]; s = fmaf(v, v, s); }
        ws[OFF_P + ((size_t)b * 32 + cc) * 192 + ct * 64 + tid] = s;
    }
    unsigned* ft = (unsigned*)(ws + OFF_T);
    #pragma unroll
    for (int it = 0; it < 8; ++it) {
        int idx = it * 256 + tid;
        int col = idx >> 5, p = idx & 31;
        int gcol = ct * 64 + col;
        if (gcol < NP) {
            unsigned lo = f2bf(Ts[2 * p][col]);
            unsigned hi = f2bf(Ts[2 * p + 1][col]);
            ft[(size_t)(b * NP + gcol) * 1024 + cc * 32 + p] = lo | (hi << 16);
        }
    }
}

// ---------------- K2: per-batch stats ----------------
__global__ void k_stats(float* __restrict__ ws) {
    int b = blockIdx.x;
    int t = threadIdx.x;
    __shared__ float arr[Nn];
    __shared__ float thr;
    float norm = 0.f;
    if (t < Nn) {
        float s = 0.f;
        #pragma unroll
        for (int ch = 0; ch < 32; ++ch) s += ws[OFF_P + ((size_t)b * 32 + ch) * 192 + t];
        norm = sqrtf(s);
        arr[t] = norm;
    }
    __syncthreads();
    float mn = INFV, mx = -INFV;
    for (int k = 0; k < Nn; ++k) { float v = arr[k]; mn = fminf(mn, v); mx = fmaxf(mx, v); }
    __syncthreads();
    float mval = 0.f;
    if (t < Nn) mval = (norm - mn) / (mx - mn + 1e-12f);
    __syncthreads();
    if (t < Nn) arr[t] = mval;
    __syncthreads();
    if (t < Nn) {
        int cl = 0, ce = 0, ceb = 0;
        for (int k = 0; k < Nn; ++k) {
            float v = arr[k];
            cl  += (v <  mval);
            ce  += (v == mval);
            ceb += (v == mval && k < t);
        }
        if (cl <= Pn && (cl + ce) > Pn && ceb == 0) thr = mval;
    }
    __syncthreads();
    if (t < Nn) {
        float inv = 1.f / fmaxf(norm, 1e-12f);
        ws[OFF_KS + (size_t)b * Nn + t] = inv;
        ws[OFF_QS + (size_t)b * Nn + t] = (mval < thr) ? 0.f : inv;
    }
}

// ---------------- K3: bf16 MFMA GEMM from featT (K-contiguous) -> cost = -sim ----------------
// Grid 704 = 11 M-tiles x 64 batches, XCD-chunked. Block 4 waves; tile 16 x 176.
// LDS [row][16 granules of 16B] with XOR swizzle g^(row&15): frag ds_read_b128 2-way max.
__global__ __launch_bounds__(256) void k_mm(const int* __restrict__ pos_ind,
                                            float* __restrict__ ws) {
    int wg = blockIdx.x;
    int xcd = wg & 7, kk = wg >> 3;
    int b  = xcd + 8 * (kk / 11);
    int mt = kk % 11;
    int tid = threadIdx.x;
    int lane = tid & 63, w = tid >> 6;
    int q0 = mt * 16;
    int pb = pos_ind[b];
    const u32x4* At = (const u32x4*)((const unsigned short*)(ws + OFF_T) + (size_t)b  * NP * Cn);
    const u32x4* Bt = (const u32x4*)((const unsigned short*)(ws + OFF_T) + (size_t)pb * NP * Cn);
    __shared__ u32x4 As[16 * 16];
    __shared__ u32x4 Bs[192 * 16];     // rows 176..191 padding (never read meaningfully)

    f32x4 acc0 = {0.f, 0.f, 0.f, 0.f}, acc1 = acc0, acc2 = acc0;
    const int ct0 = w * 3, ct1 = w * 3 + 1, ct2 = w * 3 + 2;   // col tiles 0..11 (11 invalid, guarded)
    const int fr = lane & 15, fq = lane >> 4;

    for (int c0 = 0; c0 < Cn; c0 += 128) {
        int g0 = c0 >> 3;                        // granule offset (8 ch per 16B granule)
        {   // A stage: 16 rows x 16 granules = 256 tasks
            int r = tid >> 4, g = tid & 15;
            As[r * 16 + (g ^ r)] = At[(size_t)(q0 + r) * 256 + g0 + g];
        }
        #pragma unroll
        for (int it = 0; it < 11; ++it) {        // B stage: 176 rows x 16 granules
            int task = it * 256 + tid;
            int col = task >> 4, g = task & 15;
            Bs[col * 16 + (g ^ (col & 15))] = Bt[(size_t)col * 256 + g0 + g];
        }
        __syncthreads();
        #pragma unroll
        for (int ks = 0; ks < 4; ++ks) {
            int gk = ks * 4 + fq;
            bf16x8 af = *(const bf16x8*)&As[fr * 16 + (gk ^ fr)];
            bf16x8 b0 = *(const bf16x8*)&Bs[(ct0 * 16 + fr) * 16 + (gk ^ fr)];
            bf16x8 b1 = *(const bf16x8*)&Bs[(ct1 * 16 + fr) * 16 + (gk ^ fr)];
            bf16x8 b2 = *(const bf16x8*)&Bs[(ct2 * 16 + fr) * 16 + (gk ^ fr)];
            acc0 = __builtin_amdgcn_mfma_f32_16x16x32_bf16(af, b0, acc0, 0, 0, 0);
            acc1 = __builtin_amdgcn_mfma_f32_16x16x32_bf16(af, b1, acc1, 0, 0, 0);
            acc2 = __builtin_amdgcn_mfma_f32_16x16x32_bf16(af, b2, acc2, 0, 0, 0);
        }
        __syncthreads();
    }

    // epilogue: cost[r][c] = -(sim * qs[r] * ks[c]); C/D layout col=lane&15, row=4*(lane>>4)+j
    const float* qsv = ws + OFF_QS + (size_t)b  * Nn;
    const float* ksv = ws + OFF_KS + (size_t)pb * Nn;
    float* cost = ws + OFF_COST + (size_t)b * Nn * Nn;
    int c0_ = ct0 * 16 + fr, c1_ = ct1 * 16 + fr, c2_ = ct2 * 16 + fr;
    float ks0 = (c0_ < Nn) ? ksv[c0_] : 0.f;
    float ks1 = (c1_ < Nn) ? ksv[c1_] : 0.f;
    float ks2 = (c2_ < Nn) ? ksv[c2_] : 0.f;
    #pragma unroll
    for (int j = 0; j < 4; ++j) {
        int r = q0 + fq * 4 + j;
        if (r < Nn) {
            float qsr = qsv[r];
            if (c0_ < Nn) cost[(size_t)r * Nn + c0_] = -(acc0[j] * qsr * ks0);
            if (c1_ < Nn) cost[(size_t)r * Nn + c1_] = -(acc1[j] * qsr * ks1);
            if (c2_ < Nn) cost[(size_t)r * Nn + c2_] = -(acc2[j] * qsr * ks2);
        }
    }
}

// ---------------- K4: rectangular LAPJV over NONZERO rows only ----------------
__global__ __launch_bounds__(64) void k_hung(float* __restrict__ ws) {
    const int b = blockIdx.x;
    const int lane = threadIdx.x;
    __shared__ unsigned short Cw[(Nn * RBW) / 2 + 32];
    __shared__ int rowBest[Nn + 1];
    __shared__ float Ulds[Nn + 1];
    const float* cg  = ws + OFF_COST + (size_t)b * Nn * Nn;
    const float* qsv = ws + OFF_QS   + (size_t)b * Nn;

    const bool v2ok = (lane < Nn - 128);     // lane < 34
    const int id0 = 2 * lane, id1 = 2 * lane + 1, id2 = 128 + lane;
    const int a32 = 4 * lane;
    const int a16 = 256 + 2 * lane;

    float q0 = qsv[lane];
    float q1 = qsv[64 + lane];
    float q2v = v2ok ? qsv[128 + lane] : 0.f;
    unsigned long long act0 = __ballot(q0 != 0.f);
    unsigned long long act1 = __ballot(q1 != 0.f);
    unsigned long long act2 = __ballot(v2ok && q2v != 0.f);

    for (int r = lane; r <= Nn; r += 64) { rowBest[r] = BIGI; Ulds[r] = 0.f; }

#define STAGE_ROW(r) { \
        float2 f2 = *(const float2*)(cg + (size_t)(r) * Nn + 2 * lane); \
        unsigned pk = (unsigned)f2h(f2.x) | ((unsigned)f2h(f2.y) << 16); \
        *(unsigned*)((char*)Cw + (r) * RBW + a32) = pk; \
        if (v2ok) *(unsigned short*)((char*)Cw + (r) * RBW + a16) = f2h(cg[(size_t)(r) * Nn + 128 + lane]); }
    { unsigned long long m = act0;
      while (m) { int r = __builtin_ctzll(m); m &= m - 1; STAGE_ROW(r); }
      m = act1;
      while (m) { int r = 64 + __builtin_ctzll(m); m &= m - 1; STAGE_ROW(r); }
      m = act2;
      while (m) { int r = 128 + __builtin_ctzll(m); m &= m - 1; STAGE_ROW(r); } }
    __syncthreads();

    if ((act0 | act1 | act2) == 0ull) {
        if (lane == 0) ws[OFF_PD + b] = 1.f;
        return;
    }

    float cm0 = INFV, cm1 = INFV, cm2 = INFV; int im0 = 0, im1 = 0, im2 = 0;
#define CR_ROW(r) { \
        unsigned pr = *(const unsigned*)((const char*)Cw + (r) * RBW + a32); \
        float c0 = h2f((unsigned short)pr); \
        float c1 = h2f((unsigned short)(pr >> 16)); \
        float c2 = h2f(*(const unsigned short*)((const char*)Cw + (r) * RBW + a16)); \
        if (c0 < cm0) { cm0 = c0; im0 = (r) + 1; } \
        if (c1 < cm1) { cm1 = c1; im1 = (r) + 1; } \
        if (v2ok && c2 < cm2) { cm2 = c2; im2 = (r) + 1; } }
    { unsigned long long m = act0;
      while (m) { int r = __builtin_ctzll(m); m &= m - 1; CR_ROW(r); }
      m = act1;
      while (m) { int r = 64 + __builtin_ctzll(m); m &= m - 1; CR_ROW(r); }
      m = act2;
      while (m) { int r = 128 + __builtin_ctzll(m); m &= m - 1; CR_ROW(r); } }
    if (im0 > 0) atomicMin(&rowBest[im0], id0);
    if (im1 > 0) atomicMin(&rowBest[im1], id1);
    if (v2ok && im2 > 0) atomicMin(&rowBest[im2], id2);
    __syncthreads();

    float v0 = cm0, v1 = cm1, v2 = v2ok ? cm2 : 0.f;
    int Pa0 = (im0 > 0 && rowBest[im0] == id0) ? im0 : 0;
    int Pa1 = (im1 > 0 && rowBest[im1] == id1) ? im1 : 0;
    int Pa2 = (v2ok && im2 > 0 && rowBest[im2] == id2) ? im2 : 0;
    float ur0 = 0.f, ur1 = 0.f, ur2 = 0.f;

    unsigned long long cb0 = __ballot(rowBest[lane + 1] != BIGI);
    unsigned long long cb1 = __ballot(rowBest[lane + 65] != BIGI);
    unsigned long long cb2 = __ballot(v2ok && rowBest[lane + 129] != BIGI);
    unsigned long long fr0 = act0 & ~cb0;
    unsigned long long fr1 = act1 & ~cb1;
    unsigned long long fr2 = act2 & ~cb2;

    {
        float dv0 = 0.f, dv1 = 0.f, dv2 = 0.f;
#define RTR_ROW(rr1) { \
        int j1c = rowBest[rr1]; \
        int roff = ((rr1) - 1) * RBW; \
        unsigned pr = *(const unsigned*)((const char*)Cw + roff + a32); \
        float r0 = h2f((unsigned short)pr) - v0; \
        float r1 = h2f((unsigned short)(pr >> 16)) - v1; \
        float r2 = h2f(*(const unsigned short*)((const char*)Cw + roff + a16)) - v2; \
        unsigned p0 = (id0 == j1c) ? 0xFFFFFFFFu : packnn(r0, id0); \
        unsigned p1 = (id1 == j1c) ? 0xFFFFFFFFu : packnn(r1, id1); \
        unsigned p2 = (v2ok && id2 != j1c) ? packnn(r2, id2) : 0xFFFFFFFFu; \
        unsigned pk = reduceMin64(umin32(p0, umin32(p1, p2))); \
        float min2 = unpacknn(pk); \
        if (id0 == j1c) { dv0 += min2; ur0 = min2; } \
        if (id1 == j1c) { dv1 += min2; ur1 = min2; } \
        if (v2ok && id2 == j1c) { dv2 += min2; ur2 = min2; } \
        if (lane == 0) Ulds[rr1] = min2; }
        unsigned long long m = act0 & cb0;
        while (m) { int r = __builtin_ctzll(m) + 1; m &= m - 1; RTR_ROW(r); }
        m = act1 & cb1;
        while (m) { int r = __builtin_ctzll(m) + 65; m &= m - 1; RTR_ROW(r); }
        m = act2 & cb2;
        while (m) { int r = __builtin_ctzll(m) + 129; m &= m - 1; RTR_ROW(r); }
        v0 -= dv0; v1 -= dv1; v2 -= dv2;
    }

    float minv0 = INFV, minv1 = INFV, minv2 = INFV;
    int way0 = 255, way1 = 255, way2 = 255;
    bool used0 = false, used1 = false, used2 = false;

    unsigned long long nx0 = 0, nx1 = 0, nx2 = 0;
    int arrIt = 0;
    for (int pass = 0; pass < 2; ++pass) {
        while ((fr0 | fr1 | fr2) != 0 && arrIt < ARRCAP) {
            ++arrIt;
            int i;
            if (fr0)      { int t = __builtin_ctzll(fr0); i = t + 1;   fr0 &= fr0 - 1; }
            else if (fr1) { int t = __builtin_ctzll(fr1); i = t + 65;  fr1 &= fr1 - 1; }
            else          { int t = __builtin_ctzll(fr2); i = t + 129; fr2 &= fr2 - 1; }
            int roff = (i - 1) * RBW;
            unsigned pr = *(const unsigned*)((const char*)Cw + roff + a32);
            float r0 = h2f((unsigned short)pr) - v0;
            float r1 = h2f((unsigned short)(pr >> 16)) - v1;
            float r2 = h2f(*(const unsigned short*)((const char*)Cw + roff + a16)) - v2;
            unsigned p0 = packnn(r0, id0);
            unsigned p1 = packnn(r1, id1);
            unsigned p2 = v2ok ? packnn(r2, id2) : 0xFFFFFFFFu;
            unsigned lmin = umin32(p0, umin32(p1, p2));
            unsigned lmed = umin32(umax32(p0, p1), umax32(umin32(p0, p1), p2));
            unsigned M1 = reduceMin64(lmin);
            unsigned M2 = reduceMin64(lmin == M1 ? lmed : lmin);
            int j1 = (int)(M1 & 0xFFu), j2 = (int)(M2 & 0xFFu);
            int l1 = laneOf(j1), s1 = slotOf(j1);
            int l2 = laneOf(j2), s2 = slotOf(j2);
            float umin_e = rlanef(SEL3(s1, r0, r1, r2), l1);
            float usub_e = rlanef(SEL3(s2, r0, r1, r2), l2);
            int iA = rlanei(SEL3(s1, Pa0, Pa1, Pa2), l1);
            int iB = rlanei(SEL3(s2, Pa0, Pa1, Pa2), l2);
            if (usub_e < umin_e) {
                int tj = j1; j1 = j2; j2 = tj;
                int tl = l1; l1 = l2; l2 = tl;
                int ts = s1; s1 = s2; s2 = ts;
                float tv = umin_e; umin_e = usub_e; usub_e = tv;
                int ti = iA; iA = iB; iB = ti;
            }
            bool strict = (umin_e < usub_e);
            int jt, idisp;
            float ua = usub_e;
            if (strict) {
                float d = usub_e - umin_e;
                if (lane == l1) { if (s1 == 0) v0 -= d; else if (s1 == 1) v1 -= d; else v2 -= d; }
                jt = j1; idisp = iA;
            } else if (iA > 0) {
                jt = j2; idisp = iB;
            } else {
                jt = j1; idisp = 0;
            }
            int lt = laneOf(jt), st = slotOf(jt);
            if (lane == lt) {
                if (st == 0)      { Pa0 = i; ur0 = ua; }
                else if (st == 1) { Pa1 = i; ur1 = ua; }
                else              { Pa2 = i; ur2 = ua; }
            }
            if (lane == 0) Ulds[i] = ua;
            if (idisp > 0) {
                if (strict) {
                    if (idisp <= 64)       fr0 |= 1ull << (idisp - 1);
                    else if (idisp <= 128) fr1 |= 1ull << (idisp - 65);
                    else                   fr2 |= 1ull << (idisp - 129);
                } else {
                    if (idisp <= 64)       nx0 |= 1ull << (idisp - 1);
                    else if (idisp <= 128) nx1 |= 1ull << (idisp - 65);
                    else                   nx2 |= 1ull << (idisp - 129);
                }
            }
        }
        fr0 |= nx0; fr1 |= nx1; fr2 |= nx2;
        nx0 = nx1 = nx2 = 0;
    }

    while ((fr0 | fr1 | fr2) != 0) {
        int i;
        if (fr0)      { int t = __builtin_ctzll(fr0); i = t + 1;   fr0 &= fr0 - 1; }
        else if (fr1) { int t = __builtin_ctzll(fr1); i = t + 65;  fr1 &= fr1 - 1; }
        else          { int t = __builtin_ctzll(fr2); i = t + 129; fr2 &= fr2 - 1; }
        float u_root = Ulds[i];
        minv0 = minv1 = minv2 = INFV;
        way0 = way1 = way2 = 255;
        used0 = used1 = used2 = false;
        {
            int roff = (i - 1) * RBW;
            unsigned pr = *(const unsigned*)((const char*)Cw + roff + a32);
            float c0 = h2f((unsigned short)pr);
            float c1 = h2f((unsigned short)(pr >> 16));
            float c2 = h2f(*(const unsigned short*)((const char*)Cw + roff + a16));
            minv0 = c0 - (u_root + v0);
            minv1 = c1 - (u_root + v1);
            minv2 = v2ok ? (c2 - (u_root + v2)) : INFV;
        }
        int jend = -1;
        for (int it = 0; it < Nn + 2; ++it) {
            unsigned q0p = used0 ? 0xFFFFFFFFu : packnn(minv0, id0);
            unsigned q1p = used1 ? 0xFFFFFFFFu : packnn(minv1, id1);
            unsigned q2p = (v2ok && !used2) ? packnn(minv2, id2) : 0xFFFFFFFFu;
            unsigned pk = reduceMin64(umin32(q0p, umin32(q1p, q2p)));
            int j1 = (int)(pk & 0xFFu);
            float delta = unpacknn(pk);
            int l1 = laneOf(j1), s1 = slotOf(j1);
            int i1 = rlanei(SEL3(s1, Pa0, Pa1, Pa2), l1);
            float u1 = rlanef(SEL3(s1, ur0, ur1, ur2), l1);
            u_root += delta;
            v0 = used0 ? v0 - delta : v0;  ur0 = used0 ? ur0 + delta : ur0;  minv0 = used0 ? minv0 : minv0 - delta;
            v1 = used1 ? v1 - delta : v1;  ur1 = used1 ? ur1 + delta : ur1;  minv1 = used1 ? minv1 : minv1 - delta;
            v2 = used2 ? v2 - delta : v2;  ur2 = used2 ? ur2 + delta : ur2;  minv2 = used2 ? minv2 : minv2 - delta;
            bool hit = (lane == l1);
            if (s1 == 0) used0 |= hit; else if (s1 == 1) used1 |= hit; else used2 |= hit;
            if (i1 == 0) { jend = j1; break; }
            int roff = (i1 - 1) * RBW;
            unsigned pr = *(const unsigned*)((const char*)Cw + roff + a32);
            float c0 = h2f((unsigned short)pr);
            float c1 = h2f((unsigned short)(pr >> 16));
            float c2 = h2f(*(const unsigned short*)((const char*)Cw + roff + a16));
            float n0 = c0 - (u1 + v0), n1 = c1 - (u1 + v1), n2 = c2 - (u1 + v2);
            if (!used0 && n0 < minv0) { minv0 = n0; way0 = j1; }
            if (!used1 && n1 < minv1) { minv1 = n1; way1 = j1; }
            if (v2ok && !used2 && n2 < minv2) { minv2 = n2; way2 = j1; }
        }
        int j = jend;
        while (j >= 0) {
            int l = laneOf(j), s = slotOf(j);
            int w = rlanei(SEL3(s, way0, way1, way2), l);
            int pnew; float unew;
            if (w == 255) { pnew = i; unew = u_root; }
            else {
                int lw = laneOf(w), sw = slotOf(w);
                pnew = rlanei(SEL3(sw, Pa0, Pa1, Pa2), lw);
                unew = rlanef(SEL3(sw, ur0, ur1, ur2), lw);
            }
            if (lane == l) {
                if (s == 0)      { Pa0 = pnew; ur0 = unew; }
                else if (s == 1) { Pa1 = pnew; ur1 = unew; }
                else             { Pa2 = pnew; ur2 = unew; }
            }
            j = (w == 255) ? -1 : w;
        }
    }

    float tot = 0.f;
    if (Pa0 > 0) tot -= cg[(size_t)(Pa0 - 1) * Nn + id0];
    if (Pa1 > 0) tot -= cg[(size_t)(Pa1 - 1) * Nn + id1];
    if (v2ok && Pa2 > 0) tot -= cg[(size_t)(Pa2 - 1) * Nn + id2];
    #pragma unroll
    for (int off = 32; off; off >>= 1) tot += __shfl_xor(tot, off);
    if (lane == 0) ws[OFF_PD + b] = 1.f - tot * (1.f / (float)Pn);
}

// ---------------- K5: mean over batches ----------------
__global__ void k_final(const float* __restrict__ ws, float* __restrict__ out) {
    float v = ws[OFF_PD + threadIdx.x];
    #pragma unroll
    for (int off = 32; off; off >>= 1) v += __shfl_xor(v, off);
    if (threadIdx.x == 0) out[0] = v * (1.f / 64.f);
}

extern "C" void kernel_launch(void* const* d_in, const int* in_sizes, int n_in,
                              void* d_out, int out_size, void* d_ws, size_t ws_size,
                              hipStream_t stream) {
    const float* feat = (const float*)d_in[0];
    const int*   pos  = (const int*)d_in[1];
    float* ws  = (float*)d_ws;
    float* out = (float*)d_out;
    k_tr   <<<dim3(96, 64), 256, 0, stream>>>(feat, ws);
    k_stats<<<64, 192, 0, stream>>>(ws);
    k_mm   <<<704, 256, 0, stream>>>(pos, ws);
    k_hung <<<64, 64, 0, stream>>>(ws);
    k_final<<<1, 64, 0, stream>>>(ws, out);
}

// Round 8
// 112.305 us; speedup vs baseline: 92.3266x; 1.3624x over previous
//
#include <hip/hip_runtime.h>
#include <hip/hip_bf16.h>

#define Bn 64
#define Cn 2048
#define Nn 162          // H*W = 18*9
#define Pn 81           // Nn/2
#define NP 176          // padded N for featT rows (11 tiles of 16)
#define INFV 1.0e9f
#define BIGI 0x7FFFFFFF
#define RBW 328         // k_hung LDS cost-row stride BYTES
#define ARRCAP 700

// ws layout (in floats)
#define OFF_T    0                           // bf16 featT [64][176][2048] = 11,534,336 floats
#define OFF_P    11534336                    // [64][32][192] norm^2 partials
#define OFF_QS   (OFF_P + 64*32*192)         // [64][162] masked row scale
#define OFF_KS   (OFF_QS + 64*162)           // [64][162] col scale
#define OFF_COST (OFF_KS + 64*162)           // [64][162][162] cost = -sim (fp32)
#define OFF_PD   (OFF_COST + 64*162*162)     // [64] per-batch pos_dis

typedef __attribute__((ext_vector_type(8))) short bf16x8;
typedef __attribute__((ext_vector_type(4))) float f32x4;
typedef __attribute__((ext_vector_type(4))) unsigned u32x4;

static __device__ __forceinline__ unsigned short f2bf(float x) {
    unsigned int u = __builtin_bit_cast(unsigned int, x);
    unsigned int r = (u + 0x7fffu + ((u >> 16) & 1u)) >> 16;   // RNE
    return (unsigned short)r;
}
static __device__ __forceinline__ unsigned short f2h(float x) {
    _Float16 h = (_Float16)x;
    return __builtin_bit_cast(unsigned short, h);
}
static __device__ __forceinline__ float h2f(unsigned short u) {
    return (float)__builtin_bit_cast(_Float16, u);
}
static __device__ __forceinline__ unsigned umin32(unsigned a, unsigned b) { return a < b ? a : b; }
static __device__ __forceinline__ unsigned umax32(unsigned a, unsigned b) { return a > b ? a : b; }
static __device__ __forceinline__ unsigned packnn(float v, int id) {
    float c = fmaxf(v, 0.f);
    return (__builtin_bit_cast(unsigned, c) & 0xFFFFFF00u) | (unsigned)id;
}
static __device__ __forceinline__ float unpacknn(unsigned pk) {
    return __builtin_bit_cast(float, pk & 0xFFFFFF00u);
}
static __device__ __forceinline__ unsigned reduceMin64(unsigned x) {
    int v = (int)x, t;
    t = __builtin_amdgcn_update_dpp(0, v, 0x121, 0xF, 0xF, true); v = (int)umin32((unsigned)v, (unsigned)t);
    t = __builtin_amdgcn_update_dpp(0, v, 0x122, 0xF, 0xF, true); v = (int)umin32((unsigned)v, (unsigned)t);
    t = __builtin_amdgcn_update_dpp(0, v, 0x124, 0xF, 0xF, true); v = (int)umin32((unsigned)v, (unsigned)t);
    t = __builtin_amdgcn_update_dpp(0, v, 0x128, 0xF, 0xF, true); v = (int)umin32((unsigned)v, (unsigned)t);
    unsigned a = (unsigned)__builtin_amdgcn_readlane(v, 0);
    unsigned b = (unsigned)__builtin_amdgcn_readlane(v, 16);
    unsigned c = (unsigned)__builtin_amdgcn_readlane(v, 32);
    unsigned d = (unsigned)__builtin_amdgcn_readlane(v, 48);
    return umin32(umin32(a, b), umin32(c, d));
}
static __device__ __forceinline__ int rlanei(int v, int l) { return __builtin_amdgcn_readlane(v, l); }
static __device__ __forceinline__ float rlanef(float v, int l) {
    return __builtin_bit_cast(float, __builtin_amdgcn_readlane(__builtin_bit_cast(int, v), l));
}
static __device__ __forceinline__ int laneOf(int id) { return id < 128 ? (id >> 1) : (id - 128); }
static __device__ __forceinline__ int slotOf(int id) { return id < 128 ? (id & 1) : 2; }
static __device__ __forceinline__ unsigned long long mask_n(int n) {
    if (n <= 0) return 0ull;
    if (n >= 64) return ~0ull;
    return (1ull << n) - 1ull;
}
#define SEL3(s, a0, a1, a2) ((s) == 0 ? (a0) : ((s) == 1 ? (a1) : (a2)))

// ---------------- K1: fused transpose (fp32 [C][N] -> bf16 [NP][C]) + norm^2 partials ----------------
__global__ __launch_bounds__(256) void k_tr(const float* __restrict__ feat, float* __restrict__ ws) {
    int x = blockIdx.x;            // 0..95: cc = ch-chunk (32), ct = col-chunk (3)
    int cc = x / 3, ct = x % 3;
    int b = blockIdx.y;
    int tid = threadIdx.x;
    __shared__ float Ts[64][65];
    #pragma unroll
    for (int it = 0; it < 16; ++it) {
        int ch = it * 4 + (tid >> 6);
        int col = tid & 63;
        int gc = ct * 64 + col;
        float v = (gc < Nn) ? feat[((size_t)b * Cn + cc * 64 + ch) * Nn + gc] : 0.f;
        Ts[ch][col] = v;
    }
    __syncthreads();
    if (tid < 64) {
        float s = 0.f;
        #pragma unroll 8
        for (int ch = 0; ch < 64; ++ch) { float v = Ts[ch][tid]; s = fmaf(v, v, s); }
        ws[OFF_P + ((size_t)b * 32 + cc) * 192 + ct * 64 + tid] = s;
    }
    unsigned* ft = (unsigned*)(ws + OFF_T);
    #pragma unroll
    for (int it = 0; it < 8; ++it) {
        int idx = it * 256 + tid;
        int col = idx >> 5, p = idx & 31;
        int gcol = ct * 64 + col;
        if (gcol < NP) {
            unsigned lo = f2bf(Ts[2 * p][col]);
            unsigned hi = f2bf(Ts[2 * p + 1][col]);
            ft[(size_t)(b * NP + gcol) * 1024 + cc * 32 + p] = lo | (hi << 16);
        }
    }
}

// ---------------- K2: per-batch stats ----------------
__global__ void k_stats(float* __restrict__ ws) {
    int b = blockIdx.x;
    int t = threadIdx.x;
    __shared__ float arr[Nn];
    __shared__ float thr;
    float norm = 0.f;
    if (t < Nn) {
        float s = 0.f;
        #pragma unroll
        for (int ch = 0; ch < 32; ++ch) s += ws[OFF_P + ((size_t)b * 32 + ch) * 192 + t];
        norm = sqrtf(s);
        arr[t] = norm;
    }
    __syncthreads();
    float mn = INFV, mx = -INFV;
    for (int k = 0; k < Nn; ++k) { float v = arr[k]; mn = fminf(mn, v); mx = fmaxf(mx, v); }
    __syncthreads();
    float mval = 0.f;
    if (t < Nn) mval = (norm - mn) / (mx - mn + 1e-12f);
    __syncthreads();
    if (t < Nn) arr[t] = mval;
    __syncthreads();
    if (t < Nn) {
        int cl = 0, ce = 0, ceb = 0;
        for (int k = 0; k < Nn; ++k) {
            float v = arr[k];
            cl  += (v <  mval);
            ce  += (v == mval);
            ceb += (v == mval && k < t);
        }
        if (cl <= Pn && (cl + ce) > Pn && ceb == 0) thr = mval;
    }
    __syncthreads();
    if (t < Nn) {
        float inv = 1.f / fmaxf(norm, 1e-12f);
        ws[OFF_KS + (size_t)b * Nn + t] = inv;
        ws[OFF_QS + (size_t)b * Nn + t] = (mval < thr) ? 0.f : inv;
    }
}

// ---------------- K3: bf16 MFMA GEMM from featT (K-contiguous) -> cost = -sim ----------------
__global__ __launch_bounds__(256) void k_mm(const int* __restrict__ pos_ind,
                                            float* __restrict__ ws) {
    int wg = blockIdx.x;
    int xcd = wg & 7, kk = wg >> 3;
    int b  = xcd + 8 * (kk / 11);
    int mt = kk % 11;
    int tid = threadIdx.x;
    int lane = tid & 63, w = tid >> 6;
    int q0 = mt * 16;
    int pb = pos_ind[b];
    const u32x4* At = (const u32x4*)((const unsigned short*)(ws + OFF_T) + (size_t)b  * NP * Cn);
    const u32x4* Bt = (const u32x4*)((const unsigned short*)(ws + OFF_T) + (size_t)pb * NP * Cn);
    __shared__ u32x4 As[16 * 16];
    __shared__ u32x4 Bs[192 * 16];

    f32x4 acc0 = {0.f, 0.f, 0.f, 0.f}, acc1 = acc0, acc2 = acc0;
    const int ct0 = w * 3, ct1 = w * 3 + 1, ct2 = w * 3 + 2;
    const int fr = lane & 15, fq = lane >> 4;

    for (int c0 = 0; c0 < Cn; c0 += 128) {
        int g0 = c0 >> 3;
        {
            int r = tid >> 4, g = tid & 15;
            As[r * 16 + (g ^ r)] = At[(size_t)(q0 + r) * 256 + g0 + g];
        }
        #pragma unroll
        for (int it = 0; it < 11; ++it) {
            int task = it * 256 + tid;
            int col = task >> 4, g = task & 15;
            Bs[col * 16 + (g ^ (col & 15))] = Bt[(size_t)col * 256 + g0 + g];
        }
        __syncthreads();
        #pragma unroll
        for (int ks = 0; ks < 4; ++ks) {
            int gk = ks * 4 + fq;
            bf16x8 af = *(const bf16x8*)&As[fr * 16 + (gk ^ fr)];
            bf16x8 b0 = *(const bf16x8*)&Bs[(ct0 * 16 + fr) * 16 + (gk ^ fr)];
            bf16x8 b1 = *(const bf16x8*)&Bs[(ct1 * 16 + fr) * 16 + (gk ^ fr)];
            bf16x8 b2 = *(const bf16x8*)&Bs[(ct2 * 16 + fr) * 16 + (gk ^ fr)];
            acc0 = __builtin_amdgcn_mfma_f32_16x16x32_bf16(af, b0, acc0, 0, 0, 0);
            acc1 = __builtin_amdgcn_mfma_f32_16x16x32_bf16(af, b1, acc1, 0, 0, 0);
            acc2 = __builtin_amdgcn_mfma_f32_16x16x32_bf16(af, b2, acc2, 0, 0, 0);
        }
        __syncthreads();
    }

    const float* qsv = ws + OFF_QS + (size_t)b  * Nn;
    const float* ksv = ws + OFF_KS + (size_t)pb * Nn;
    float* cost = ws + OFF_COST + (size_t)b * Nn * Nn;
    int c0_ = ct0 * 16 + fr, c1_ = ct1 * 16 + fr, c2_ = ct2 * 16 + fr;
    float ks0 = (c0_ < Nn) ? ksv[c0_] : 0.f;
    float ks1 = (c1_ < Nn) ? ksv[c1_] : 0.f;
    float ks2 = (c2_ < Nn) ? ksv[c2_] : 0.f;
    #pragma unroll
    for (int j = 0; j < 4; ++j) {
        int r = q0 + fq * 4 + j;
        if (r < Nn) {
            float qsr = qsv[r];
            if (c0_ < Nn) cost[(size_t)r * Nn + c0_] = -(acc0[j] * qsr * ks0);
            if (c1_ < Nn) cost[(size_t)r * Nn + c1_] = -(acc1[j] * qsr * ks1);
            if (c2_ < Nn) cost[(size_t)r * Nn + c2_] = -(acc2[j] * qsr * ks2);
        }
    }
}

// ---------------- K4: rectangular LAPJV, 4 waves: parallel stage/CR/RTR, serial ARR/Dijkstra ----------------
// Active rows packed densely (packed order = original order). Wave w handles
// packed rows k%4==w for staging/CR/RTR; wave 0 runs ARR+Dijkstra alone.
__global__ __launch_bounds__(256) void k_hung(float* __restrict__ ws) {
    const int b = blockIdx.x;
    const int tid = threadIdx.x;
    const int lane = tid & 63, wv = tid >> 6;
    __shared__ unsigned short Cw[(Nn * RBW) / 2 + 32];
    __shared__ int rowBest[Nn + 1];
    __shared__ float Ulds[Nn + 1];
    __shared__ float dvA[192];
    __shared__ float pcm[4][192];
    __shared__ int   pim[4][192];
    __shared__ short rowIdxL[Nn];
    const float* cg  = ws + OFF_COST + (size_t)b * Nn * Nn;
    const float* qsv = ws + OFF_QS   + (size_t)b * Nn;

    const bool v2ok = (lane < Nn - 128);     // lane < 34
    const int id0 = 2 * lane, id1 = 2 * lane + 1, id2 = 128 + lane;
    const int a32 = 4 * lane;
    const int a16 = 256 + 2 * lane;

    // active-row masks over ORIGINAL rows (per-wave ballots, identical data)
    float q0 = qsv[lane];
    float q1 = qsv[64 + lane];
    float q2v = v2ok ? qsv[128 + lane] : 0.f;
    unsigned long long act0 = __ballot(q0 != 0.f);
    unsigned long long act1 = __ballot(q1 != 0.f);
    unsigned long long act2 = __ballot(v2ok && q2v != 0.f);
    int n0 = __popcll(act0), n1 = __popcll(act1), n2 = __popcll(act2);
    const int nact = n0 + n1 + n2;
    if (nact == 0) { if (tid == 0) ws[OFF_PD + b] = 1.f; return; }

    if (tid <= Nn) { rowBest[tid] = BIGI; Ulds[tid] = 0.f; }
    if (tid < 192) dvA[tid] = 0.f;
    if (wv == 0) {   // packed index map (order-preserving)
        unsigned long long lt = (lane == 63) ? ~0ull >> 1 : ((1ull << lane) - 1);
        lt = (1ull << lane) - 1;   // lane<64 => safe (lane=63 -> shift 63 ok)
        if ((act0 >> lane) & 1) rowIdxL[__popcll(act0 & lt)] = (short)lane;
        if ((act1 >> lane) & 1) rowIdxL[n0 + __popcll(act1 & lt)] = (short)(64 + lane);
        if (v2ok && ((act2 >> lane) & 1)) rowIdxL[n0 + n1 + __popcll(act2 & lt)] = (short)(128 + lane);
    }
    __syncthreads();   // B1

    // ---- stage packed rows (fp16), 4-wave strided ----
    for (int k = wv; k < nact; k += 4) {
        int orig = rowIdxL[k];
        float2 f2 = *(const float2*)(cg + (size_t)orig * Nn + 2 * lane);
        unsigned pk = (unsigned)f2h(f2.x) | ((unsigned)f2h(f2.y) << 16);
        *(unsigned*)((char*)Cw + k * RBW + a32) = pk;
        if (v2ok) *(unsigned short*)((char*)Cw + k * RBW + a16) = f2h(cg[(size_t)orig * Nn + 128 + lane]);
    }
    __syncthreads();   // B2

    // ---- CR partials per wave ----
    float cm0 = INFV, cm1 = INFV, cm2 = INFV; int im0 = 0, im1 = 0, im2 = 0;
    for (int k = wv; k < nact; k += 4) {
        unsigned pr = *(const unsigned*)((const char*)Cw + k * RBW + a32);
        float c0 = h2f((unsigned short)pr);
        float c1 = h2f((unsigned short)(pr >> 16));
        float c2 = h2f(*(const unsigned short*)((const char*)Cw + k * RBW + a16));
        if (c0 < cm0) { cm0 = c0; im0 = k + 1; }
        if (c1 < cm1) { cm1 = c1; im1 = k + 1; }
        if (v2ok && c2 < cm2) { cm2 = c2; im2 = k + 1; }
    }
    pcm[wv][id0] = cm0; pim[wv][id0] = im0;
    pcm[wv][id1] = cm1; pim[wv][id1] = im1;
    if (v2ok) { pcm[wv][id2] = cm2; pim[wv][id2] = im2; }
    __syncthreads();   // B3

    // ---- exact combine (all waves, identical): (val, then smaller packed idx) ----
    cm0 = INFV; im0 = 0; cm1 = INFV; im1 = 0; cm2 = INFV; im2 = 0;
    #pragma unroll
    for (int ww = 0; ww < 4; ++ww) {
        float c; int im;
        c = pcm[ww][id0]; im = pim[ww][id0];
        if (im > 0 && (im0 == 0 || c < cm0 || (c == cm0 && im < im0))) { cm0 = c; im0 = im; }
        c = pcm[ww][id1]; im = pim[ww][id1];
        if (im > 0 && (im1 == 0 || c < cm1 || (c == cm1 && im < im1))) { cm1 = c; im1 = im; }
        if (v2ok) {
            c = pcm[ww][id2]; im = pim[ww][id2];
            if (im > 0 && (im2 == 0 || c < cm2 || (c == cm2 && im < im2))) { cm2 = c; im2 = im; }
        }
    }
    if (wv == 0) {
        if (im0 > 0) atomicMin(&rowBest[im0], id0);
        if (im1 > 0) atomicMin(&rowBest[im1], id1);
        if (v2ok && im2 > 0) atomicMin(&rowBest[im2], id2);
    }
    __syncthreads();   // B4

    float v0 = cm0, v1 = cm1, v2 = v2ok ? cm2 : 0.f;
    int Pa0 = (im0 > 0 && rowBest[im0] == id0) ? im0 : 0;
    int Pa1 = (im1 > 0 && rowBest[im1] == id1) ? im1 : 0;
    int Pa2 = (v2ok && im2 > 0 && rowBest[im2] == id2) ? im2 : 0;

    // free-row masks over PACKED rows (bit k-1 in 1-based terms: bit t = packed row t+1)
    unsigned long long cb0 = __ballot(lane + 1 <= nact && rowBest[lane + 1] != BIGI);
    unsigned long long cb1 = __ballot(lane + 65 <= nact && rowBest[lane + 65] != BIGI);
    unsigned long long cb2 = __ballot(lane + 129 <= nact && rowBest[lane + 129] != BIGI);
    unsigned long long fr0 = mask_n(nact)       & ~cb0;
    unsigned long long fr1 = mask_n(nact - 64)  & ~cb1;
    unsigned long long fr2 = mask_n(nact - 128) & ~cb2;

    // ---- RTR, 4-wave strided (rows independent; matched col unique per row) ----
    for (int k = wv; k < nact; k += 4) {
        int j1c = rowBest[k + 1];
        if (j1c == BIGI) continue;
        int roff = k * RBW;
        unsigned pr = *(const unsigned*)((const char*)Cw + roff + a32);
        float r0 = h2f((unsigned short)pr) - v0;
        float r1 = h2f((unsigned short)(pr >> 16)) - v1;
        float r2 = h2f(*(const unsigned short*)((const char*)Cw + roff + a16)) - v2;
        unsigned p0 = (id0 == j1c) ? 0xFFFFFFFFu : packnn(r0, id0);
        unsigned p1 = (id1 == j1c) ? 0xFFFFFFFFu : packnn(r1, id1);
        unsigned p2 = (v2ok && id2 != j1c) ? packnn(r2, id2) : 0xFFFFFFFFu;
        unsigned pk = reduceMin64(umin32(p0, umin32(p1, p2)));
        float min2 = unpacknn(pk);
        if (lane == 0) { dvA[j1c] = min2; Ulds[k + 1] = min2; }
    }
    __syncthreads();   // B5 — last barrier; waves 1-3 retire
    if (wv != 0) return;

    float ur0, ur1, ur2;
    v0 -= dvA[id0]; ur0 = dvA[id0];
    v1 -= dvA[id1]; ur1 = dvA[id1];
    if (v2ok) { v2 -= dvA[id2]; ur2 = dvA[id2]; } else ur2 = 0.f;

    float minv0 = INFV, minv1 = INFV, minv2 = INFV;
    int way0 = 255, way1 = 255, way2 = 255;
    bool used0 = false, used1 = false, used2 = false;

    // ---- ARR (wave 0, serial) ----
    unsigned long long nx0 = 0, nx1 = 0, nx2 = 0;
    int arrIt = 0;
    for (int pass = 0; pass < 2; ++pass) {
        while ((fr0 | fr1 | fr2) != 0 && arrIt < ARRCAP) {
            ++arrIt;
            int i;
            if (fr0)      { int t = __builtin_ctzll(fr0); i = t + 1;   fr0 &= fr0 - 1; }
            else if (fr1) { int t = __builtin_ctzll(fr1); i = t + 65;  fr1 &= fr1 - 1; }
            else          { int t = __builtin_ctzll(fr2); i = t + 129; fr2 &= fr2 - 1; }
            int roff = (i - 1) * RBW;
            unsigned pr = *(const unsigned*)((const char*)Cw + roff + a32);
            float r0 = h2f((unsigned short)pr) - v0;
            float r1 = h2f((unsigned short)(pr >> 16)) - v1;
            float r2 = h2f(*(const unsigned short*)((const char*)Cw + roff + a16)) - v2;
            unsigned p0 = packnn(r0, id0);
            unsigned p1 = packnn(r1, id1);
            unsigned p2 = v2ok ? packnn(r2, id2) : 0xFFFFFFFFu;
            unsigned lmin = umin32(p0, umin32(p1, p2));
            unsigned lmed = umin32(umax32(p0, p1), umax32(umin32(p0, p1), p2));
            unsigned M1 = reduceMin64(lmin);
            unsigned M2 = reduceMin64(lmin == M1 ? lmed : lmin);
            int j1 = (int)(M1 & 0xFFu), j2 = (int)(M2 & 0xFFu);
            int l1 = laneOf(j1), s1 = slotOf(j1);
            int l2 = laneOf(j2), s2 = slotOf(j2);
            float umin_e = rlanef(SEL3(s1, r0, r1, r2), l1);
            float usub_e = rlanef(SEL3(s2, r0, r1, r2), l2);
            int iA = rlanei(SEL3(s1, Pa0, Pa1, Pa2), l1);
            int iB = rlanei(SEL3(s2, Pa0, Pa1, Pa2), l2);
            if (usub_e < umin_e) {
                int tj = j1; j1 = j2; j2 = tj;
                int tl = l1; l1 = l2; l2 = tl;
                int ts = s1; s1 = s2; s2 = ts;
                float tv = umin_e; umin_e = usub_e; usub_e = tv;
                int ti = iA; iA = iB; iB = ti;
            }
            bool strict = (umin_e < usub_e);
            int jt, idisp;
            float ua = usub_e;
            if (strict) {
                float d = usub_e - umin_e;
                if (lane == l1) { if (s1 == 0) v0 -= d; else if (s1 == 1) v1 -= d; else v2 -= d; }
                jt = j1; idisp = iA;
            } else if (iA > 0) {
                jt = j2; idisp = iB;
            } else {
                jt = j1; idisp = 0;
            }
            int lt = laneOf(jt), st = slotOf(jt);
            if (lane == lt) {
                if (st == 0)      { Pa0 = i; ur0 = ua; }
                else if (st == 1) { Pa1 = i; ur1 = ua; }
                else              { Pa2 = i; ur2 = ua; }
            }
            if (lane == 0) Ulds[i] = ua;
            if (idisp > 0) {
                if (strict) {
                    if (idisp <= 64)       fr0 |= 1ull << (idisp - 1);
                    else if (idisp <= 128) fr1 |= 1ull << (idisp - 65);
                    else                   fr2 |= 1ull << (idisp - 129);
                } else {
                    if (idisp <= 64)       nx0 |= 1ull << (idisp - 1);
                    else if (idisp <= 128) nx1 |= 1ull << (idisp - 65);
                    else                   nx2 |= 1ull << (idisp - 129);
                }
            }
        }
        fr0 |= nx0; fr1 |= nx1; fr2 |= nx2;
        nx0 = nx1 = nx2 = 0;
    }

    // ---- Dijkstra augmentation (wave 0, serial) ----
    while ((fr0 | fr1 | fr2) != 0) {
        int i;
        if (fr0)      { int t = __builtin_ctzll(fr0); i = t + 1;   fr0 &= fr0 - 1; }
        else if (fr1) { int t = __builtin_ctzll(fr1); i = t + 65;  fr1 &= fr1 - 1; }
        else          { int t = __builtin_ctzll(fr2); i = t + 129; fr2 &= fr2 - 1; }
        float u_root = Ulds[i];
        minv0 = minv1 = minv2 = INFV;
        way0 = way1 = way2 = 255;
        used0 = used1 = used2 = false;
        {
            int roff = (i - 1) * RBW;
            unsigned pr = *(const unsigned*)((const char*)Cw + roff + a32);
            float c0 = h2f((unsigned short)pr);
            float c1 = h2f((unsigned short)(pr >> 16));
            float c2 = h2f(*(const unsigned short*)((const char*)Cw + roff + a16));
            minv0 = c0 - (u_root + v0);
            minv1 = c1 - (u_root + v1);
            minv2 = v2ok ? (c2 - (u_root + v2)) : INFV;
        }
        int jend = -1;
        for (int it = 0; it < Nn + 2; ++it) {
            unsigned q0p = used0 ? 0xFFFFFFFFu : packnn(minv0, id0);
            unsigned q1p = used1 ? 0xFFFFFFFFu : packnn(minv1, id1);
            unsigned q2p = (v2ok && !used2) ? packnn(minv2, id2) : 0xFFFFFFFFu;
            unsigned pk = reduceMin64(umin32(q0p, umin32(q1p, q2p)));
            int j1 = (int)(pk & 0xFFu);
            float delta = unpacknn(pk);
            int l1 = laneOf(j1), s1 = slotOf(j1);
            int i1 = rlanei(SEL3(s1, Pa0, Pa1, Pa2), l1);
            float u1 = rlanef(SEL3(s1, ur0, ur1, ur2), l1);
            u_root += delta;
            v0 = used0 ? v0 - delta : v0;  ur0 = used0 ? ur0 + delta : ur0;  minv0 = used0 ? minv0 : minv0 - delta;
            v1 = used1 ? v1 - delta : v1;  ur1 = used1 ? ur1 + delta : ur1;  minv1 = used1 ? minv1 : minv1 - delta;
            v2 = used2 ? v2 - delta : v2;  ur2 = used2 ? ur2 + delta : ur2;  minv2 = used2 ? minv2 : minv2 - delta;
            bool hit = (lane == l1);
            if (s1 == 0) used0 |= hit; else if (s1 == 1) used1 |= hit; else used2 |= hit;
            if (i1 == 0) { jend = j1; break; }
            int roff = (i1 - 1) * RBW;
            unsigned pr = *(const unsigned*)((const char*)Cw + roff + a32);
            float c0 = h2f((unsigned short)pr);
            float c1 = h2f((unsigned short)(pr >> 16));
            float c2 = h2f(*(const unsigned short*)((const char*)Cw + roff + a16));
            float n0 = c0 - (u1 + v0), n1 = c1 - (u1 + v1), n2 = c2 - (u1 + v2);
            if (!used0 && n0 < minv0) { minv0 = n0; way0 = j1; }
            if (!used1 && n1 < minv1) { minv1 = n1; way1 = j1; }
            if (v2ok && !used2 && n2 < minv2) { minv2 = n2; way2 = j1; }
        }
        int j = jend;
        while (j >= 0) {
            int l = laneOf(j), s = slotOf(j);
            int w = rlanei(SEL3(s, way0, way1, way2), l);
            int pnew; float unew;
            if (w == 255) { pnew = i; unew = u_root; }
            else {
                int lw = laneOf(w), sw = slotOf(w);
                pnew = rlanei(SEL3(sw, Pa0, Pa1, Pa2), lw);
                unew = rlanef(SEL3(sw, ur0, ur1, ur2), lw);
            }
            if (lane == l) {
                if (s == 0)      { Pa0 = pnew; ur0 = unew; }
                else if (s == 1) { Pa1 = pnew; ur1 = unew; }
                else             { Pa2 = pnew; ur2 = unew; }
            }
            j = (w == 255) ? -1 : w;
        }
    }

    // ---- assigned-sim sum from fp32 cost (map packed -> original row) ----
    float tot = 0.f;
    if (Pa0 > 0) { int orig = rowIdxL[Pa0 - 1]; tot -= cg[(size_t)orig * Nn + id0]; }
    if (Pa1 > 0) { int orig = rowIdxL[Pa1 - 1]; tot -= cg[(size_t)orig * Nn + id1]; }
    if (v2ok && Pa2 > 0) { int orig = rowIdxL[Pa2 - 1]; tot -= cg[(size_t)orig * Nn + id2]; }
    #pragma unroll
    for (int off = 32; off; off >>= 1) tot += __shfl_xor(tot, off);
    if (lane == 0) ws[OFF_PD + b] = 1.f - tot * (1.f / (float)Pn);
}

// ---------------- K5: mean over batches ----------------
__global__ void k_final(const float* __restrict__ ws, float* __restrict__ out) {
    float v = ws[OFF_PD + threadIdx.x];
    #pragma unroll
    for (int off = 32; off; off >>= 1) v += __shfl_xor(v, off);
    if (threadIdx.x == 0) out[0] = v * (1.f / 64.f);
}

extern "C" void kernel_launch(void* const* d_in, const int* in_sizes, int n_in,
                              void* d_out, int out_size, void* d_ws, size_t ws_size,
                              hipStream_t stream) {
    const float* feat = (const float*)d_in[0];
    const int*   pos  = (const int*)d_in[1];
    float* ws  = (float*)d_ws;
    float* out = (float*)d_out;
    k_tr   <<<dim3(96, 64), 256, 0, stream>>>(feat, ws);
    k_stats<<<64, 192, 0, stream>>>(ws);
    k_mm   <<<704, 256, 0, stream>>>(pos, ws);
    k_hung <<<64, 256, 0, stream>>>(ws);
    k_final<<<1, 64, 0, stream>>>(ws, out);
}

// Round 9
// 108.663 us; speedup vs baseline: 95.4210x; 1.0335x over previous
//
#include <hip/hip_runtime.h>
#include <hip/hip_bf16.h>

#define Bn 64
#define Cn 2048
#define Nn 162          // H*W = 18*9
#define Pn 81           // Nn/2
#define NP 176          // padded N for featT rows (11 tiles of 16)
#define INFV 1.0e9f
#define BIGI 0x7FFFFFFF
#define RBW 328         // k_hung LDS cost-row stride BYTES
#define ARRCAP 700

// ws layout (in floats)
#define OFF_T    0                           // bf16 featT [64][176][2048] = 11,534,336 floats
#define OFF_P    11534336                    // [64][32][192] norm^2 partials
#define OFF_QS   (OFF_P + 64*32*192)         // [64][162] masked row scale
#define OFF_KS   (OFF_QS + 64*162)           // [64][162] col scale
#define OFF_COST (OFF_KS + 64*162)           // [64][162][162] cost = -sim (fp32)
#define OFF_PD   (OFF_COST + 64*162*162)     // [64] per-batch pos_dis

typedef __attribute__((ext_vector_type(8))) short bf16x8;
typedef __attribute__((ext_vector_type(4))) float f32x4;
typedef __attribute__((ext_vector_type(4))) unsigned u32x4;

static __device__ __forceinline__ unsigned short f2bf(float x) {
    unsigned int u = __builtin_bit_cast(unsigned int, x);
    unsigned int r = (u + 0x7fffu + ((u >> 16) & 1u)) >> 16;   // RNE
    return (unsigned short)r;
}
static __device__ __forceinline__ unsigned short f2h(float x) {
    _Float16 h = (_Float16)x;
    return __builtin_bit_cast(unsigned short, h);
}
static __device__ __forceinline__ float h2f(unsigned short u) {
    return (float)__builtin_bit_cast(_Float16, u);
}
static __device__ __forceinline__ unsigned umin32(unsigned a, unsigned b) { return a < b ? a : b; }
static __device__ __forceinline__ unsigned umax32(unsigned a, unsigned b) { return a > b ? a : b; }
static __device__ __forceinline__ unsigned packnn(float v, int id) {
    float c = fmaxf(v, 0.f);
    return (__builtin_bit_cast(unsigned, c) & 0xFFFFFF00u) | (unsigned)id;
}
static __device__ __forceinline__ float unpacknn(unsigned pk) {
    return __builtin_bit_cast(float, pk & 0xFFFFFF00u);
}
static __device__ __forceinline__ unsigned reduceMin64(unsigned x) {
    int v = (int)x, t;
    t = __builtin_amdgcn_update_dpp(0, v, 0x121, 0xF, 0xF, true); v = (int)umin32((unsigned)v, (unsigned)t);
    t = __builtin_amdgcn_update_dpp(0, v, 0x122, 0xF, 0xF, true); v = (int)umin32((unsigned)v, (unsigned)t);
    t = __builtin_amdgcn_update_dpp(0, v, 0x124, 0xF, 0xF, true); v = (int)umin32((unsigned)v, (unsigned)t);
    t = __builtin_amdgcn_update_dpp(0, v, 0x128, 0xF, 0xF, true); v = (int)umin32((unsigned)v, (unsigned)t);
    unsigned a = (unsigned)__builtin_amdgcn_readlane(v, 0);
    unsigned b = (unsigned)__builtin_amdgcn_readlane(v, 16);
    unsigned c = (unsigned)__builtin_amdgcn_readlane(v, 32);
    unsigned d = (unsigned)__builtin_amdgcn_readlane(v, 48);
    return umin32(umin32(a, b), umin32(c, d));
}
static __device__ __forceinline__ int rlanei(int v, int l) { return __builtin_amdgcn_readlane(v, l); }
static __device__ __forceinline__ float rlanef(float v, int l) {
    return __builtin_bit_cast(float, __builtin_amdgcn_readlane(__builtin_bit_cast(int, v), l));
}
static __device__ __forceinline__ int laneOf(int id) { return id < 128 ? (id >> 1) : (id - 128); }
static __device__ __forceinline__ int slotOf(int id) { return id < 128 ? (id & 1) : 2; }
static __device__ __forceinline__ unsigned long long mask_n(int n) {
    if (n <= 0) return 0ull;
    if (n >= 64) return ~0ull;
    return (1ull << n) - 1ull;
}
#define SEL3(s, a0, a1, a2) ((s) == 0 ? (a0) : ((s) == 1 ? (a1) : (a2)))

// ---------------- K1: pack-at-load transpose (fp32 [C][N] -> bf16-pair u32 [NP][C/2]) + norm^2 ----------------
// Thread (pg,col) loads ch=2p,2p+1 directly from global (coalesced 256B rows),
// packs to one u32 in Tp[p][col] (bank (p+col)%32 -> conflict-free), accumulates
// norm^2 in registers (fixed order). No fp32 LDS round-trip.
__global__ __launch_bounds__(256) void k_tr(const float* __restrict__ feat, float* __restrict__ ws) {
    int x = blockIdx.x;            // 0..95: cc = ch-chunk (32), ct = col-chunk (3)
    int cc = x / 3, ct = x % 3;
    int b = blockIdx.y;
    int tid = threadIdx.x;
    int col = tid & 63, pg = tid >> 6;        // pg 0..3
    __shared__ unsigned Tp[32][65];           // packed bf16 pairs [p][col]
    __shared__ float Pp[4][64];               // norm^2 partials per p-group
    int gc = ct * 64 + col;
    bool okc = (gc < Nn);
    const float* fbase = feat + ((size_t)b * Cn + (size_t)cc * 64) * Nn + gc;
    float s = 0.f;
    #pragma unroll
    for (int it = 0; it < 8; ++it) {
        int p = pg + it * 4;                  // 0..31
        float v0 = okc ? fbase[(size_t)(2 * p) * Nn] : 0.f;
        float v1 = okc ? fbase[(size_t)(2 * p + 1) * Nn] : 0.f;
        s = fmaf(v0, v0, fmaf(v1, v1, s));
        Tp[p][col] = (unsigned)f2bf(v0) | ((unsigned)f2bf(v1) << 16);
    }
    Pp[pg][col] = s;
    __syncthreads();
    if (tid < 64) {
        float t0 = Pp[0][tid] + Pp[1][tid];
        float t1 = Pp[2][tid] + Pp[3][tid];
        ws[OFF_P + ((size_t)b * 32 + cc) * 192 + ct * 64 + tid] = t0 + t1;
    }
    unsigned* ft = (unsigned*)(ws + OFF_T);
    #pragma unroll
    for (int it = 0; it < 8; ++it) {
        int idx = it * 256 + tid;
        int c2 = idx >> 5, p = idx & 31;
        int gcol = ct * 64 + c2;
        if (gcol < NP) {
            ft[(size_t)(b * NP + gcol) * 1024 + cc * 32 + p] = Tp[p][c2];
        }
    }
}

// ---------------- K2: per-batch stats ----------------
__global__ void k_stats(float* __restrict__ ws) {
    int b = blockIdx.x;
    int t = threadIdx.x;
    __shared__ float arr[Nn];
    __shared__ float thr;
    float norm = 0.f;
    if (t < Nn) {
        float s = 0.f;
        #pragma unroll
        for (int ch = 0; ch < 32; ++ch) s += ws[OFF_P + ((size_t)b * 32 + ch) * 192 + t];
        norm = sqrtf(s);
        arr[t] = norm;
    }
    __syncthreads();
    float mn = INFV, mx = -INFV;
    for (int k = 0; k < Nn; ++k) { float v = arr[k]; mn = fminf(mn, v); mx = fmaxf(mx, v); }
    __syncthreads();
    float mval = 0.f;
    if (t < Nn) mval = (norm - mn) / (mx - mn + 1e-12f);
    __syncthreads();
    if (t < Nn) arr[t] = mval;
    __syncthreads();
    if (t < Nn) {
        int cl = 0, ce = 0, ceb = 0;
        for (int k = 0; k < Nn; ++k) {
            float v = arr[k];
            cl  += (v <  mval);
            ce  += (v == mval);
            ceb += (v == mval && k < t);
        }
        if (cl <= Pn && (cl + ce) > Pn && ceb == 0) thr = mval;
    }
    __syncthreads();
    if (t < Nn) {
        float inv = 1.f / fmaxf(norm, 1e-12f);
        ws[OFF_KS + (size_t)b * Nn + t] = inv;
        ws[OFF_QS + (size_t)b * Nn + t] = (mval < thr) ? 0.f : inv;
    }
}

// ---------------- K3: bf16 MFMA GEMM from featT (K-contiguous) -> cost = -sim ----------------
__global__ __launch_bounds__(256) void k_mm(const int* __restrict__ pos_ind,
                                            float* __restrict__ ws) {
    int wg = blockIdx.x;
    int xcd = wg & 7, kk = wg >> 3;
    int b  = xcd + 8 * (kk / 11);
    int mt = kk % 11;
    int tid = threadIdx.x;
    int lane = tid & 63, w = tid >> 6;
    int q0 = mt * 16;
    int pb = pos_ind[b];
    const u32x4* At = (const u32x4*)((const unsigned short*)(ws + OFF_T) + (size_t)b  * NP * Cn);
    const u32x4* Bt = (const u32x4*)((const unsigned short*)(ws + OFF_T) + (size_t)pb * NP * Cn);
    __shared__ u32x4 As[16 * 16];
    __shared__ u32x4 Bs[192 * 16];

    f32x4 acc0 = {0.f, 0.f, 0.f, 0.f}, acc1 = acc0, acc2 = acc0;
    const int ct0 = w * 3, ct1 = w * 3 + 1, ct2 = w * 3 + 2;
    const int fr = lane & 15, fq = lane >> 4;

    for (int c0 = 0; c0 < Cn; c0 += 128) {
        int g0 = c0 >> 3;
        {
            int r = tid >> 4, g = tid & 15;
            As[r * 16 + (g ^ r)] = At[(size_t)(q0 + r) * 256 + g0 + g];
        }
        #pragma unroll
        for (int it = 0; it < 11; ++it) {
            int task = it * 256 + tid;
            int col = task >> 4, g = task & 15;
            Bs[col * 16 + (g ^ (col & 15))] = Bt[(size_t)col * 256 + g0 + g];
        }
        __syncthreads();
        #pragma unroll
        for (int ks = 0; ks < 4; ++ks) {
            int gk = ks * 4 + fq;
            bf16x8 af = *(const bf16x8*)&As[fr * 16 + (gk ^ fr)];
            bf16x8 b0 = *(const bf16x8*)&Bs[(ct0 * 16 + fr) * 16 + (gk ^ fr)];
            bf16x8 b1 = *(const bf16x8*)&Bs[(ct1 * 16 + fr) * 16 + (gk ^ fr)];
            bf16x8 b2 = *(const bf16x8*)&Bs[(ct2 * 16 + fr) * 16 + (gk ^ fr)];
            acc0 = __builtin_amdgcn_mfma_f32_16x16x32_bf16(af, b0, acc0, 0, 0, 0);
            acc1 = __builtin_amdgcn_mfma_f32_16x16x32_bf16(af, b1, acc1, 0, 0, 0);
            acc2 = __builtin_amdgcn_mfma_f32_16x16x32_bf16(af, b2, acc2, 0, 0, 0);
        }
        __syncthreads();
    }

    const float* qsv = ws + OFF_QS + (size_t)b  * Nn;
    const float* ksv = ws + OFF_KS + (size_t)pb * Nn;
    float* cost = ws + OFF_COST + (size_t)b * Nn * Nn;
    int c0_ = ct0 * 16 + fr, c1_ = ct1 * 16 + fr, c2_ = ct2 * 16 + fr;
    float ks0 = (c0_ < Nn) ? ksv[c0_] : 0.f;
    float ks1 = (c1_ < Nn) ? ksv[c1_] : 0.f;
    float ks2 = (c2_ < Nn) ? ksv[c2_] : 0.f;
    #pragma unroll
    for (int j = 0; j < 4; ++j) {
        int r = q0 + fq * 4 + j;
        if (r < Nn) {
            float qsr = qsv[r];
            if (c0_ < Nn) cost[(size_t)r * Nn + c0_] = -(acc0[j] * qsr * ks0);
            if (c1_ < Nn) cost[(size_t)r * Nn + c1_] = -(acc1[j] * qsr * ks1);
            if (c2_ < Nn) cost[(size_t)r * Nn + c2_] = -(acc2[j] * qsr * ks2);
        }
    }
}

// ---------------- K4: rectangular LAPJV, 4 waves: parallel stage/CR/RTR, serial ARR/Dijkstra ----------------
__global__ __launch_bounds__(256) void k_hung(float* __restrict__ ws) {
    const int b = blockIdx.x;
    const int tid = threadIdx.x;
    const int lane = tid & 63, wv = tid >> 6;
    __shared__ unsigned short Cw[(Nn * RBW) / 2 + 32];
    __shared__ int rowBest[Nn + 1];
    __shared__ float Ulds[Nn + 1];
    __shared__ float dvA[192];
    __shared__ float pcm[4][192];
    __shared__ int   pim[4][192];
    __shared__ short rowIdxL[Nn];
    const float* cg  = ws + OFF_COST + (size_t)b * Nn * Nn;
    const float* qsv = ws + OFF_QS   + (size_t)b * Nn;

    const bool v2ok = (lane < Nn - 128);     // lane < 34
    const int id0 = 2 * lane, id1 = 2 * lane + 1, id2 = 128 + lane;
    const int a32 = 4 * lane;
    const int a16 = 256 + 2 * lane;

    float q0 = qsv[lane];
    float q1 = qsv[64 + lane];
    float q2v = v2ok ? qsv[128 + lane] : 0.f;
    unsigned long long act0 = __ballot(q0 != 0.f);
    unsigned long long act1 = __ballot(q1 != 0.f);
    unsigned long long act2 = __ballot(v2ok && q2v != 0.f);
    int n0 = __popcll(act0), n1 = __popcll(act1), n2 = __popcll(act2);
    const int nact = n0 + n1 + n2;
    if (nact == 0) { if (tid == 0) ws[OFF_PD + b] = 1.f; return; }

    if (tid <= Nn) { rowBest[tid] = BIGI; Ulds[tid] = 0.f; }
    if (tid < 192) dvA[tid] = 0.f;
    if (wv == 0) {   // packed index map (order-preserving)
        unsigned long long lt = (1ull << lane) - 1;
        if ((act0 >> lane) & 1) rowIdxL[__popcll(act0 & lt)] = (short)lane;
        if ((act1 >> lane) & 1) rowIdxL[n0 + __popcll(act1 & lt)] = (short)(64 + lane);
        if (v2ok && ((act2 >> lane) & 1)) rowIdxL[n0 + n1 + __popcll(act2 & lt)] = (short)(128 + lane);
    }
    __syncthreads();   // B1

    for (int k = wv; k < nact; k += 4) {
        int orig = rowIdxL[k];
        float2 f2 = *(const float2*)(cg + (size_t)orig * Nn + 2 * lane);
        unsigned pk = (unsigned)f2h(f2.x) | ((unsigned)f2h(f2.y) << 16);
        *(unsigned*)((char*)Cw + k * RBW + a32) = pk;
        if (v2ok) *(unsigned short*)((char*)Cw + k * RBW + a16) = f2h(cg[(size_t)orig * Nn + 128 + lane]);
    }
    __syncthreads();   // B2

    float cm0 = INFV, cm1 = INFV, cm2 = INFV; int im0 = 0, im1 = 0, im2 = 0;
    for (int k = wv; k < nact; k += 4) {
        unsigned pr = *(const unsigned*)((const char*)Cw + k * RBW + a32);
        float c0 = h2f((unsigned short)pr);
        float c1 = h2f((unsigned short)(pr >> 16));
        float c2 = h2f(*(const unsigned short*)((const char*)Cw + k * RBW + a16));
        if (c0 < cm0) { cm0 = c0; im0 = k + 1; }
        if (c1 < cm1) { cm1 = c1; im1 = k + 1; }
        if (v2ok && c2 < cm2) { cm2 = c2; im2 = k + 1; }
    }
    pcm[wv][id0] = cm0; pim[wv][id0] = im0;
    pcm[wv][id1] = cm1; pim[wv][id1] = im1;
    if (v2ok) { pcm[wv][id2] = cm2; pim[wv][id2] = im2; }
    __syncthreads();   // B3

    cm0 = INFV; im0 = 0; cm1 = INFV; im1 = 0; cm2 = INFV; im2 = 0;
    #pragma unroll
    for (int ww = 0; ww < 4; ++ww) {
        float c; int im;
        c = pcm[ww][id0]; im = pim[ww][id0];
        if (im > 0 && (im0 == 0 || c < cm0 || (c == cm0 && im < im0))) { cm0 = c; im0 = im; }
        c = pcm[ww][id1]; im = pim[ww][id1];
        if (im > 0 && (im1 == 0 || c < cm1 || (c == cm1 && im < im1))) { cm1 = c; im1 = im; }
        if (v2ok) {
            c = pcm[ww][id2]; im = pim[ww][id2];
            if (im > 0 && (im2 == 0 || c < cm2 || (c == cm2 && im < im2))) { cm2 = c; im2 = im; }
        }
    }
    if (wv == 0) {
        if (im0 > 0) atomicMin(&rowBest[im0], id0);
        if (im1 > 0) atomicMin(&rowBest[im1], id1);
        if (v2ok && im2 > 0) atomicMin(&rowBest[im2], id2);
    }
    __syncthreads();   // B4

    float v0 = cm0, v1 = cm1, v2 = v2ok ? cm2 : 0.f;
    int Pa0 = (im0 > 0 && rowBest[im0] == id0) ? im0 : 0;
    int Pa1 = (im1 > 0 && rowBest[im1] == id1) ? im1 : 0;
    int Pa2 = (v2ok && im2 > 0 && rowBest[im2] == id2) ? im2 : 0;

    unsigned long long cb0 = __ballot(lane + 1 <= nact && rowBest[lane + 1] != BIGI);
    unsigned long long cb1 = __ballot(lane + 65 <= nact && rowBest[lane + 65] != BIGI);
    unsigned long long cb2 = __ballot(lane + 129 <= nact && rowBest[lane + 129] != BIGI);
    unsigned long long fr0 = mask_n(nact)       & ~cb0;
    unsigned long long fr1 = mask_n(nact - 64)  & ~cb1;
    unsigned long long fr2 = mask_n(nact - 128) & ~cb2;

    for (int k = wv; k < nact; k += 4) {
        int j1c = rowBest[k + 1];
        if (j1c == BIGI) continue;
        int roff = k * RBW;
        unsigned pr = *(const unsigned*)((const char*)Cw + roff + a32);
        float r0 = h2f((unsigned short)pr) - v0;
        float r1 = h2f((unsigned short)(pr >> 16)) - v1;
        float r2 = h2f(*(const unsigned short*)((const char*)Cw + roff + a16)) - v2;
        unsigned p0 = (id0 == j1c) ? 0xFFFFFFFFu : packnn(r0, id0);
        unsigned p1 = (id1 == j1c) ? 0xFFFFFFFFu : packnn(r1, id1);
        unsigned p2 = (v2ok && id2 != j1c) ? packnn(r2, id2) : 0xFFFFFFFFu;
        unsigned pk = reduceMin64(umin32(p0, umin32(p1, p2)));
        float min2 = unpacknn(pk);
        if (lane == 0) { dvA[j1c] = min2; Ulds[k + 1] = min2; }
    }
    __syncthreads();   // B5 — last barrier; waves 1-3 retire
    if (wv != 0) return;

    float ur0, ur1, ur2;
    v0 -= dvA[id0]; ur0 = dvA[id0];
    v1 -= dvA[id1]; ur1 = dvA[id1];
    if (v2ok) { v2 -= dvA[id2]; ur2 = dvA[id2]; } else ur2 = 0.f;

    float minv0 = INFV, minv1 = INFV, minv2 = INFV;
    int way0 = 255, way1 = 255, way2 = 255;
    bool used0 = false, used1 = false, used2 = false;

    unsigned long long nx0 = 0, nx1 = 0, nx2 = 0;
    int arrIt = 0;
    for (int pass = 0; pass < 2; ++pass) {
        while ((fr0 | fr1 | fr2) != 0 && arrIt < ARRCAP) {
            ++arrIt;
            int i;
            if (fr0)      { int t = __builtin_ctzll(fr0); i = t + 1;   fr0 &= fr0 - 1; }
            else if (fr1) { int t = __builtin_ctzll(fr1); i = t + 65;  fr1 &= fr1 - 1; }
            else          { int t = __builtin_ctzll(fr2); i = t + 129; fr2 &= fr2 - 1; }
            int roff = (i - 1) * RBW;
            unsigned pr = *(const unsigned*)((const char*)Cw + roff + a32);
            float r0 = h2f((unsigned short)pr) - v0;
            float r1 = h2f((unsigned short)(pr >> 16)) - v1;
            float r2 = h2f(*(const unsigned short*)((const char*)Cw + roff + a16)) - v2;
            unsigned p0 = packnn(r0, id0);
            unsigned p1 = packnn(r1, id1);
            unsigned p2 = v2ok ? packnn(r2, id2) : 0xFFFFFFFFu;
            unsigned lmin = umin32(p0, umin32(p1, p2));
            unsigned lmed = umin32(umax32(p0, p1), umax32(umin32(p0, p1), p2));
            unsigned M1 = reduceMin64(lmin);
            unsigned M2 = reduceMin64(lmin == M1 ? lmed : lmin);
            int j1 = (int)(M1 & 0xFFu), j2 = (int)(M2 & 0xFFu);
            int l1 = laneOf(j1), s1 = slotOf(j1);
            int l2 = laneOf(j2), s2 = slotOf(j2);
            float umin_e = rlanef(SEL3(s1, r0, r1, r2), l1);
            float usub_e = rlanef(SEL3(s2, r0, r1, r2), l2);
            int iA = rlanei(SEL3(s1, Pa0, Pa1, Pa2), l1);
            int iB = rlanei(SEL3(s2, Pa0, Pa1, Pa2), l2);
            if (usub_e < umin_e) {
                int tj = j1; j1 = j2; j2 = tj;
                int tl = l1; l1 = l2; l2 = tl;
                int ts = s1; s1 = s2; s2 = ts;
                float tv = umin_e; umin_e = usub_e; usub_e = tv;
                int ti = iA; iA = iB; iB = ti;
            }
            bool strict = (umin_e < usub_e);
            int jt, idisp;
            float ua = usub_e;
            if (strict) {
                float d = usub_e - umin_e;
                if (lane == l1) { if (s1 == 0) v0 -= d; else if (s1 == 1) v1 -= d; else v2 -= d; }
                jt = j1; idisp = iA;
            } else if (iA > 0) {
                jt = j2; idisp = iB;
            } else {
                jt = j1; idisp = 0;
            }
            int lt = laneOf(jt), st = slotOf(jt);
            if (lane == lt) {
                if (st == 0)      { Pa0 = i; ur0 = ua; }
                else if (st == 1) { Pa1 = i; ur1 = ua; }
                else              { Pa2 = i; ur2 = ua; }
            }
            if (lane == 0) Ulds[i] = ua;
            if (idisp > 0) {
                if (strict) {
                    if (idisp <= 64)       fr0 |= 1ull << (idisp - 1);
                    else if (idisp <= 128) fr1 |= 1ull << (idisp - 65);
                    else                   fr2 |= 1ull << (idisp - 129);
                } else {
                    if (idisp <= 64)       nx0 |= 1ull << (idisp - 1);
                    else if (idisp <= 128) nx1 |= 1ull << (idisp - 65);
                    else                   nx2 |= 1ull << (idisp - 129);
                }
            }
        }
        fr0 |= nx0; fr1 |= nx1; fr2 |= nx2;
        nx0 = nx1 = nx2 = 0;
    }

    while ((fr0 | fr1 | fr2) != 0) {
        int i;
        if (fr0)      { int t = __builtin_ctzll(fr0); i = t + 1;   fr0 &= fr0 - 1; }
        else if (fr1) { int t = __builtin_ctzll(fr1); i = t + 65;  fr1 &= fr1 - 1; }
        else          { int t = __builtin_ctzll(fr2); i = t + 129; fr2 &= fr2 - 1; }
        float u_root = Ulds[i];
        minv0 = minv1 = minv2 = INFV;
        way0 = way1 = way2 = 255;
        used0 = used1 = used2 = false;
        {
            int roff = (i - 1) * RBW;
            unsigned pr = *(const unsigned*)((const char*)Cw + roff + a32);
            float c0 = h2f((unsigned short)pr);
            float c1 = h2f((unsigned short)(pr >> 16));
            float c2 = h2f(*(const unsigned short*)((const char*)Cw + roff + a16));
            minv0 = c0 - (u_root + v0);
            minv1 = c1 - (u_root + v1);
            minv2 = v2ok ? (c2 - (u_root + v2)) : INFV;
        }
        int jend = -1;
        for (int it = 0; it < Nn + 2; ++it) {
            unsigned q0p = used0 ? 0xFFFFFFFFu : packnn(minv0, id0);
            unsigned q1p = used1 ? 0xFFFFFFFFu : packnn(minv1, id1);
            unsigned q2p = (v2ok && !used2) ? packnn(minv2, id2) : 0xFFFFFFFFu;
            unsigned pk = reduceMin64(umin32(q0p, umin32(q1p, q2p)));
            int j1 = (int)(pk & 0xFFu);
            float delta = unpacknn(pk);
            int l1 = laneOf(j1), s1 = slotOf(j1);
            int i1 = rlanei(SEL3(s1, Pa0, Pa1, Pa2), l1);
            float u1 = rlanef(SEL3(s1, ur0, ur1, ur2), l1);
            u_root += delta;
            v0 = used0 ? v0 - delta : v0;  ur0 = used0 ? ur0 + delta : ur0;  minv0 = used0 ? minv0 : minv0 - delta;
            v1 = used1 ? v1 - delta : v1;  ur1 = used1 ? ur1 + delta : ur1;  minv1 = used1 ? minv1 : minv1 - delta;
            v2 = used2 ? v2 - delta : v2;  ur2 = used2 ? ur2 + delta : ur2;  minv2 = used2 ? minv2 : minv2 - delta;
            bool hit = (lane == l1);
            if (s1 == 0) used0 |= hit; else if (s1 == 1) used1 |= hit; else used2 |= hit;
            if (i1 == 0) { jend = j1; break; }
            int roff = (i1 - 1) * RBW;
            unsigned pr = *(const unsigned*)((const char*)Cw + roff + a32);
            float c0 = h2f((unsigned short)pr);
            float c1 = h2f((unsigned short)(pr >> 16));
            float c2 = h2f(*(const unsigned short*)((const char*)Cw + roff + a16));
            float n0 = c0 - (u1 + v0), n1 = c1 - (u1 + v1), n2 = c2 - (u1 + v2);
            if (!used0 && n0 < minv0) { minv0 = n0; way0 = j1; }
            if (!used1 && n1 < minv1) { minv1 = n1; way1 = j1; }
            if (v2ok && !used2 && n2 < minv2) { minv2 = n2; way2 = j1; }
        }
        int j = jend;
        while (j >= 0) {
            int l = laneOf(j), s = slotOf(j);
            int w = rlanei(SEL3(s, way0, way1, way2), l);
            int pnew; float unew;
            if (w == 255) { pnew = i; unew = u_root; }
            else {
                int lw = laneOf(w), sw = slotOf(w);
                pnew = rlanei(SEL3(sw, Pa0, Pa1, Pa2), lw);
                unew = rlanef(SEL3(sw, ur0, ur1, ur2), lw);
            }
            if (lane == l) {
                if (s == 0)      { Pa0 = pnew; ur0 = unew; }
                else if (s == 1) { Pa1 = pnew; ur1 = unew; }
                else             { Pa2 = pnew; ur2 = unew; }
            }
            j = (w == 255) ? -1 : w;
        }
    }

    float tot = 0.f;
    if (Pa0 > 0) { int orig = rowIdxL[Pa0 - 1]; tot -= cg[(size_t)orig * Nn + id0]; }
    if (Pa1 > 0) { int orig = rowIdxL[Pa1 - 1]; tot -= cg[(size_t)orig * Nn + id1]; }
    if (v2ok && Pa2 > 0) { int orig = rowIdxL[Pa2 - 1]; tot -= cg[(size_t)orig * Nn + id2]; }
    #pragma unroll
    for (int off = 32; off; off >>= 1) tot += __shfl_xor(tot, off);
    if (lane == 0) ws[OFF_PD + b] = 1.f - tot * (1.f / (float)Pn);
}

// ---------------- K5: mean over batches ----------------
__global__ void k_final(const float* __restrict__ ws, float* __restrict__ out) {
    float v = ws[OFF_PD + threadIdx.x];
    #pragma unroll
    for (int off = 32; off; off >>= 1) v += __shfl_xor(v, off);
    if (threadIdx.x == 0) out[0] = v * (1.f / 64.f);
}

extern "C" void kernel_launch(void* const* d_in, const int* in_sizes, int n_in,
                              void* d_out, int out_size, void* d_ws, size_t ws_size,
                              hipStream_t stream) {
    const float* feat = (const float*)d_in[0];
    const int*   pos  = (const int*)d_in[1];
    float* ws  = (float*)d_ws;
    float* out = (float*)d_out;
    k_tr   <<<dim3(96, 64), 256, 0, stream>>>(feat, ws);
    k_stats<<<64, 192, 0, stream>>>(ws);
    k_mm   <<<704, 256, 0, stream>>>(pos, ws);
    k_hung <<<64, 256, 0, stream>>>(ws);
    k_final<<<1, 64, 0, stream>>>(ws, out);
}

// Round 10
// 103.568 us; speedup vs baseline: 100.1160x; 1.0492x over previous
//
#include <hip/hip_runtime.h>
#include <hip/hip_bf16.h>

#define Bn 64
#define Cn 2048
#define Nn 162          // H*W = 18*9
#define Pn 81           // Nn/2
#define NP 176          // padded N for featT rows (11 tiles of 16)
#define INFV 1.0e9f
#define BIGI 0x7FFFFFFF
#define RBW 328         // k_hung LDS cost-row stride BYTES
#define ARRCAP 700

// ws layout (in floats)
#define OFF_T    0                           // bf16 featT [64][176][2048] = 11,534,336 floats
#define OFF_P    11534336                    // [64][32][192] norm^2 partials
#define OFF_QS   (OFF_P + 64*32*192)         // (unused, layout keep)
#define OFF_KS   (OFF_QS + 64*162)           // (unused, layout keep)
#define OFF_COST (OFF_KS + 64*162)           // [64][162][162] RAW sim (fp32)
#define OFF_PD   (OFF_COST + 64*162*162)     // [64] per-batch pos_dis

typedef __attribute__((ext_vector_type(8))) short bf16x8;
typedef __attribute__((ext_vector_type(4))) float f32x4;
typedef __attribute__((ext_vector_type(4))) unsigned u32x4;

static __device__ __forceinline__ unsigned short f2bf(float x) {
    unsigned int u = __builtin_bit_cast(unsigned int, x);
    unsigned int r = (u + 0x7fffu + ((u >> 16) & 1u)) >> 16;   // RNE
    return (unsigned short)r;
}
static __device__ __forceinline__ unsigned short f2h(float x) {
    _Float16 h = (_Float16)x;
    return __builtin_bit_cast(unsigned short, h);
}
static __device__ __forceinline__ float h2f(unsigned short u) {
    return (float)__builtin_bit_cast(_Float16, u);
}
static __device__ __forceinline__ unsigned umin32(unsigned a, unsigned b) { return a < b ? a : b; }
static __device__ __forceinline__ unsigned umax32(unsigned a, unsigned b) { return a > b ? a : b; }
static __device__ __forceinline__ unsigned packnn(float v, int id) {
    float c = fmaxf(v, 0.f);
    return (__builtin_bit_cast(unsigned, c) & 0xFFFFFF00u) | (unsigned)id;
}
static __device__ __forceinline__ float unpacknn(unsigned pk) {
    return __builtin_bit_cast(float, pk & 0xFFFFFF00u);
}
static __device__ __forceinline__ unsigned reduceMin64(unsigned x) {
    int v = (int)x, t;
    t = __builtin_amdgcn_update_dpp(0, v, 0x121, 0xF, 0xF, true); v = (int)umin32((unsigned)v, (unsigned)t);
    t = __builtin_amdgcn_update_dpp(0, v, 0x122, 0xF, 0xF, true); v = (int)umin32((unsigned)v, (unsigned)t);
    t = __builtin_amdgcn_update_dpp(0, v, 0x124, 0xF, 0xF, true); v = (int)umin32((unsigned)v, (unsigned)t);
    t = __builtin_amdgcn_update_dpp(0, v, 0x128, 0xF, 0xF, true); v = (int)umin32((unsigned)v, (unsigned)t);
    unsigned a = (unsigned)__builtin_amdgcn_readlane(v, 0);
    unsigned b = (unsigned)__builtin_amdgcn_readlane(v, 16);
    unsigned c = (unsigned)__builtin_amdgcn_readlane(v, 32);
    unsigned d = (unsigned)__builtin_amdgcn_readlane(v, 48);
    return umin32(umin32(a, b), umin32(c, d));
}
static __device__ __forceinline__ int rlanei(int v, int l) { return __builtin_amdgcn_readlane(v, l); }
static __device__ __forceinline__ float rlanef(float v, int l) {
    return __builtin_bit_cast(float, __builtin_amdgcn_readlane(__builtin_bit_cast(int, v), l));
}
static __device__ __forceinline__ int laneOf(int id) { return id < 128 ? (id >> 1) : (id - 128); }
static __device__ __forceinline__ int slotOf(int id) { return id < 128 ? (id & 1) : 2; }
static __device__ __forceinline__ unsigned long long mask_n(int n) {
    if (n <= 0) return 0ull;
    if (n >= 64) return ~0ull;
    return (1ull << n) - 1ull;
}
#define SEL3(s, a0, a1, a2) ((s) == 0 ? (a0) : ((s) == 1 ? (a1) : (a2)))

// ---------------- K1: pack-at-load transpose + norm^2, float2 loads ----------------
// Thread (pg,c2) owns col pair gc0=ct*64+2*c2 and channels p=pg+8k: two float2
// loads per p (rows 2p,2p+1) -> 512B/wave/instr. Packs channel-pairs to u32.
__global__ __launch_bounds__(256) void k_tr(const float* __restrict__ feat, float* __restrict__ ws) {
    int x = blockIdx.x;            // 0..95: cc = ch-chunk (32), ct = col-chunk (3)
    int cc = x / 3, ct = x % 3;
    int b = blockIdx.y;
    int tid = threadIdx.x;
    int c2 = tid & 31, pg = tid >> 5;         // col-pair 0..31, p-group 0..7
    __shared__ unsigned Tp[32][65];           // packed bf16 ch-pairs [p][col]
    __shared__ float Pp[8][64];               // norm^2 partials
    int gc0 = ct * 64 + 2 * c2;
    bool ok  = (gc0 < Nn);
    bool ok1 = (gc0 + 1 < Nn);
    const float* fb = feat + ((size_t)b * Cn + (size_t)cc * 64) * Nn;
    float s0 = 0.f, s1 = 0.f;
    #pragma unroll
    for (int it = 0; it < 4; ++it) {
        int p = pg + it * 8;                  // 0..31
        float2 fa = {0.f, 0.f}, fc = {0.f, 0.f};
        if (ok) {
            fa = *(const float2*)(fb + (size_t)(2 * p) * Nn + gc0);
            fc = *(const float2*)(fb + (size_t)(2 * p + 1) * Nn + gc0);
            if (!ok1) { fa.y = 0.f; fc.y = 0.f; }
        }
        s0 = fmaf(fa.x, fa.x, fmaf(fc.x, fc.x, s0));
        s1 = fmaf(fa.y, fa.y, fmaf(fc.y, fc.y, s1));
        Tp[p][2 * c2]     = (unsigned)f2bf(fa.x) | ((unsigned)f2bf(fc.x) << 16);
        Tp[p][2 * c2 + 1] = (unsigned)f2bf(fa.y) | ((unsigned)f2bf(fc.y) << 16);
    }
    Pp[pg][2 * c2]     = s0;
    Pp[pg][2 * c2 + 1] = s1;
    __syncthreads();
    if (tid < 64) {
        float t = 0.f;
        #pragma unroll
        for (int g = 0; g < 8; ++g) t += Pp[g][tid];
        ws[OFF_P + ((size_t)b * 32 + cc) * 192 + ct * 64 + tid] = t;
    }
    unsigned* ft = (unsigned*)(ws + OFF_T);
    #pragma unroll
    for (int it = 0; it < 8; ++it) {
        int idx = it * 256 + tid;
        int c = idx >> 5, p = idx & 31;
        int gcol = ct * 64 + c;
        if (gcol < NP) {
            ft[(size_t)(b * NP + gcol) * 1024 + cc * 32 + p] = Tp[p][c];
        }
    }
}

// ---------------- K2: bf16 MFMA GEMM from featT -> RAW sim ----------------
// 6 blocks/batch (32-row tiles), XCD-chunked. Block 4 waves; tile 32 x 176.
__global__ __launch_bounds__(256) void k_mm(const int* __restrict__ pos_ind,
                                            float* __restrict__ ws) {
    int wg = blockIdx.x;
    int xcd = wg & 7, kk = wg >> 3;
    int b  = xcd + 8 * (kk / 6);
    int mt = kk % 6;
    int tid = threadIdx.x;
    int lane = tid & 63, w = tid >> 6;
    int q0 = mt * 32;
    int pb = pos_ind[b];
    const u32x4* At = (const u32x4*)((const unsigned short*)(ws + OFF_T) + (size_t)b  * NP * Cn);
    const u32x4* Bt = (const u32x4*)((const unsigned short*)(ws + OFF_T) + (size_t)pb * NP * Cn);
    __shared__ u32x4 As[32 * 16];
    __shared__ u32x4 Bs[192 * 16];

    f32x4 a00 = {0.f, 0.f, 0.f, 0.f}, a01 = a00, a02 = a00, a10 = a00, a11 = a00, a12 = a00;
    const int ct0 = w * 3, ct1 = w * 3 + 1, ct2 = w * 3 + 2;
    const int fr = lane & 15, fq = lane >> 4;

    for (int c0 = 0; c0 < Cn; c0 += 128) {
        int g0 = c0 >> 3;
        #pragma unroll
        for (int it = 0; it < 2; ++it) {
            int task = it * 256 + tid;
            int r = task >> 4, g = task & 15;
            int rowc = q0 + r; if (rowc > NP - 1) rowc = NP - 1;
            As[r * 16 + (g ^ (r & 15))] = At[(size_t)rowc * 256 + g0 + g];
        }
        #pragma unroll
        for (int it = 0; it < 12; ++it) {
            int task = it * 256 + tid;
            int col = task >> 4, g = task & 15;
            int rowc = col; if (rowc > NP - 1) rowc = NP - 1;
            Bs[col * 16 + (g ^ (col & 15))] = Bt[(size_t)rowc * 256 + g0 + g];
        }
        __syncthreads();
        #pragma unroll
        for (int ks = 0; ks < 4; ++ks) {
            int gk = ks * 4 + fq;
            bf16x8 af0 = *(const bf16x8*)&As[fr * 16 + (gk ^ fr)];
            bf16x8 af1 = *(const bf16x8*)&As[(16 + fr) * 16 + (gk ^ fr)];
            bf16x8 b0 = *(const bf16x8*)&Bs[(ct0 * 16 + fr) * 16 + (gk ^ fr)];
            bf16x8 b1 = *(const bf16x8*)&Bs[(ct1 * 16 + fr) * 16 + (gk ^ fr)];
            bf16x8 b2 = *(const bf16x8*)&Bs[(ct2 * 16 + fr) * 16 + (gk ^ fr)];
            a00 = __builtin_amdgcn_mfma_f32_16x16x32_bf16(af0, b0, a00, 0, 0, 0);
            a01 = __builtin_amdgcn_mfma_f32_16x16x32_bf16(af0, b1, a01, 0, 0, 0);
            a02 = __builtin_amdgcn_mfma_f32_16x16x32_bf16(af0, b2, a02, 0, 0, 0);
            a10 = __builtin_amdgcn_mfma_f32_16x16x32_bf16(af1, b0, a10, 0, 0, 0);
            a11 = __builtin_amdgcn_mfma_f32_16x16x32_bf16(af1, b1, a11, 0, 0, 0);
            a12 = __builtin_amdgcn_mfma_f32_16x16x32_bf16(af1, b2, a12, 0, 0, 0);
        }
        __syncthreads();
    }

    float* simg = ws + OFF_COST + (size_t)b * Nn * Nn;
    int c0_ = ct0 * 16 + fr, c1_ = ct1 * 16 + fr, c2_ = ct2 * 16 + fr;
    #pragma unroll
    for (int j = 0; j < 4; ++j) {
        int r0 = q0 + fq * 4 + j;
        int r1 = r0 + 16;
        if (r0 < Nn) {
            if (c0_ < Nn) simg[(size_t)r0 * Nn + c0_] = a00[j];
            if (c1_ < Nn) simg[(size_t)r0 * Nn + c1_] = a01[j];
            if (c2_ < Nn) simg[(size_t)r0 * Nn + c2_] = a02[j];
        }
        if (r1 < Nn) {
            if (c0_ < Nn) simg[(size_t)r1 * Nn + c0_] = a10[j];
            if (c1_ < Nn) simg[(size_t)r1 * Nn + c1_] = a11[j];
            if (c2_ < Nn) simg[(size_t)r1 * Nn + c2_] = a12[j];
        }
    }
}

// ---------------- K3: fused stats + rectangular LAPJV ----------------
// Prologue computes per-batch stats (was k_stats). Staging applies
// cost = -(sim*qs[r]*ks[c]) on the fly. 4 waves parallel stage/CR/RTR,
// wave 0 serial ARR/Dijkstra.
__global__ __launch_bounds__(256) void k_hung(float* __restrict__ ws) {
    const int b = blockIdx.x;
    const int tid = threadIdx.x;
    const int lane = tid & 63, wv = tid >> 6;
    __shared__ unsigned short Cw[(Nn * RBW) / 2 + 32];
    __shared__ int rowBest[Nn + 1];
    __shared__ float Ulds[Nn + 1];
    __shared__ float dvA[192];
    __shared__ float pcm[4][192];
    __shared__ int   pim[4][192];
    __shared__ short rowIdxL[Nn];
    __shared__ float qsL[192];
    __shared__ float ksL[192];
    const float* cg = ws + OFF_COST + (size_t)b * Nn * Nn;   // RAW sim

    const bool v2ok = (lane < Nn - 128);     // lane < 34
    const int id0 = 2 * lane, id1 = 2 * lane + 1, id2 = 128 + lane;
    const int a32 = 4 * lane;
    const int a16 = 256 + 2 * lane;

    if (tid <= Nn) { rowBest[tid] = BIGI; Ulds[tid] = 0.f; }
    if (tid < 192) dvA[tid] = 0.f;

    // ---- fused stats (reuses pcm as scratch before CR) ----
    float* arrS = &pcm[0][0];
    float* thrP = &pcm[1][0];
    float normv = 0.f, mvalv = 0.f;
    if (tid < Nn) {
        float s = 0.f;
        #pragma unroll
        for (int ch = 0; ch < 32; ++ch) s += ws[OFF_P + ((size_t)b * 32 + ch) * 192 + tid];
        normv = sqrtf(s);
        arrS[tid] = normv;
    }
    __syncthreads();   // S1
    {
        float mn = INFV, mx = -INFV;
        for (int k = 0; k < Nn; ++k) { float v = arrS[k]; mn = fminf(mn, v); mx = fmaxf(mx, v); }
        if (tid < Nn) mvalv = (normv - mn) / (mx - mn + 1e-12f);
    }
    __syncthreads();   // S2
    if (tid < Nn) arrS[tid] = mvalv;
    __syncthreads();   // S3
    if (tid < Nn) {
        int cl = 0, ce = 0, ceb = 0;
        for (int k = 0; k < Nn; ++k) {
            float v = arrS[k];
            cl  += (v <  mvalv);
            ce  += (v == mvalv);
            ceb += (v == mvalv && k < tid);
        }
        if (cl <= Pn && (cl + ce) > Pn && ceb == 0) thrP[0] = mvalv;
    }
    if (tid < 192) { qsL[tid] = 0.f; ksL[tid] = 0.f; }
    __syncthreads();   // S4
    if (tid < Nn) {
        float inv = 1.f / fmaxf(normv, 1e-12f);
        ksL[tid] = inv;
        qsL[tid] = (mvalv < thrP[0]) ? 0.f : inv;
    }
    __syncthreads();   // S5

    const float ks0f = ksL[id0];
    const float ks1f = ksL[id1];
    const float ks2f = v2ok ? ksL[id2] : 0.f;

    // active-row masks
    float aq0 = qsL[lane];
    float aq1 = qsL[64 + lane];
    float aq2 = v2ok ? qsL[128 + lane] : 0.f;
    unsigned long long act0 = __ballot(aq0 != 0.f);
    unsigned long long act1 = __ballot(aq1 != 0.f);
    unsigned long long act2 = __ballot(v2ok && aq2 != 0.f);
    int n0 = __popcll(act0), n1 = __popcll(act1), n2 = __popcll(act2);
    const int nact = n0 + n1 + n2;
    if (nact == 0) { if (tid == 0) ws[OFF_PD + b] = 1.f; return; }

    if (wv == 0) {   // packed index map (order-preserving)
        unsigned long long lt = (1ull << lane) - 1;
        if ((act0 >> lane) & 1) rowIdxL[__popcll(act0 & lt)] = (short)lane;
        if ((act1 >> lane) & 1) rowIdxL[n0 + __popcll(act1 & lt)] = (short)(64 + lane);
        if (v2ok && ((act2 >> lane) & 1)) rowIdxL[n0 + n1 + __popcll(act2 & lt)] = (short)(128 + lane);
    }
    __syncthreads();   // B1

    // ---- stage packed rows: c = -(sim*qs*ks) as fp16, 4-wave strided ----
    for (int k = wv; k < nact; k += 4) {
        int orig = rowIdxL[k];
        float qsr = qsL[orig];
        float2 f2 = *(const float2*)(cg + (size_t)orig * Nn + 2 * lane);
        unsigned pk = (unsigned)f2h(-(f2.x * qsr * ks0f))
                    | ((unsigned)f2h(-(f2.y * qsr * ks1f)) << 16);
        *(unsigned*)((char*)Cw + k * RBW + a32) = pk;
        if (v2ok) *(unsigned short*)((char*)Cw + k * RBW + a16) =
            f2h(-(cg[(size_t)orig * Nn + 128 + lane] * qsr * ks2f));
    }
    __syncthreads();   // B2

    float cm0 = INFV, cm1 = INFV, cm2 = INFV; int im0 = 0, im1 = 0, im2 = 0;
    for (int k = wv; k < nact; k += 4) {
        unsigned pr = *(const unsigned*)((const char*)Cw + k * RBW + a32);
        float c0 = h2f((unsigned short)pr);
        float c1 = h2f((unsigned short)(pr >> 16));
        float c2 = h2f(*(const unsigned short*)((const char*)Cw + k * RBW + a16));
        if (c0 < cm0) { cm0 = c0; im0 = k + 1; }
        if (c1 < cm1) { cm1 = c1; im1 = k + 1; }
        if (v2ok && c2 < cm2) { cm2 = c2; im2 = k + 1; }
    }
    pcm[wv][id0] = cm0; pim[wv][id0] = im0;
    pcm[wv][id1] = cm1; pim[wv][id1] = im1;
    if (v2ok) { pcm[wv][id2] = cm2; pim[wv][id2] = im2; }
    __syncthreads();   // B3

    cm0 = INFV; im0 = 0; cm1 = INFV; im1 = 0; cm2 = INFV; im2 = 0;
    #pragma unroll
    for (int ww = 0; ww < 4; ++ww) {
        float c; int im;
        c = pcm[ww][id0]; im = pim[ww][id0];
        if (im > 0 && (im0 == 0 || c < cm0 || (c == cm0 && im < im0))) { cm0 = c; im0 = im; }
        c = pcm[ww][id1]; im = pim[ww][id1];
        if (im > 0 && (im1 == 0 || c < cm1 || (c == cm1 && im < im1))) { cm1 = c; im1 = im; }
        if (v2ok) {
            c = pcm[ww][id2]; im = pim[ww][id2];
            if (im > 0 && (im2 == 0 || c < cm2 || (c == cm2 && im < im2))) { cm2 = c; im2 = im; }
        }
    }
    if (wv == 0) {
        if (im0 > 0) atomicMin(&rowBest[im0], id0);
        if (im1 > 0) atomicMin(&rowBest[im1], id1);
        if (v2ok && im2 > 0) atomicMin(&rowBest[im2], id2);
    }
    __syncthreads();   // B4

    float v0 = cm0, v1 = cm1, v2 = v2ok ? cm2 : 0.f;
    int Pa0 = (im0 > 0 && rowBest[im0] == id0) ? im0 : 0;
    int Pa1 = (im1 > 0 && rowBest[im1] == id1) ? im1 : 0;
    int Pa2 = (v2ok && im2 > 0 && rowBest[im2] == id2) ? im2 : 0;

    unsigned long long cb0 = __ballot(lane + 1 <= nact && rowBest[lane + 1] != BIGI);
    unsigned long long cb1 = __ballot(lane + 65 <= nact && rowBest[lane + 65] != BIGI);
    unsigned long long cb2 = __ballot(lane + 129 <= nact && rowBest[lane + 129] != BIGI);
    unsigned long long fr0 = mask_n(nact)       & ~cb0;
    unsigned long long fr1 = mask_n(nact - 64)  & ~cb1;
    unsigned long long fr2 = mask_n(nact - 128) & ~cb2;

    for (int k = wv; k < nact; k += 4) {
        int j1c = rowBest[k + 1];
        if (j1c == BIGI) continue;
        int roff = k * RBW;
        unsigned pr = *(const unsigned*)((const char*)Cw + roff + a32);
        float r0 = h2f((unsigned short)pr) - v0;
        float r1 = h2f((unsigned short)(pr >> 16)) - v1;
        float r2 = h2f(*(const unsigned short*)((const char*)Cw + roff + a16)) - v2;
        unsigned p0 = (id0 == j1c) ? 0xFFFFFFFFu : packnn(r0, id0);
        unsigned p1 = (id1 == j1c) ? 0xFFFFFFFFu : packnn(r1, id1);
        unsigned p2 = (v2ok && id2 != j1c) ? packnn(r2, id2) : 0xFFFFFFFFu;
        unsigned pk = reduceMin64(umin32(p0, umin32(p1, p2)));
        float min2 = unpacknn(pk);
        if (lane == 0) { dvA[j1c] = min2; Ulds[k + 1] = min2; }
    }
    __syncthreads();   // B5 — last barrier; waves 1-3 retire
    if (wv != 0) return;

    float ur0, ur1, ur2;
    v0 -= dvA[id0]; ur0 = dvA[id0];
    v1 -= dvA[id1]; ur1 = dvA[id1];
    if (v2ok) { v2 -= dvA[id2]; ur2 = dvA[id2]; } else ur2 = 0.f;

    float minv0 = INFV, minv1 = INFV, minv2 = INFV;
    int way0 = 255, way1 = 255, way2 = 255;
    bool used0 = false, used1 = false, used2 = false;

    unsigned long long nx0 = 0, nx1 = 0, nx2 = 0;
    int arrIt = 0;
    for (int pass = 0; pass < 2; ++pass) {
        while ((fr0 | fr1 | fr2) != 0 && arrIt < ARRCAP) {
            ++arrIt;
            int i;
            if (fr0)      { int t = __builtin_ctzll(fr0); i = t + 1;   fr0 &= fr0 - 1; }
            else if (fr1) { int t = __builtin_ctzll(fr1); i = t + 65;  fr1 &= fr1 - 1; }
            else          { int t = __builtin_ctzll(fr2); i = t + 129; fr2 &= fr2 - 1; }
            int roff = (i - 1) * RBW;
            unsigned pr = *(const unsigned*)((const char*)Cw + roff + a32);
            float r0 = h2f((unsigned short)pr) - v0;
            float r1 = h2f((unsigned short)(pr >> 16)) - v1;
            float r2 = h2f(*(const unsigned short*)((const char*)Cw + roff + a16)) - v2;
            unsigned p0 = packnn(r0, id0);
            unsigned p1 = packnn(r1, id1);
            unsigned p2 = v2ok ? packnn(r2, id2) : 0xFFFFFFFFu;
            unsigned lmin = umin32(p0, umin32(p1, p2));
            unsigned lmed = umin32(umax32(p0, p1), umax32(umin32(p0, p1), p2));
            unsigned M1 = reduceMin64(lmin);
            unsigned M2 = reduceMin64(lmin == M1 ? lmed : lmin);
            int j1 = (int)(M1 & 0xFFu), j2 = (int)(M2 & 0xFFu);
            int l1 = laneOf(j1), s1 = slotOf(j1);
            int l2 = laneOf(j2), s2 = slotOf(j2);
            float umin_e = rlanef(SEL3(s1, r0, r1, r2), l1);
            float usub_e = rlanef(SEL3(s2, r0, r1, r2), l2);
            int iA = rlanei(SEL3(s1, Pa0, Pa1, Pa2), l1);
            int iB = rlanei(SEL3(s2, Pa0, Pa1, Pa2), l2);
            if (usub_e < umin_e) {
                int tj = j1; j1 = j2; j2 = tj;
                int tl = l1; l1 = l2; l2 = tl;
                int ts = s1; s1 = s2; s2 = ts;
                float tv = umin_e; umin_e = usub_e; usub_e = tv;
                int ti = iA; iA = iB; iB = ti;
            }
            bool strict = (umin_e < usub_e);
            int jt, idisp;
            float ua = usub_e;
            if (strict) {
                float d = usub_e - umin_e;
                if (lane == l1) { if (s1 == 0) v0 -= d; else if (s1 == 1) v1 -= d; else v2 -= d; }
                jt = j1; idisp = iA;
            } else if (iA > 0) {
                jt = j2; idisp = iB;
            } else {
                jt = j1; idisp = 0;
            }
            int lt = laneOf(jt), st = slotOf(jt);
            if (lane == lt) {
                if (st == 0)      { Pa0 = i; ur0 = ua; }
                else if (st == 1) { Pa1 = i; ur1 = ua; }
                else              { Pa2 = i; ur2 = ua; }
            }
            if (lane == 0) Ulds[i] = ua;
            if (idisp > 0) {
                if (strict) {
                    if (idisp <= 64)       fr0 |= 1ull << (idisp - 1);
                    else if (idisp <= 128) fr1 |= 1ull << (idisp - 65);
                    else                   fr2 |= 1ull << (idisp - 129);
                } else {
                    if (idisp <= 64)       nx0 |= 1ull << (idisp - 1);
                    else if (idisp <= 128) nx1 |= 1ull << (idisp - 65);
                    else                   nx2 |= 1ull << (idisp - 129);
                }
            }
        }
        fr0 |= nx0; fr1 |= nx1; fr2 |= nx2;
        nx0 = nx1 = nx2 = 0;
    }

    while ((fr0 | fr1 | fr2) != 0) {
        int i;
        if (fr0)      { int t = __builtin_ctzll(fr0); i = t + 1;   fr0 &= fr0 - 1; }
        else if (fr1) { int t = __builtin_ctzll(fr1); i = t + 65;  fr1 &= fr1 - 1; }
        else          { int t = __builtin_ctzll(fr2); i = t + 129; fr2 &= fr2 - 1; }
        float u_root = Ulds[i];
        minv0 = minv1 = minv2 = INFV;
        way0 = way1 = way2 = 255;
        used0 = used1 = used2 = false;
        {
            int roff = (i - 1) * RBW;
            unsigned pr = *(const unsigned*)((const char*)Cw + roff + a32);
            float c0 = h2f((unsigned short)pr);
            float c1 = h2f((unsigned short)(pr >> 16));
            float c2 = h2f(*(const unsigned short*)((const char*)Cw + roff + a16));
            minv0 = c0 - (u_root + v0);
            minv1 = c1 - (u_root + v1);
            minv2 = v2ok ? (c2 - (u_root + v2)) : INFV;
        }
        int jend = -1;
        for (int it = 0; it < Nn + 2; ++it) {
            unsigned q0p = used0 ? 0xFFFFFFFFu : packnn(minv0, id0);
            unsigned q1p = used1 ? 0xFFFFFFFFu : packnn(minv1, id1);
            unsigned q2p = (v2ok && !used2) ? packnn(minv2, id2) : 0xFFFFFFFFu;
            unsigned pk = reduceMin64(umin32(q0p, umin32(q1p, q2p)));
            int j1 = (int)(pk & 0xFFu);
            float delta = unpacknn(pk);
            int l1 = laneOf(j1), s1 = slotOf(j1);
            int i1 = rlanei(SEL3(s1, Pa0, Pa1, Pa2), l1);
            float u1 = rlanef(SEL3(s1, ur0, ur1, ur2), l1);
            u_root += delta;
            v0 = used0 ? v0 - delta : v0;  ur0 = used0 ? ur0 + delta : ur0;  minv0 = used0 ? minv0 : minv0 - delta;
            v1 = used1 ? v1 - delta : v1;  ur1 = used1 ? ur1 + delta : ur1;  minv1 = used1 ? minv1 : minv1 - delta;
            v2 = used2 ? v2 - delta : v2;  ur2 = used2 ? ur2 + delta : ur2;  minv2 = used2 ? minv2 : minv2 - delta;
            bool hit = (lane == l1);
            if (s1 == 0) used0 |= hit; else if (s1 == 1) used1 |= hit; else used2 |= hit;
            if (i1 == 0) { jend = j1; break; }
            int roff = (i1 - 1) * RBW;
            unsigned pr = *(const unsigned*)((const char*)Cw + roff + a32);
            float c0 = h2f((unsigned short)pr);
            float c1 = h2f((unsigned short)(pr >> 16));
            float c2 = h2f(*(const unsigned short*)((const char*)Cw + roff + a16));
            float n0_ = c0 - (u1 + v0), n1_ = c1 - (u1 + v1), n2_ = c2 - (u1 + v2);
            if (!used0 && n0_ < minv0) { minv0 = n0_; way0 = j1; }
            if (!used1 && n1_ < minv1) { minv1 = n1_; way1 = j1; }
            if (v2ok && !used2 && n2_ < minv2) { minv2 = n2_; way2 = j1; }
        }
        int j = jend;
        while (j >= 0) {
            int l = laneOf(j), s = slotOf(j);
            int w = rlanei(SEL3(s, way0, way1, way2), l);
            int pnew; float unew;
            if (w == 255) { pnew = i; unew = u_root; }
            else {
                int lw = laneOf(w), sw = slotOf(w);
                pnew = rlanei(SEL3(sw, Pa0, Pa1, Pa2), lw);
                unew = rlanef(SEL3(sw, ur0, ur1, ur2), lw);
            }
            if (lane == l) {
                if (s == 0)      { Pa0 = pnew; ur0 = unew; }
                else if (s == 1) { Pa1 = pnew; ur1 = unew; }
                else             { Pa2 = pnew; ur2 = unew; }
            }
            j = (w == 255) ? -1 : w;
        }
    }

    // ---- assigned-sim sum from fp32 raw sim * scales ----
    float tot = 0.f;
    if (Pa0 > 0) { int orig = rowIdxL[Pa0 - 1]; tot += cg[(size_t)orig * Nn + id0] * qsL[orig] * ks0f; }
    if (Pa1 > 0) { int orig = rowIdxL[Pa1 - 1]; tot += cg[(size_t)orig * Nn + id1] * qsL[orig] * ks1f; }
    if (v2ok && Pa2 > 0) { int orig = rowIdxL[Pa2 - 1]; tot += cg[(size_t)orig * Nn + id2] * qsL[orig] * ks2f; }
    #pragma unroll
    for (int off = 32; off; off >>= 1) tot += __shfl_xor(tot, off);
    if (lane == 0) ws[OFF_PD + b] = 1.f - tot * (1.f / (float)Pn);
}

// ---------------- K4: mean over batches ----------------
__global__ void k_final(const float* __restrict__ ws, float* __restrict__ out) {
    float v = ws[OFF_PD + threadIdx.x];
    #pragma unroll
    for (int off = 32; off; off >>= 1) v += __shfl_xor(v, off);
    if (threadIdx.x == 0) out[0] = v * (1.f / 64.f);
}

extern "C" void kernel_launch(void* const* d_in, const int* in_sizes, int n_in,
                              void* d_out, int out_size, void* d_ws, size_t ws_size,
                              hipStream_t stream) {
    const float* feat = (const float*)d_in[0];
    const int*   pos  = (const int*)d_in[1];
    float* ws  = (float*)d_ws;
    float* out = (float*)d_out;
    k_tr   <<<dim3(96, 64), 256, 0, stream>>>(feat, ws);
    k_mm   <<<384, 256, 0, stream>>>(pos, ws);
    k_hung <<<64, 256, 0, stream>>>(ws);
    k_final<<<1, 64, 0, stream>>>(ws, out);
}

// Round 11
// 102.801 us; speedup vs baseline: 100.8624x; 1.0075x over previous
//
#include <hip/hip_runtime.h>
#include <hip/hip_bf16.h>

#define Bn 64
#define Cn 2048
#define Nn 162          // H*W = 18*9
#define Pn 81           // Nn/2
#define NP 176          // padded N for featT rows (11 tiles of 16)
#define INFV 1.0e9f
#define BIGI 0x7FFFFFFF
#define RBW 328         // k_hung LDS cost-row stride BYTES
#define ARRCAP 700

// ws layout (in floats)
#define OFF_T    0                           // bf16 featT [64][176][2048] = 11,534,336 floats
#define OFF_P    11534336                    // [64][32][192] norm^2 partials
#define OFF_QS   (OFF_P + 64*32*192)         // (unused, layout keep)
#define OFF_KS   (OFF_QS + 64*162)           // (unused, layout keep)
#define OFF_COST (OFF_KS + 64*162)           // [64][162][162] RAW sim (fp32)
#define OFF_PD   (OFF_COST + 64*162*162)     // [64] per-batch pos_dis

typedef __attribute__((ext_vector_type(8))) short bf16x8;
typedef __attribute__((ext_vector_type(4))) float f32x4;
typedef __attribute__((ext_vector_type(4))) unsigned u32x4;

static __device__ __forceinline__ unsigned short f2bf(float x) {
    unsigned int u = __builtin_bit_cast(unsigned int, x);
    unsigned int r = (u + 0x7fffu + ((u >> 16) & 1u)) >> 16;   // RNE
    return (unsigned short)r;
}
static __device__ __forceinline__ unsigned short f2h(float x) {
    _Float16 h = (_Float16)x;
    return __builtin_bit_cast(unsigned short, h);
}
static __device__ __forceinline__ float h2f(unsigned short u) {
    return (float)__builtin_bit_cast(_Float16, u);
}
static __device__ __forceinline__ unsigned umin32(unsigned a, unsigned b) { return a < b ? a : b; }
static __device__ __forceinline__ unsigned umax32(unsigned a, unsigned b) { return a > b ? a : b; }
static __device__ __forceinline__ unsigned packnn(float v, int id) {
    float c = fmaxf(v, 0.f);
    return (__builtin_bit_cast(unsigned, c) & 0xFFFFFF00u) | (unsigned)id;
}
static __device__ __forceinline__ float unpacknn(unsigned pk) {
    return __builtin_bit_cast(float, pk & 0xFFFFFF00u);
}
static __device__ __forceinline__ unsigned reduceMin64(unsigned x) {
    int v = (int)x, t;
    t = __builtin_amdgcn_update_dpp(0, v, 0x121, 0xF, 0xF, true); v = (int)umin32((unsigned)v, (unsigned)t);
    t = __builtin_amdgcn_update_dpp(0, v, 0x122, 0xF, 0xF, true); v = (int)umin32((unsigned)v, (unsigned)t);
    t = __builtin_amdgcn_update_dpp(0, v, 0x124, 0xF, 0xF, true); v = (int)umin32((unsigned)v, (unsigned)t);
    t = __builtin_amdgcn_update_dpp(0, v, 0x128, 0xF, 0xF, true); v = (int)umin32((unsigned)v, (unsigned)t);
    unsigned a = (unsigned)__builtin_amdgcn_readlane(v, 0);
    unsigned b = (unsigned)__builtin_amdgcn_readlane(v, 16);
    unsigned c = (unsigned)__builtin_amdgcn_readlane(v, 32);
    unsigned d = (unsigned)__builtin_amdgcn_readlane(v, 48);
    return umin32(umin32(a, b), umin32(c, d));
}
static __device__ __forceinline__ int rlanei(int v, int l) { return __builtin_amdgcn_readlane(v, l); }
static __device__ __forceinline__ float rlanef(float v, int l) {
    return __builtin_bit_cast(float, __builtin_amdgcn_readlane(__builtin_bit_cast(int, v), l));
}
static __device__ __forceinline__ int laneOf(int id) { return id < 128 ? (id >> 1) : (id - 128); }
static __device__ __forceinline__ int slotOf(int id) { return id < 128 ? (id & 1) : 2; }
static __device__ __forceinline__ unsigned long long mask_n(int n) {
    if (n <= 0) return 0ull;
    if (n >= 64) return ~0ull;
    return (1ull << n) - 1ull;
}
#define SEL3(s, a0, a1, a2) ((s) == 0 ? (a0) : ((s) == 1 ? (a1) : (a2)))

// ---------------- K1: pack-at-load transpose + norm^2, MLP-restructured ----------------
// Phase 1: ALL 8 global loads issued back-to-back into registers (max loads in
// flight per wave). Phase 2: convert/pack/LDS-write + register norm^2.
__global__ __launch_bounds__(256) void k_tr(const float* __restrict__ feat, float* __restrict__ ws) {
    int x = blockIdx.x;            // 0..95: cc = ch-chunk (32), ct = col-chunk (3)
    int cc = x / 3, ct = x % 3;
    int b = blockIdx.y;
    int tid = threadIdx.x;
    int c2 = tid & 31, pg = tid >> 5;         // col-pair 0..31, p-group 0..7
    __shared__ unsigned Tp[32][65];           // packed bf16 ch-pairs [p][col]
    __shared__ float Pp[8][64];               // norm^2 partials
    int gc0 = ct * 64 + 2 * c2;
    bool ok  = (gc0 < Nn);
    bool ok1 = (gc0 + 1 < Nn);
    int gcs = ok ? gc0 : 0;                   // clamp addr, mask values later
    const float* fb = feat + ((size_t)b * Cn + (size_t)cc * 64) * Nn;
    float2 fa[4], fc[4];
    #pragma unroll
    for (int it = 0; it < 4; ++it) {          // pure load phase: 8 loads in flight
        int p = pg + it * 8;
        fa[it] = *(const float2*)(fb + (size_t)(2 * p) * Nn + gcs);
        fc[it] = *(const float2*)(fb + (size_t)(2 * p + 1) * Nn + gcs);
    }
    float s0 = 0.f, s1 = 0.f;
    #pragma unroll
    for (int it = 0; it < 4; ++it) {          // convert/pack/store phase
        int p = pg + it * 8;
        float ax = ok  ? fa[it].x : 0.f;
        float ay = ok1 ? fa[it].y : 0.f;
        float cx = ok  ? fc[it].x : 0.f;
        float cy = ok1 ? fc[it].y : 0.f;
        s0 = fmaf(ax, ax, fmaf(cx, cx, s0));
        s1 = fmaf(ay, ay, fmaf(cy, cy, s1));
        Tp[p][2 * c2]     = (unsigned)f2bf(ax) | ((unsigned)f2bf(cx) << 16);
        Tp[p][2 * c2 + 1] = (unsigned)f2bf(ay) | ((unsigned)f2bf(cy) << 16);
    }
    Pp[pg][2 * c2]     = s0;
    Pp[pg][2 * c2 + 1] = s1;
    __syncthreads();
    if (tid < 64) {
        float t = 0.f;
        #pragma unroll
        for (int g = 0; g < 8; ++g) t += Pp[g][tid];
        ws[OFF_P + ((size_t)b * 32 + cc) * 192 + ct * 64 + tid] = t;
    }
    unsigned* ft = (unsigned*)(ws + OFF_T);
    #pragma unroll
    for (int it = 0; it < 8; ++it) {
        int idx = it * 256 + tid;
        int c = idx >> 5, p = idx & 31;
        int gcol = ct * 64 + c;
        if (gcol < NP) {
            ft[(size_t)(b * NP + gcol) * 1024 + cc * 32 + p] = Tp[p][c];
        }
    }
}

// ---------------- K2: bf16 MFMA GEMM from featT -> RAW sim ----------------
// 6 blocks/batch (32-row tiles), XCD-chunked. Bs trimmed to 176 real rows:
// LDS 53.2 KB -> 3 blocks/CU (12 waves/CU). Tile 11 skipped via has2 guard.
__global__ __launch_bounds__(256) void k_mm(const int* __restrict__ pos_ind,
                                            float* __restrict__ ws) {
    int wg = blockIdx.x;
    int xcd = wg & 7, kk = wg >> 3;
    int b  = xcd + 8 * (kk / 6);
    int mt = kk % 6;
    int tid = threadIdx.x;
    int lane = tid & 63, w = tid >> 6;
    int q0 = mt * 32;
    int pb = pos_ind[b];
    const u32x4* At = (const u32x4*)((const unsigned short*)(ws + OFF_T) + (size_t)b  * NP * Cn);
    const u32x4* Bt = (const u32x4*)((const unsigned short*)(ws + OFF_T) + (size_t)pb * NP * Cn);
    __shared__ u32x4 As[32 * 16];      // 8 KB
    __shared__ u32x4 Bs[176 * 16];     // 44 KB (real rows only)

    f32x4 a00 = {0.f, 0.f, 0.f, 0.f}, a01 = a00, a02 = a00, a10 = a00, a11 = a00, a12 = a00;
    const int ct0 = w * 3, ct1 = w * 3 + 1, ct2 = w * 3 + 2;
    const bool has2 = (ct2 < 11);      // wave-uniform: wave 3 has only tiles 9,10
    const int fr = lane & 15, fq = lane >> 4;

    for (int c0 = 0; c0 < Cn; c0 += 128) {
        int g0 = c0 >> 3;
        #pragma unroll
        for (int it = 0; it < 2; ++it) {
            int task = it * 256 + tid;
            int r = task >> 4, g = task & 15;
            int rowc = q0 + r; if (rowc > NP - 1) rowc = NP - 1;
            As[r * 16 + (g ^ (r & 15))] = At[(size_t)rowc * 256 + g0 + g];
        }
        #pragma unroll
        for (int it = 0; it < 11; ++it) {          // 176 x 16 = 2816 tasks exactly
            int task = it * 256 + tid;
            int col = task >> 4, g = task & 15;
            Bs[col * 16 + (g ^ (col & 15))] = Bt[(size_t)col * 256 + g0 + g];
        }
        __syncthreads();
        #pragma unroll
        for (int ks = 0; ks < 4; ++ks) {
            int gk = ks * 4 + fq;
            bf16x8 af0 = *(const bf16x8*)&As[fr * 16 + (gk ^ fr)];
            bf16x8 af1 = *(const bf16x8*)&As[(16 + fr) * 16 + (gk ^ fr)];
            bf16x8 b0 = *(const bf16x8*)&Bs[(ct0 * 16 + fr) * 16 + (gk ^ fr)];
            bf16x8 b1 = *(const bf16x8*)&Bs[(ct1 * 16 + fr) * 16 + (gk ^ fr)];
            a00 = __builtin_amdgcn_mfma_f32_16x16x32_bf16(af0, b0, a00, 0, 0, 0);
            a01 = __builtin_amdgcn_mfma_f32_16x16x32_bf16(af0, b1, a01, 0, 0, 0);
            a10 = __builtin_amdgcn_mfma_f32_16x16x32_bf16(af1, b0, a10, 0, 0, 0);
            a11 = __builtin_amdgcn_mfma_f32_16x16x32_bf16(af1, b1, a11, 0, 0, 0);
            if (has2) {
                bf16x8 b2 = *(const bf16x8*)&Bs[(ct2 * 16 + fr) * 16 + (gk ^ fr)];
                a02 = __builtin_amdgcn_mfma_f32_16x16x32_bf16(af0, b2, a02, 0, 0, 0);
                a12 = __builtin_amdgcn_mfma_f32_16x16x32_bf16(af1, b2, a12, 0, 0, 0);
            }
        }
        __syncthreads();
    }

    float* simg = ws + OFF_COST + (size_t)b * Nn * Nn;
    int c0_ = ct0 * 16 + fr, c1_ = ct1 * 16 + fr, c2_ = ct2 * 16 + fr;
    #pragma unroll
    for (int j = 0; j < 4; ++j) {
        int r0 = q0 + fq * 4 + j;
        int r1 = r0 + 16;
        if (r0 < Nn) {
            if (c0_ < Nn) simg[(size_t)r0 * Nn + c0_] = a00[j];
            if (c1_ < Nn) simg[(size_t)r0 * Nn + c1_] = a01[j];
            if (has2 && c2_ < Nn) simg[(size_t)r0 * Nn + c2_] = a02[j];
        }
        if (r1 < Nn) {
            if (c0_ < Nn) simg[(size_t)r1 * Nn + c0_] = a10[j];
            if (c1_ < Nn) simg[(size_t)r1 * Nn + c1_] = a11[j];
            if (has2 && c2_ < Nn) simg[(size_t)r1 * Nn + c2_] = a12[j];
        }
    }
}

// ---------------- K3: fused stats + rectangular LAPJV ----------------
__global__ __launch_bounds__(256) void k_hung(float* __restrict__ ws) {
    const int b = blockIdx.x;
    const int tid = threadIdx.x;
    const int lane = tid & 63, wv = tid >> 6;
    __shared__ unsigned short Cw[(Nn * RBW) / 2 + 32];
    __shared__ int rowBest[Nn + 1];
    __shared__ float Ulds[Nn + 1];
    __shared__ float dvA[192];
    __shared__ float pcm[4][192];
    __shared__ int   pim[4][192];
    __shared__ short rowIdxL[Nn];
    __shared__ float qsL[192];
    __shared__ float ksL[192];
    const float* cg = ws + OFF_COST + (size_t)b * Nn * Nn;   // RAW sim

    const bool v2ok = (lane < Nn - 128);     // lane < 34
    const int id0 = 2 * lane, id1 = 2 * lane + 1, id2 = 128 + lane;
    const int a32 = 4 * lane;
    const int a16 = 256 + 2 * lane;

    if (tid <= Nn) { rowBest[tid] = BIGI; Ulds[tid] = 0.f; }
    if (tid < 192) dvA[tid] = 0.f;

    // ---- fused stats ----
    float* arrS = &pcm[0][0];
    float* thrP = &pcm[1][0];
    float normv = 0.f, mvalv = 0.f;
    if (tid < Nn) {
        float s = 0.f;
        #pragma unroll
        for (int ch = 0; ch < 32; ++ch) s += ws[OFF_P + ((size_t)b * 32 + ch) * 192 + tid];
        normv = sqrtf(s);
        arrS[tid] = normv;
    }
    __syncthreads();   // S1
    {
        float mn = INFV, mx = -INFV;
        for (int k = 0; k < Nn; ++k) { float v = arrS[k]; mn = fminf(mn, v); mx = fmaxf(mx, v); }
        if (tid < Nn) mvalv = (normv - mn) / (mx - mn + 1e-12f);
    }
    __syncthreads();   // S2
    if (tid < Nn) arrS[tid] = mvalv;
    __syncthreads();   // S3
    if (tid < Nn) {
        int cl = 0, ce = 0, ceb = 0;
        for (int k = 0; k < Nn; ++k) {
            float v = arrS[k];
            cl  += (v <  mvalv);
            ce  += (v == mvalv);
            ceb += (v == mvalv && k < tid);
        }
        if (cl <= Pn && (cl + ce) > Pn && ceb == 0) thrP[0] = mvalv;
    }
    if (tid < 192) { qsL[tid] = 0.f; ksL[tid] = 0.f; }
    __syncthreads();   // S4
    if (tid < Nn) {
        float inv = 1.f / fmaxf(normv, 1e-12f);
        ksL[tid] = inv;
        qsL[tid] = (mvalv < thrP[0]) ? 0.f : inv;
    }
    __syncthreads();   // S5

    const float ks0f = ksL[id0];
    const float ks1f = ksL[id1];
    const float ks2f = v2ok ? ksL[id2] : 0.f;

    float aq0 = qsL[lane];
    float aq1 = qsL[64 + lane];
    float aq2 = v2ok ? qsL[128 + lane] : 0.f;
    unsigned long long act0 = __ballot(aq0 != 0.f);
    unsigned long long act1 = __ballot(aq1 != 0.f);
    unsigned long long act2 = __ballot(v2ok && aq2 != 0.f);
    int n0 = __popcll(act0), n1 = __popcll(act1), n2 = __popcll(act2);
    const int nact = n0 + n1 + n2;
    if (nact == 0) { if (tid == 0) ws[OFF_PD + b] = 1.f; return; }

    if (wv == 0) {
        unsigned long long lt = (1ull << lane) - 1;
        if ((act0 >> lane) & 1) rowIdxL[__popcll(act0 & lt)] = (short)lane;
        if ((act1 >> lane) & 1) rowIdxL[n0 + __popcll(act1 & lt)] = (short)(64 + lane);
        if (v2ok && ((act2 >> lane) & 1)) rowIdxL[n0 + n1 + __popcll(act2 & lt)] = (short)(128 + lane);
    }
    __syncthreads();   // B1

    for (int k = wv; k < nact; k += 4) {
        int orig = rowIdxL[k];
        float qsr = qsL[orig];
        float2 f2 = *(const float2*)(cg + (size_t)orig * Nn + 2 * lane);
        unsigned pk = (unsigned)f2h(-(f2.x * qsr * ks0f))
                    | ((unsigned)f2h(-(f2.y * qsr * ks1f)) << 16);
        *(unsigned*)((char*)Cw + k * RBW + a32) = pk;
        if (v2ok) *(unsigned short*)((char*)Cw + k * RBW + a16) =
            f2h(-(cg[(size_t)orig * Nn + 128 + lane] * qsr * ks2f));
    }
    __syncthreads();   // B2

    float cm0 = INFV, cm1 = INFV, cm2 = INFV; int im0 = 0, im1 = 0, im2 = 0;
    for (int k = wv; k < nact; k += 4) {
        unsigned pr = *(const unsigned*)((const char*)Cw + k * RBW + a32);
        float c0 = h2f((unsigned short)pr);
        float c1 = h2f((unsigned short)(pr >> 16));
        float c2 = h2f(*(const unsigned short*)((const char*)Cw + k * RBW + a16));
        if (c0 < cm0) { cm0 = c0; im0 = k + 1; }
        if (c1 < cm1) { cm1 = c1; im1 = k + 1; }
        if (v2ok && c2 < cm2) { cm2 = c2; im2 = k + 1; }
    }
    pcm[wv][id0] = cm0; pim[wv][id0] = im0;
    pcm[wv][id1] = cm1; pim[wv][id1] = im1;
    if (v2ok) { pcm[wv][id2] = cm2; pim[wv][id2] = im2; }
    __syncthreads();   // B3

    cm0 = INFV; im0 = 0; cm1 = INFV; im1 = 0; cm2 = INFV; im2 = 0;
    #pragma unroll
    for (int ww = 0; ww < 4; ++ww) {
        float c; int im;
        c = pcm[ww][id0]; im = pim[ww][id0];
        if (im > 0 && (im0 == 0 || c < cm0 || (c == cm0 && im < im0))) { cm0 = c; im0 = im; }
        c = pcm[ww][id1]; im = pim[ww][id1];
        if (im > 0 && (im1 == 0 || c < cm1 || (c == cm1 && im < im1))) { cm1 = c; im1 = im; }
        if (v2ok) {
            c = pcm[ww][id2]; im = pim[ww][id2];
            if (im > 0 && (im2 == 0 || c < cm2 || (c == cm2 && im < im2))) { cm2 = c; im2 = im; }
        }
    }
    if (wv == 0) {
        if (im0 > 0) atomicMin(&rowBest[im0], id0);
        if (im1 > 0) atomicMin(&rowBest[im1], id1);
        if (v2ok && im2 > 0) atomicMin(&rowBest[im2], id2);
    }
    __syncthreads();   // B4

    float v0 = cm0, v1 = cm1, v2 = v2ok ? cm2 : 0.f;
    int Pa0 = (im0 > 0 && rowBest[im0] == id0) ? im0 : 0;
    int Pa1 = (im1 > 0 && rowBest[im1] == id1) ? im1 : 0;
    int Pa2 = (v2ok && im2 > 0 && rowBest[im2] == id2) ? im2 : 0;

    unsigned long long cb0 = __ballot(lane + 1 <= nact && rowBest[lane + 1] != BIGI);
    unsigned long long cb1 = __ballot(lane + 65 <= nact && rowBest[lane + 65] != BIGI);
    unsigned long long cb2 = __ballot(lane + 129 <= nact && rowBest[lane + 129] != BIGI);
    unsigned long long fr0 = mask_n(nact)       & ~cb0;
    unsigned long long fr1 = mask_n(nact - 64)  & ~cb1;
    unsigned long long fr2 = mask_n(nact - 128) & ~cb2;

    for (int k = wv; k < nact; k += 4) {
        int j1c = rowBest[k + 1];
        if (j1c == BIGI) continue;
        int roff = k * RBW;
        unsigned pr = *(const unsigned*)((const char*)Cw + roff + a32);
        float r0 = h2f((unsigned short)pr) - v0;
        float r1 = h2f((unsigned short)(pr >> 16)) - v1;
        float r2 = h2f(*(const unsigned short*)((const char*)Cw + roff + a16)) - v2;
        unsigned p0 = (id0 == j1c) ? 0xFFFFFFFFu : packnn(r0, id0);
        unsigned p1 = (id1 == j1c) ? 0xFFFFFFFFu : packnn(r1, id1);
        unsigned p2 = (v2ok && id2 != j1c) ? packnn(r2, id2) : 0xFFFFFFFFu;
        unsigned pk = reduceMin64(umin32(p0, umin32(p1, p2)));
        float min2 = unpacknn(pk);
        if (lane == 0) { dvA[j1c] = min2; Ulds[k + 1] = min2; }
    }
    __syncthreads();   // B5 — last barrier; waves 1-3 retire
    if (wv != 0) return;

    float ur0, ur1, ur2;
    v0 -= dvA[id0]; ur0 = dvA[id0];
    v1 -= dvA[id1]; ur1 = dvA[id1];
    if (v2ok) { v2 -= dvA[id2]; ur2 = dvA[id2]; } else ur2 = 0.f;

    float minv0 = INFV, minv1 = INFV, minv2 = INFV;
    int way0 = 255, way1 = 255, way2 = 255;
    bool used0 = false, used1 = false, used2 = false;

    unsigned long long nx0 = 0, nx1 = 0, nx2 = 0;
    int arrIt = 0;
    for (int pass = 0; pass < 2; ++pass) {
        while ((fr0 | fr1 | fr2) != 0 && arrIt < ARRCAP) {
            ++arrIt;
            int i;
            if (fr0)      { int t = __builtin_ctzll(fr0); i = t + 1;   fr0 &= fr0 - 1; }
            else if (fr1) { int t = __builtin_ctzll(fr1); i = t + 65;  fr1 &= fr1 - 1; }
            else          { int t = __builtin_ctzll(fr2); i = t + 129; fr2 &= fr2 - 1; }
            int roff = (i - 1) * RBW;
            unsigned pr = *(const unsigned*)((const char*)Cw + roff + a32);
            float r0 = h2f((unsigned short)pr) - v0;
            float r1 = h2f((unsigned short)(pr >> 16)) - v1;
            float r2 = h2f(*(const unsigned short*)((const char*)Cw + roff + a16)) - v2;
            unsigned p0 = packnn(r0, id0);
            unsigned p1 = packnn(r1, id1);
            unsigned p2 = v2ok ? packnn(r2, id2) : 0xFFFFFFFFu;
            unsigned lmin = umin32(p0, umin32(p1, p2));
            unsigned lmed = umin32(umax32(p0, p1), umax32(umin32(p0, p1), p2));
            unsigned M1 = reduceMin64(lmin);
            unsigned M2 = reduceMin64(lmin == M1 ? lmed : lmin);
            int j1 = (int)(M1 & 0xFFu), j2 = (int)(M2 & 0xFFu);
            int l1 = laneOf(j1), s1 = slotOf(j1);
            int l2 = laneOf(j2), s2 = slotOf(j2);
            float umin_e = rlanef(SEL3(s1, r0, r1, r2), l1);
            float usub_e = rlanef(SEL3(s2, r0, r1, r2), l2);
            int iA = rlanei(SEL3(s1, Pa0, Pa1, Pa2), l1);
            int iB = rlanei(SEL3(s2, Pa0, Pa1, Pa2), l2);
            if (usub_e < umin_e) {
                int tj = j1; j1 = j2; j2 = tj;
                int tl = l1; l1 = l2; l2 = tl;
                int ts = s1; s1 = s2; s2 = ts;
                float tv = umin_e; umin_e = usub_e; usub_e = tv;
                int ti = iA; iA = iB; iB = ti;
            }
            bool strict = (umin_e < usub_e);
            int jt, idisp;
            float ua = usub_e;
            if (strict) {
                float d = usub_e - umin_e;
                if (lane == l1) { if (s1 == 0) v0 -= d; else if (s1 == 1) v1 -= d; else v2 -= d; }
                jt = j1; idisp = iA;
            } else if (iA > 0) {
                jt = j2; idisp = iB;
            } else {
                jt = j1; idisp = 0;
            }
            int lt = laneOf(jt), st = slotOf(jt);
            if (lane == lt) {
                if (st == 0)      { Pa0 = i; ur0 = ua; }
                else if (st == 1) { Pa1 = i; ur1 = ua; }
                else              { Pa2 = i; ur2 = ua; }
            }
            if (lane == 0) Ulds[i] = ua;
            if (idisp > 0) {
                if (strict) {
                    if (idisp <= 64)       fr0 |= 1ull << (idisp - 1);
                    else if (idisp <= 128) fr1 |= 1ull << (idisp - 65);
                    else                   fr2 |= 1ull << (idisp - 129);
                } else {
                    if (idisp <= 64)       nx0 |= 1ull << (idisp - 1);
                    else if (idisp <= 128) nx1 |= 1ull << (idisp - 65);
                    else                   nx2 |= 1ull << (idisp - 129);
                }
            }
        }
        fr0 |= nx0; fr1 |= nx1; fr2 |= nx2;
        nx0 = nx1 = nx2 = 0;
    }

    while ((fr0 | fr1 | fr2) != 0) {
        int i;
        if (fr0)      { int t = __builtin_ctzll(fr0); i = t + 1;   fr0 &= fr0 - 1; }
        else if (fr1) { int t = __builtin_ctzll(fr1); i = t + 65;  fr1 &= fr1 - 1; }
        else          { int t = __builtin_ctzll(fr2); i = t + 129; fr2 &= fr2 - 1; }
        float u_root = Ulds[i];
        minv0 = minv1 = minv2 = INFV;
        way0 = way1 = way2 = 255;
        used0 = used1 = used2 = false;
        {
            int roff = (i - 1) * RBW;
            unsigned pr = *(const unsigned*)((const char*)Cw + roff + a32);
            float c0 = h2f((unsigned short)pr);
            float c1 = h2f((unsigned short)(pr >> 16));
            float c2 = h2f(*(const unsigned short*)((const char*)Cw + roff + a16));
            minv0 = c0 - (u_root + v0);
            minv1 = c1 - (u_root + v1);
            minv2 = v2ok ? (c2 - (u_root + v2)) : INFV;
        }
        int jend = -1;
        for (int it = 0; it < Nn + 2; ++it) {
            unsigned q0p = used0 ? 0xFFFFFFFFu : packnn(minv0, id0);
            unsigned q1p = used1 ? 0xFFFFFFFFu : packnn(minv1, id1);
            unsigned q2p = (v2ok && !used2) ? packnn(minv2, id2) : 0xFFFFFFFFu;
            unsigned pk = reduceMin64(umin32(q0p, umin32(q1p, q2p)));
            int j1 = (int)(pk & 0xFFu);
            float delta = unpacknn(pk);
            int l1 = laneOf(j1), s1 = slotOf(j1);
            int i1 = rlanei(SEL3(s1, Pa0, Pa1, Pa2), l1);
            float u1 = rlanef(SEL3(s1, ur0, ur1, ur2), l1);
            u_root += delta;
            v0 = used0 ? v0 - delta : v0;  ur0 = used0 ? ur0 + delta : ur0;  minv0 = used0 ? minv0 : minv0 - delta;
            v1 = used1 ? v1 - delta : v1;  ur1 = used1 ? ur1 + delta : ur1;  minv1 = used1 ? minv1 : minv1 - delta;
            v2 = used2 ? v2 - delta : v2;  ur2 = used2 ? ur2 + delta : ur2;  minv2 = used2 ? minv2 : minv2 - delta;
            bool hit = (lane == l1);
            if (s1 == 0) used0 |= hit; else if (s1 == 1) used1 |= hit; else used2 |= hit;
            if (i1 == 0) { jend = j1; break; }
            int roff = (i1 - 1) * RBW;
            unsigned pr = *(const unsigned*)((const char*)Cw + roff + a32);
            float c0 = h2f((unsigned short)pr);
            float c1 = h2f((unsigned short)(pr >> 16));
            float c2 = h2f(*(const unsigned short*)((const char*)Cw + roff + a16));
            float n0_ = c0 - (u1 + v0), n1_ = c1 - (u1 + v1), n2_ = c2 - (u1 + v2);
            if (!used0 && n0_ < minv0) { minv0 = n0_; way0 = j1; }
            if (!used1 && n1_ < minv1) { minv1 = n1_; way1 = j1; }
            if (v2ok && !used2 && n2_ < minv2) { minv2 = n2_; way2 = j1; }
        }
        int j = jend;
        while (j >= 0) {
            int l = laneOf(j), s = slotOf(j);
            int w = rlanei(SEL3(s, way0, way1, way2), l);
            int pnew; float unew;
            if (w == 255) { pnew = i; unew = u_root; }
            else {
                int lw = laneOf(w), sw = slotOf(w);
                pnew = rlanei(SEL3(sw, Pa0, Pa1, Pa2), lw);
                unew = rlanef(SEL3(sw, ur0, ur1, ur2), lw);
            }
            if (lane == l) {
                if (s == 0)      { Pa0 = pnew; ur0 = unew; }
                else if (s == 1) { Pa1 = pnew; ur1 = unew; }
                else             { Pa2 = pnew; ur2 = unew; }
            }
            j = (w == 255) ? -1 : w;
        }
    }

    float tot = 0.f;
    if (Pa0 > 0) { int orig = rowIdxL[Pa0 - 1]; tot += cg[(size_t)orig * Nn + id0] * qsL[orig] * ks0f; }
    if (Pa1 > 0) { int orig = rowIdxL[Pa1 - 1]; tot += cg[(size_t)orig * Nn + id1] * qsL[orig] * ks1f; }
    if (v2ok && Pa2 > 0) { int orig = rowIdxL[Pa2 - 1]; tot += cg[(size_t)orig * Nn + id2] * qsL[orig] * ks2f; }
    #pragma unroll
    for (int off = 32; off; off >>= 1) tot += __shfl_xor(tot, off);
    if (lane == 0) ws[OFF_PD + b] = 1.f - tot * (1.f / (float)Pn);
}

// ---------------- K4: mean over batches ----------------
__global__ void k_final(const float* __restrict__ ws, float* __restrict__ out) {
    float v = ws[OFF_PD + threadIdx.x];
    #pragma unroll
    for (int off = 32; off; off >>= 1) v += __shfl_xor(v, off);
    if (threadIdx.x == 0) out[0] = v * (1.f / 64.f);
}

extern "C" void kernel_launch(void* const* d_in, const int* in_sizes, int n_in,
                              void* d_out, int out_size, void* d_ws, size_t ws_size,
                              hipStream_t stream) {
    const float* feat = (const float*)d_in[0];
    const int*   pos  = (const int*)d_in[1];
    float* ws  = (float*)d_ws;
    float* out = (float*)d_out;
    k_tr   <<<dim3(96, 64), 256, 0, stream>>>(feat, ws);
    k_mm   <<<384, 256, 0, stream>>>(pos, ws);
    k_hung <<<64, 256, 0, stream>>>(ws);
    k_final<<<1, 64, 0, stream>>>(ws, out);
}

// Round 12
// 102.392 us; speedup vs baseline: 101.2652x; 1.0040x over previous
//
#include <hip/hip_runtime.h>
#include <hip/hip_bf16.h>

#define Bn 64
#define Cn 2048
#define Nn 162          // H*W = 18*9
#define Pn 81           // Nn/2
#define NP 176          // padded N for featT rows (11 tiles of 16)
#define INFV 1.0e9f
#define BIGI 0x7FFFFFFF
#define RBW 328         // k_hung LDS cost-row stride BYTES
#define ARRCAP 700

// ws layout (in floats)
// featT layout: [b][cc(32)][gcol(NP)][32 u32]  (cc = 64-channel chunk)
#define OFF_T    0                           // bf16 featT = 11,534,336 floats
#define OFF_P    11534336                    // [64][32][192] norm^2 partials
#define OFF_QS   (OFF_P + 64*32*192)         // (unused, layout keep)
#define OFF_KS   (OFF_QS + 64*162)           // (unused, layout keep)
#define OFF_COST (OFF_KS + 64*162)           // [64][162][162] RAW sim (fp32)
#define OFF_PD   (OFF_COST + 64*162*162)     // [64] per-batch pos_dis

typedef __attribute__((ext_vector_type(8))) short bf16x8;
typedef __attribute__((ext_vector_type(4))) float f32x4;
typedef __attribute__((ext_vector_type(4))) unsigned u32x4;

static __device__ __forceinline__ unsigned short f2bf(float x) {
    unsigned int u = __builtin_bit_cast(unsigned int, x);
    unsigned int r = (u + 0x7fffu + ((u >> 16) & 1u)) >> 16;   // RNE
    return (unsigned short)r;
}
static __device__ __forceinline__ unsigned short f2h(float x) {
    _Float16 h = (_Float16)x;
    return __builtin_bit_cast(unsigned short, h);
}
static __device__ __forceinline__ float h2f(unsigned short u) {
    return (float)__builtin_bit_cast(_Float16, u);
}
static __device__ __forceinline__ unsigned umin32(unsigned a, unsigned b) { return a < b ? a : b; }
static __device__ __forceinline__ unsigned umax32(unsigned a, unsigned b) { return a > b ? a : b; }
static __device__ __forceinline__ unsigned packnn(float v, int id) {
    float c = fmaxf(v, 0.f);
    return (__builtin_bit_cast(unsigned, c) & 0xFFFFFF00u) | (unsigned)id;
}
static __device__ __forceinline__ float unpacknn(unsigned pk) {
    return __builtin_bit_cast(float, pk & 0xFFFFFF00u);
}
static __device__ __forceinline__ unsigned reduceMin64(unsigned x) {
    int v = (int)x, t;
    t = __builtin_amdgcn_update_dpp(0, v, 0x121, 0xF, 0xF, true); v = (int)umin32((unsigned)v, (unsigned)t);
    t = __builtin_amdgcn_update_dpp(0, v, 0x122, 0xF, 0xF, true); v = (int)umin32((unsigned)v, (unsigned)t);
    t = __builtin_amdgcn_update_dpp(0, v, 0x124, 0xF, 0xF, true); v = (int)umin32((unsigned)v, (unsigned)t);
    t = __builtin_amdgcn_update_dpp(0, v, 0x128, 0xF, 0xF, true); v = (int)umin32((unsigned)v, (unsigned)t);
    unsigned a = (unsigned)__builtin_amdgcn_readlane(v, 0);
    unsigned b = (unsigned)__builtin_amdgcn_readlane(v, 16);
    unsigned c = (unsigned)__builtin_amdgcn_readlane(v, 32);
    unsigned d = (unsigned)__builtin_amdgcn_readlane(v, 48);
    return umin32(umin32(a, b), umin32(c, d));
}
static __device__ __forceinline__ int rlanei(int v, int l) { return __builtin_amdgcn_readlane(v, l); }
static __device__ __forceinline__ float rlanef(float v, int l) {
    return __builtin_bit_cast(float, __builtin_amdgcn_readlane(__builtin_bit_cast(int, v), l));
}
static __device__ __forceinline__ int laneOf(int id) { return id < 128 ? (id >> 1) : (id - 128); }
static __device__ __forceinline__ int slotOf(int id) { return id < 128 ? (id & 1) : 2; }
static __device__ __forceinline__ unsigned long long mask_n(int n) {
    if (n <= 0) return 0ull;
    if (n >= 64) return ~0ull;
    return (1ull << n) - 1ull;
}
#define SEL3(s, a0, a1, a2) ((s) == 0 ? (a0) : ((s) == 1 ? (a1) : (a2)))

// ---------------- K1: pack-at-load transpose + norm^2, contiguous writes ----------------
// featT [b][cc][gcol][32p]: block (b,cc,ct) writes ONE contiguous 8KB region.
__global__ __launch_bounds__(256) void k_tr(const float* __restrict__ feat, float* __restrict__ ws) {
    int x = blockIdx.x;            // 0..95: cc = ch-chunk (32), ct = col-chunk (3)
    int cc = x / 3, ct = x % 3;
    int b = blockIdx.y;
    int tid = threadIdx.x;
    int c2 = tid & 31, pg = tid >> 5;         // col-pair 0..31, p-group 0..7
    __shared__ unsigned Tp[32][65];           // packed bf16 ch-pairs [p][col]
    __shared__ float Pp[8][64];               // norm^2 partials
    int gc0 = ct * 64 + 2 * c2;
    bool ok  = (gc0 < Nn);
    bool ok1 = (gc0 + 1 < Nn);
    int gcs = ok ? gc0 : 0;                   // clamp addr, mask values later
    const float* fb = feat + ((size_t)b * Cn + (size_t)cc * 64) * Nn;
    float2 fa[4], fc[4];
    #pragma unroll
    for (int it = 0; it < 4; ++it) {
        int p = pg + it * 8;
        fa[it] = *(const float2*)(fb + (size_t)(2 * p) * Nn + gcs);
        fc[it] = *(const float2*)(fb + (size_t)(2 * p + 1) * Nn + gcs);
    }
    float s0 = 0.f, s1 = 0.f;
    #pragma unroll
    for (int it = 0; it < 4; ++it) {
        int p = pg + it * 8;
        float ax = ok  ? fa[it].x : 0.f;
        float ay = ok1 ? fa[it].y : 0.f;
        float cx = ok  ? fc[it].x : 0.f;
        float cy = ok1 ? fc[it].y : 0.f;
        s0 = fmaf(ax, ax, fmaf(cx, cx, s0));
        s1 = fmaf(ay, ay, fmaf(cy, cy, s1));
        Tp[p][2 * c2]     = (unsigned)f2bf(ax) | ((unsigned)f2bf(cx) << 16);
        Tp[p][2 * c2 + 1] = (unsigned)f2bf(ay) | ((unsigned)f2bf(cy) << 16);
    }
    Pp[pg][2 * c2]     = s0;
    Pp[pg][2 * c2 + 1] = s1;
    __syncthreads();
    if (tid < 64) {
        float t = 0.f;
        #pragma unroll
        for (int g = 0; g < 8; ++g) t += Pp[g][tid];
        ws[OFF_P + ((size_t)b * 32 + cc) * 192 + ct * 64 + tid] = t;
    }
    unsigned* ft = (unsigned*)(ws + OFF_T);
    size_t base = ((size_t)(b * 32 + cc) * NP + ct * 64) * 32;
    #pragma unroll
    for (int it = 0; it < 8; ++it) {
        int idx = it * 256 + tid;
        int c = idx >> 5;
        int gcol = ct * 64 + c;
        if (gcol < NP) ft[base + idx] = Tp[idx & 31][c];   // fully coalesced, contiguous
    }
}

// ---------------- K2: bf16 MFMA GEMM from featT -> RAW sim ----------------
// featT [b][cc][gcol][8 granules of 16B]; granule gg: cc=gg>>3, g'=gg&7.
__global__ __launch_bounds__(256) void k_mm(const int* __restrict__ pos_ind,
                                            float* __restrict__ ws) {
    int wg = blockIdx.x;
    int xcd = wg & 7, kk = wg >> 3;
    int b  = xcd + 8 * (kk / 6);
    int mt = kk % 6;
    int tid = threadIdx.x;
    int lane = tid & 63, w = tid >> 6;
    int q0 = mt * 32;
    int pb = pos_ind[b];
    const u32x4* At = (const u32x4*)((const unsigned short*)(ws + OFF_T) + (size_t)b  * NP * Cn);
    const u32x4* Bt = (const u32x4*)((const unsigned short*)(ws + OFF_T) + (size_t)pb * NP * Cn);
    __shared__ u32x4 As[32 * 16];      // 8 KB
    __shared__ u32x4 Bs[176 * 16];     // 44 KB

    f32x4 a00 = {0.f, 0.f, 0.f, 0.f}, a01 = a00, a02 = a00, a10 = a00, a11 = a00, a12 = a00;
    const int ct0 = w * 3, ct1 = w * 3 + 1, ct2 = w * 3 + 2;
    const bool has2 = (ct2 < 11);
    const int fr = lane & 15, fq = lane >> 4;

    for (int c0 = 0; c0 < Cn; c0 += 128) {
        int cc0 = c0 >> 6;                     // base 64-ch chunk (2 per iter)
        #pragma unroll
        for (int it = 0; it < 2; ++it) {
            int task = it * 256 + tid;
            int r = task >> 4, g = task & 15;
            int rowc = q0 + r; if (rowc > NP - 1) rowc = NP - 1;
            As[r * 16 + (g ^ (r & 15))] = At[((size_t)(cc0 + (g >> 3)) * NP + rowc) * 8 + (g & 7)];
        }
        #pragma unroll
        for (int it = 0; it < 11; ++it) {
            int task = it * 256 + tid;
            int col = task >> 4, g = task & 15;
            Bs[col * 16 + (g ^ (col & 15))] = Bt[((size_t)(cc0 + (g >> 3)) * NP + col) * 8 + (g & 7)];
        }
        __syncthreads();
        #pragma unroll
        for (int ks = 0; ks < 4; ++ks) {
            int gk = ks * 4 + fq;
            bf16x8 af0 = *(const bf16x8*)&As[fr * 16 + (gk ^ fr)];
            bf16x8 af1 = *(const bf16x8*)&As[(16 + fr) * 16 + (gk ^ fr)];
            bf16x8 b0 = *(const bf16x8*)&Bs[(ct0 * 16 + fr) * 16 + (gk ^ fr)];
            bf16x8 b1 = *(const bf16x8*)&Bs[(ct1 * 16 + fr) * 16 + (gk ^ fr)];
            a00 = __builtin_amdgcn_mfma_f32_16x16x32_bf16(af0, b0, a00, 0, 0, 0);
            a01 = __builtin_amdgcn_mfma_f32_16x16x32_bf16(af0, b1, a01, 0, 0, 0);
            a10 = __builtin_amdgcn_mfma_f32_16x16x32_bf16(af1, b0, a10, 0, 0, 0);
            a11 = __builtin_amdgcn_mfma_f32_16x16x32_bf16(af1, b1, a11, 0, 0, 0);
            if (has2) {
                bf16x8 b2 = *(const bf16x8*)&Bs[(ct2 * 16 + fr) * 16 + (gk ^ fr)];
                a02 = __builtin_amdgcn_mfma_f32_16x16x32_bf16(af0, b2, a02, 0, 0, 0);
                a12 = __builtin_amdgcn_mfma_f32_16x16x32_bf16(af1, b2, a12, 0, 0, 0);
            }
        }
        __syncthreads();
    }

    float* simg = ws + OFF_COST + (size_t)b * Nn * Nn;
    int c0_ = ct0 * 16 + fr, c1_ = ct1 * 16 + fr, c2_ = ct2 * 16 + fr;
    #pragma unroll
    for (int j = 0; j < 4; ++j) {
        int r0 = q0 + fq * 4 + j;
        int r1 = r0 + 16;
        if (r0 < Nn) {
            if (c0_ < Nn) simg[(size_t)r0 * Nn + c0_] = a00[j];
            if (c1_ < Nn) simg[(size_t)r0 * Nn + c1_] = a01[j];
            if (has2 && c2_ < Nn) simg[(size_t)r0 * Nn + c2_] = a02[j];
        }
        if (r1 < Nn) {
            if (c0_ < Nn) simg[(size_t)r1 * Nn + c0_] = a10[j];
            if (c1_ < Nn) simg[(size_t)r1 * Nn + c1_] = a11[j];
            if (has2 && c2_ < Nn) simg[(size_t)r1 * Nn + c2_] = a12[j];
        }
    }
}

// ---------------- K3: fused stats + rectangular LAPJV ----------------
__global__ __launch_bounds__(256) void k_hung(float* __restrict__ ws) {
    const int b = blockIdx.x;
    const int tid = threadIdx.x;
    const int lane = tid & 63, wv = tid >> 6;
    __shared__ unsigned short Cw[(Nn * RBW) / 2 + 32];
    __shared__ int rowBest[Nn + 1];
    __shared__ float Ulds[Nn + 1];
    __shared__ float dvA[192];
    __shared__ float pcm[4][192];
    __shared__ int   pim[4][192];
    __shared__ short rowIdxL[Nn];
    __shared__ float qsL[192];
    __shared__ float ksL[192];
    const float* cg = ws + OFF_COST + (size_t)b * Nn * Nn;   // RAW sim

    const bool v2ok = (lane < Nn - 128);     // lane < 34
    const int id0 = 2 * lane, id1 = 2 * lane + 1, id2 = 128 + lane;
    const int a32 = 4 * lane;
    const int a16 = 256 + 2 * lane;

    if (tid <= Nn) { rowBest[tid] = BIGI; Ulds[tid] = 0.f; }
    if (tid < 192) dvA[tid] = 0.f;

    // ---- fused stats ----
    float* arrS = &pcm[0][0];
    float* thrP = &pcm[1][0];
    float normv = 0.f, mvalv = 0.f;
    if (tid < Nn) {
        float s = 0.f;
        #pragma unroll
        for (int ch = 0; ch < 32; ++ch) s += ws[OFF_P + ((size_t)b * 32 + ch) * 192 + tid];
        normv = sqrtf(s);
        arrS[tid] = normv;
    }
    __syncthreads();   // S1
    {
        float mn = INFV, mx = -INFV;
        for (int k = 0; k < Nn; ++k) { float v = arrS[k]; mn = fminf(mn, v); mx = fmaxf(mx, v); }
        if (tid < Nn) mvalv = (normv - mn) / (mx - mn + 1e-12f);
    }
    __syncthreads();   // S2
    if (tid < Nn) arrS[tid] = mvalv;
    __syncthreads();   // S3
    if (tid < Nn) {
        int cl = 0, ce = 0, ceb = 0;
        for (int k = 0; k < Nn; ++k) {
            float v = arrS[k];
            cl  += (v <  mvalv);
            ce  += (v == mvalv);
            ceb += (v == mvalv && k < tid);
        }
        if (cl <= Pn && (cl + ce) > Pn && ceb == 0) thrP[0] = mvalv;
    }
    if (tid < 192) { qsL[tid] = 0.f; ksL[tid] = 0.f; }
    __syncthreads();   // S4
    if (tid < Nn) {
        float inv = 1.f / fmaxf(normv, 1e-12f);
        ksL[tid] = inv;
        qsL[tid] = (mvalv < thrP[0]) ? 0.f : inv;
    }
    __syncthreads();   // S5

    const float ks0f = ksL[id0];
    const float ks1f = ksL[id1];
    const float ks2f = v2ok ? ksL[id2] : 0.f;

    float aq0 = qsL[lane];
    float aq1 = qsL[64 + lane];
    float aq2 = v2ok ? qsL[128 + lane] : 0.f;
    unsigned long long act0 = __ballot(aq0 != 0.f);
    unsigned long long act1 = __ballot(aq1 != 0.f);
    unsigned long long act2 = __ballot(v2ok && aq2 != 0.f);
    int n0 = __popcll(act0), n1 = __popcll(act1), n2 = __popcll(act2);
    const int nact = n0 + n1 + n2;
    if (nact == 0) { if (tid == 0) ws[OFF_PD + b] = 1.f; return; }

    if (wv == 0) {
        unsigned long long lt = (1ull << lane) - 1;
        if ((act0 >> lane) & 1) rowIdxL[__popcll(act0 & lt)] = (short)lane;
        if ((act1 >> lane) & 1) rowIdxL[n0 + __popcll(act1 & lt)] = (short)(64 + lane);
        if (v2ok && ((act2 >> lane) & 1)) rowIdxL[n0 + n1 + __popcll(act2 & lt)] = (short)(128 + lane);
    }
    __syncthreads();   // B1

    for (int k = wv; k < nact; k += 4) {
        int orig = rowIdxL[k];
        float qsr = qsL[orig];
        float2 f2 = *(const float2*)(cg + (size_t)orig * Nn + 2 * lane);
        unsigned pk = (unsigned)f2h(-(f2.x * qsr * ks0f))
                    | ((unsigned)f2h(-(f2.y * qsr * ks1f)) << 16);
        *(unsigned*)((char*)Cw + k * RBW + a32) = pk;
        if (v2ok) *(unsigned short*)((char*)Cw + k * RBW + a16) =
            f2h(-(cg[(size_t)orig * Nn + 128 + lane] * qsr * ks2f));
    }
    __syncthreads();   // B2

    float cm0 = INFV, cm1 = INFV, cm2 = INFV; int im0 = 0, im1 = 0, im2 = 0;
    for (int k = wv; k < nact; k += 4) {
        unsigned pr = *(const unsigned*)((const char*)Cw + k * RBW + a32);
        float c0 = h2f((unsigned short)pr);
        float c1 = h2f((unsigned short)(pr >> 16));
        float c2 = h2f(*(const unsigned short*)((const char*)Cw + k * RBW + a16));
        if (c0 < cm0) { cm0 = c0; im0 = k + 1; }
        if (c1 < cm1) { cm1 = c1; im1 = k + 1; }
        if (v2ok && c2 < cm2) { cm2 = c2; im2 = k + 1; }
    }
    pcm[wv][id0] = cm0; pim[wv][id0] = im0;
    pcm[wv][id1] = cm1; pim[wv][id1] = im1;
    if (v2ok) { pcm[wv][id2] = cm2; pim[wv][id2] = im2; }
    __syncthreads();   // B3

    cm0 = INFV; im0 = 0; cm1 = INFV; im1 = 0; cm2 = INFV; im2 = 0;
    #pragma unroll
    for (int ww = 0; ww < 4; ++ww) {
        float c; int im;
        c = pcm[ww][id0]; im = pim[ww][id0];
        if (im > 0 && (im0 == 0 || c < cm0 || (c == cm0 && im < im0))) { cm0 = c; im0 = im; }
        c = pcm[ww][id1]; im = pim[ww][id1];
        if (im > 0 && (im1 == 0 || c < cm1 || (c == cm1 && im < im1))) { cm1 = c; im1 = im; }
        if (v2ok) {
            c = pcm[ww][id2]; im = pim[ww][id2];
            if (im > 0 && (im2 == 0 || c < cm2 || (c == cm2 && im < im2))) { cm2 = c; im2 = im; }
        }
    }
    if (wv == 0) {
        if (im0 > 0) atomicMin(&rowBest[im0], id0);
        if (im1 > 0) atomicMin(&rowBest[im1], id1);
        if (v2ok && im2 > 0) atomicMin(&rowBest[im2], id2);
    }
    __syncthreads();   // B4

    float v0 = cm0, v1 = cm1, v2 = v2ok ? cm2 : 0.f;
    int Pa0 = (im0 > 0 && rowBest[im0] == id0) ? im0 : 0;
    int Pa1 = (im1 > 0 && rowBest[im1] == id1) ? im1 : 0;
    int Pa2 = (v2ok && im2 > 0 && rowBest[im2] == id2) ? im2 : 0;

    unsigned long long cb0 = __ballot(lane + 1 <= nact && rowBest[lane + 1] != BIGI);
    unsigned long long cb1 = __ballot(lane + 65 <= nact && rowBest[lane + 65] != BIGI);
    unsigned long long cb2 = __ballot(lane + 129 <= nact && rowBest[lane + 129] != BIGI);
    unsigned long long fr0 = mask_n(nact)       & ~cb0;
    unsigned long long fr1 = mask_n(nact - 64)  & ~cb1;
    unsigned long long fr2 = mask_n(nact - 128) & ~cb2;

    for (int k = wv; k < nact; k += 4) {
        int j1c = rowBest[k + 1];
        if (j1c == BIGI) continue;
        int roff = k * RBW;
        unsigned pr = *(const unsigned*)((const char*)Cw + roff + a32);
        float r0 = h2f((unsigned short)pr) - v0;
        float r1 = h2f((unsigned short)(pr >> 16)) - v1;
        float r2 = h2f(*(const unsigned short*)((const char*)Cw + roff + a16)) - v2;
        unsigned p0 = (id0 == j1c) ? 0xFFFFFFFFu : packnn(r0, id0);
        unsigned p1 = (id1 == j1c) ? 0xFFFFFFFFu : packnn(r1, id1);
        unsigned p2 = (v2ok && id2 != j1c) ? packnn(r2, id2) : 0xFFFFFFFFu;
        unsigned pk = reduceMin64(umin32(p0, umin32(p1, p2)));
        float min2 = unpacknn(pk);
        if (lane == 0) { dvA[j1c] = min2; Ulds[k + 1] = min2; }
    }
    __syncthreads();   // B5 — last barrier; waves 1-3 retire
    if (wv != 0) return;

    float ur0, ur1, ur2;
    v0 -= dvA[id0]; ur0 = dvA[id0];
    v1 -= dvA[id1]; ur1 = dvA[id1];
    if (v2ok) { v2 -= dvA[id2]; ur2 = dvA[id2]; } else ur2 = 0.f;

    float minv0 = INFV, minv1 = INFV, minv2 = INFV;
    int way0 = 255, way1 = 255, way2 = 255;
    bool used0 = false, used1 = false, used2 = false;

    unsigned long long nx0 = 0, nx1 = 0, nx2 = 0;
    int arrIt = 0;
    for (int pass = 0; pass < 2; ++pass) {
        while ((fr0 | fr1 | fr2) != 0 && arrIt < ARRCAP) {
            ++arrIt;
            int i;
            if (fr0)      { int t = __builtin_ctzll(fr0); i = t + 1;   fr0 &= fr0 - 1; }
            else if (fr1) { int t = __builtin_ctzll(fr1); i = t + 65;  fr1 &= fr1 - 1; }
            else          { int t = __builtin_ctzll(fr2); i = t + 129; fr2 &= fr2 - 1; }
            int roff = (i - 1) * RBW;
            unsigned pr = *(const unsigned*)((const char*)Cw + roff + a32);
            float r0 = h2f((unsigned short)pr) - v0;
            float r1 = h2f((unsigned short)(pr >> 16)) - v1;
            float r2 = h2f(*(const unsigned short*)((const char*)Cw + roff + a16)) - v2;
            unsigned p0 = packnn(r0, id0);
            unsigned p1 = packnn(r1, id1);
            unsigned p2 = v2ok ? packnn(r2, id2) : 0xFFFFFFFFu;
            unsigned lmin = umin32(p0, umin32(p1, p2));
            unsigned lmed = umin32(umax32(p0, p1), umax32(umin32(p0, p1), p2));
            unsigned M1 = reduceMin64(lmin);
            unsigned M2 = reduceMin64(lmin == M1 ? lmed : lmin);
            int j1 = (int)(M1 & 0xFFu), j2 = (int)(M2 & 0xFFu);
            int l1 = laneOf(j1), s1 = slotOf(j1);
            int l2 = laneOf(j2), s2 = slotOf(j2);
            float umin_e = rlanef(SEL3(s1, r0, r1, r2), l1);
            float usub_e = rlanef(SEL3(s2, r0, r1, r2), l2);
            int iA = rlanei(SEL3(s1, Pa0, Pa1, Pa2), l1);
            int iB = rlanei(SEL3(s2, Pa0, Pa1, Pa2), l2);
            if (usub_e < umin_e) {
                int tj = j1; j1 = j2; j2 = tj;
                int tl = l1; l1 = l2; l2 = tl;
                int ts = s1; s1 = s2; s2 = ts;
                float tv = umin_e; umin_e = usub_e; usub_e = tv;
                int ti = iA; iA = iB; iB = ti;
            }
            bool strict = (umin_e < usub_e);
            int jt, idisp;
            float ua = usub_e;
            if (strict) {
                float d = usub_e - umin_e;
                if (lane == l1) { if (s1 == 0) v0 -= d; else if (s1 == 1) v1 -= d; else v2 -= d; }
                jt = j1; idisp = iA;
            } else if (iA > 0) {
                jt = j2; idisp = iB;
            } else {
                jt = j1; idisp = 0;
            }
            int lt = laneOf(jt), st = slotOf(jt);
            if (lane == lt) {
                if (st == 0)      { Pa0 = i; ur0 = ua; }
                else if (st == 1) { Pa1 = i; ur1 = ua; }
                else              { Pa2 = i; ur2 = ua; }
            }
            if (lane == 0) Ulds[i] = ua;
            if (idisp > 0) {
                if (strict) {
                    if (idisp <= 64)       fr0 |= 1ull << (idisp - 1);
                    else if (idisp <= 128) fr1 |= 1ull << (idisp - 65);
                    else                   fr2 |= 1ull << (idisp - 129);
                } else {
                    if (idisp <= 64)       nx0 |= 1ull << (idisp - 1);
                    else if (idisp <= 128) nx1 |= 1ull << (idisp - 65);
                    else                   nx2 |= 1ull << (idisp - 129);
                }
            }
        }
        fr0 |= nx0; fr1 |= nx1; fr2 |= nx2;
        nx0 = nx1 = nx2 = 0;
    }

    while ((fr0 | fr1 | fr2) != 0) {
        int i;
        if (fr0)      { int t = __builtin_ctzll(fr0); i = t + 1;   fr0 &= fr0 - 1; }
        else if (fr1) { int t = __builtin_ctzll(fr1); i = t + 65;  fr1 &= fr1 - 1; }
        else          { int t = __builtin_ctzll(fr2); i = t + 129; fr2 &= fr2 - 1; }
        float u_root = Ulds[i];
        minv0 = minv1 = minv2 = INFV;
        way0 = way1 = way2 = 255;
        used0 = used1 = used2 = false;
        {
            int roff = (i - 1) * RBW;
            unsigned pr = *(const unsigned*)((const char*)Cw + roff + a32);
            float c0 = h2f((unsigned short)pr);
            float c1 = h2f((unsigned short)(pr >> 16));
            float c2 = h2f(*(const unsigned short*)((const char*)Cw + roff + a16));
            minv0 = c0 - (u_root + v0);
            minv1 = c1 - (u_root + v1);
            minv2 = v2ok ? (c2 - (u_root + v2)) : INFV;
        }
        int jend = -1;
        for (int it = 0; it < Nn + 2; ++it) {
            unsigned q0p = used0 ? 0xFFFFFFFFu : packnn(minv0, id0);
            unsigned q1p = used1 ? 0xFFFFFFFFu : packnn(minv1, id1);
            unsigned q2p = (v2ok && !used2) ? packnn(minv2, id2) : 0xFFFFFFFFu;
            unsigned pk = reduceMin64(umin32(q0p, umin32(q1p, q2p)));
            int j1 = (int)(pk & 0xFFu);
            float delta = unpacknn(pk);
            int l1 = laneOf(j1), s1 = slotOf(j1);
            int i1 = rlanei(SEL3(s1, Pa0, Pa1, Pa2), l1);
            float u1 = rlanef(SEL3(s1, ur0, ur1, ur2), l1);
            u_root += delta;
            v0 = used0 ? v0 - delta : v0;  ur0 = used0 ? ur0 + delta : ur0;  minv0 = used0 ? minv0 : minv0 - delta;
            v1 = used1 ? v1 - delta : v1;  ur1 = used1 ? ur1 + delta : ur1;  minv1 = used1 ? minv1 : minv1 - delta;
            v2 = used2 ? v2 - delta : v2;  ur2 = used2 ? ur2 + delta : ur2;  minv2 = used2 ? minv2 : minv2 - delta;
            bool hit = (lane == l1);
            if (s1 == 0) used0 |= hit; else if (s1 == 1) used1 |= hit; else used2 |= hit;
            if (i1 == 0) { jend = j1; break; }
            int roff = (i1 - 1) * RBW;
            unsigned pr = *(const unsigned*)((const char*)Cw + roff + a32);
            float c0 = h2f((unsigned short)pr);
            float c1 = h2f((unsigned short)(pr >> 16));
            float c2 = h2f(*(const unsigned short*)((const char*)Cw + roff + a16));
            float n0_ = c0 - (u1 + v0), n1_ = c1 - (u1 + v1), n2_ = c2 - (u1 + v2);
            if (!used0 && n0_ < minv0) { minv0 = n0_; way0 = j1; }
            if (!used1 && n1_ < minv1) { minv1 = n1_; way1 = j1; }
            if (v2ok && !used2 && n2_ < minv2) { minv2 = n2_; way2 = j1; }
        }
        int j = jend;
        while (j >= 0) {
            int l = laneOf(j), s = slotOf(j);
            int w = rlanei(SEL3(s, way0, way1, way2), l);
            int pnew; float unew;
            if (w == 255) { pnew = i; unew = u_root; }
            else {
                int lw = laneOf(w), sw = slotOf(w);
                pnew = rlanei(SEL3(sw, Pa0, Pa1, Pa2), lw);
                unew = rlanef(SEL3(sw, ur0, ur1, ur2), lw);
            }
            if (lane == l) {
                if (s == 0)      { Pa0 = pnew; ur0 = unew; }
                else if (s == 1) { Pa1 = pnew; ur1 = unew; }
                else             { Pa2 = pnew; ur2 = unew; }
            }
            j = (w == 255) ? -1 : w;
        }
    }

    float tot = 0.f;
    if (Pa0 > 0) { int orig = rowIdxL[Pa0 - 1]; tot += cg[(size_t)orig * Nn + id0] * qsL[orig] * ks0f; }
    if (Pa1 > 0) { int orig = rowIdxL[Pa1 - 1]; tot += cg[(size_t)orig * Nn + id1] * qsL[orig] * ks1f; }
    if (v2ok && Pa2 > 0) { int orig = rowIdxL[Pa2 - 1]; tot += cg[(size_t)orig * Nn + id2] * qsL[orig] * ks2f; }
    #pragma unroll
    for (int off = 32; off; off >>= 1) tot += __shfl_xor(tot, off);
    if (lane == 0) ws[OFF_PD + b] = 1.f - tot * (1.f / (float)Pn);
}

// ---------------- K4: mean over batches ----------------
__global__ void k_final(const float* __restrict__ ws, float* __restrict__ out) {
    float v = ws[OFF_PD + threadIdx.x];
    #pragma unroll
    for (int off = 32; off; off >>= 1) v += __shfl_xor(v, off);
    if (threadIdx.x == 0) out[0] = v * (1.f / 64.f);
}

extern "C" void kernel_launch(void* const* d_in, const int* in_sizes, int n_in,
                              void* d_out, int out_size, void* d_ws, size_t ws_size,
                              hipStream_t stream) {
    const float* feat = (const float*)d_in[0];
    const int*   pos  = (const int*)d_in[1];
    float* ws  = (float*)d_ws;
    float* out = (float*)d_out;
    k_tr   <<<dim3(96, 64), 256, 0, stream>>>(feat, ws);
    k_mm   <<<384, 256, 0, stream>>>(pos, ws);
    k_hung <<<64, 256, 0, stream>>>(ws);
    k_final<<<1, 64, 0, stream>>>(ws, out);
}